// Round 1
// 735.484 us; speedup vs baseline: 1.2541x; 1.2541x over previous
//
#include <hip/hip_runtime.h>

// ---------------- problem constants ----------------
#define Bc   4
#define Tc   2048
#define Dc   1024
#define Hc   16
#define DKc  64
#define DVc  128
#define QKDc 1024
#define VDc  2048
#define NPRJ 5120        // q|k|v|gate fused projection width
#define Mc   (Bc * Tc)   // 8192 tokens
#define CHUNK 64         // delta-rule chunk size
#define NCHK (Tc / CHUNK) // 32 chunks per (b,h)

typedef __bf16 bf16;
typedef __bf16 bf16x4 __attribute__((ext_vector_type(4)));
typedef __bf16 bf16x8 __attribute__((ext_vector_type(8)));
typedef float  f32x4  __attribute__((ext_vector_type(4)));

__device__ __forceinline__ float bf2f(bf16 v) { return (float)v; }
__device__ __forceinline__ bf16  f2bf(float v) { return (bf16)v; }
__device__ __forceinline__ float sigmoidf_(float x) { return 1.0f / (1.0f + __expf(-x)); }
__device__ __forceinline__ f32x4 mfma16(bf16x8 a, bf16x8 b, f32x4 c) {
    return __builtin_amdgcn_mfma_f32_16x16x32_bf16(a, b, c, 0, 0, 0);
}

// async global->LDS, 16B/lane; lds dest = wave-uniform base + lane*16
__device__ __forceinline__ void glds16(const bf16* g, void* l) {
    __builtin_amdgcn_global_load_lds((const __attribute__((address_space(1))) void*)g,
                                     (__attribute__((address_space(3))) void*)l, 16, 0, 0);
}

// XOR-swizzled addressing for [32][64] bf16 LDS tiles (bank-conflict-free b128
// column-slice reads; bijective within each row's 128B).
__device__ __forceinline__ bf16* swz32x64(bf16* base, int r, int k) {
    int byte = (((r << 6) + k) << 1) ^ ((r & 7) << 4);
    return (bf16*)((char*)base + byte);
}

// ---------------- cast fp32 -> bf16 ----------------
__global__ __launch_bounds__(256) void cast_f32_bf16(const float* __restrict__ src,
                                                     bf16* __restrict__ dst, int n4) {
    int i = blockIdx.x * 256 + threadIdx.x;
    if (i < n4) {
        float4 v = ((const float4*)src)[i];
        bf16x4 o = { f2bf(v.x), f2bf(v.y), f2bf(v.z), f2bf(v.w) };
        ((bf16x4*)dst)[i] = o;
    }
}

// ---------------- transpose + cast: fp32 [R][C] -> bf16 [C][R] ----------------
__global__ __launch_bounds__(256) void transpose_cast(const float* __restrict__ src,
                                                      bf16* __restrict__ dst,
                                                      int R, int C) {
    __shared__ float tile[32][33];
    int c0 = blockIdx.x * 32, r0 = blockIdx.y * 32;
    int tx = threadIdx.x, ty = threadIdx.y;
#pragma unroll
    for (int i = 0; i < 32; i += 8) {
        int r = r0 + ty + i, c = c0 + tx;
        tile[ty + i][tx] = (r < R && c < C) ? src[(size_t)r * C + c] : 0.0f;
    }
    __syncthreads();
#pragma unroll
    for (int i = 0; i < 32; i += 8) {
        int rr = c0 + ty + i, cc = r0 + tx;
        if (rr < C && cc < R) dst[(size_t)rr * R + cc] = f2bf(tile[tx][ty + i]);
    }
}

// ---------------- GEMM: C[M,N] = A[M,K] @ Bt[N,K]^T, strided A/C/gate ----------------
template <typename OutT>
__global__ __launch_bounds__(256) void gemm_bt(const bf16* __restrict__ A,
                                               const bf16* __restrict__ Bt,
                                               OutT* __restrict__ C,
                                               int M, int N, int K,
                                               const bf16* __restrict__ gate,
                                               int lda, int ldc, int ldg) {
    __shared__ bf16 As[128 * 32];
    __shared__ bf16 Bs[128 * 32];

    const int n0 = blockIdx.x * 128;
    const int m0 = blockIdx.y * 128;
    const int t = threadIdx.x;
    const int wid = t >> 6, lane = t & 63;
    const int wm = (wid & 1) * 64;
    const int wn = (wid >> 1) * 64;

    f32x4 acc[4][4] = {};

    const int srow = lane >> 2;          // 0..15
    const int scol = (lane & 3) * 8;     // bf16 col offset
    char* AsB = (char*)As;
    char* BsB = (char*)Bs;

    for (int k0 = 0; k0 < K; k0 += 32) {
        glds16(&A[(size_t)(m0 + wid * 16 + srow) * lda + k0 + scol],       AsB + wid * 1024);
        glds16(&A[(size_t)(m0 + 64 + wid * 16 + srow) * lda + k0 + scol],  AsB + 4096 + wid * 1024);
        glds16(&Bt[(size_t)(n0 + wid * 16 + srow) * K + k0 + scol],        BsB + wid * 1024);
        glds16(&Bt[(size_t)(n0 + 64 + wid * 16 + srow) * K + k0 + scol],   BsB + 4096 + wid * 1024);
        __syncthreads();

        const int kh = (lane >> 4) * 8;
        const int lm = lane & 15;
        bf16x8 a[4], b[4];
#pragma unroll
        for (int i = 0; i < 4; i++) a[i] = *(const bf16x8*)&As[(wm + i * 16 + lm) * 32 + kh];
#pragma unroll
        for (int j = 0; j < 4; j++) b[j] = *(const bf16x8*)&Bs[(wn + j * 16 + lm) * 32 + kh];
#pragma unroll
        for (int i = 0; i < 4; i++)
#pragma unroll
            for (int j = 0; j < 4; j++)
                acc[i][j] = __builtin_amdgcn_mfma_f32_16x16x32_bf16(a[i], b[j], acc[i][j], 0, 0, 0);
        __syncthreads();
    }

    const int lm = lane & 15, lq = lane >> 4;
#pragma unroll
    for (int i = 0; i < 4; i++) {
#pragma unroll
        for (int j = 0; j < 4; j++) {
#pragma unroll
            for (int rI = 0; rI < 4; rI++) {
                int row = m0 + wm + i * 16 + lq * 4 + rI;
                int col = n0 + wn + j * 16 + lm;
                float val = acc[i][j][rI];
                if (gate) {
                    float g = bf2f(gate[(size_t)row * ldg + col]);
                    val *= sigmoidf_(g);
                }
                C[(size_t)row * ldc + col] = (OutT)val;
            }
        }
    }
}

// ---------------- zero-centered RMSNorm in place, strided rows ----------------
template <int L>
__global__ __launch_bounds__(256) void zc_rms_kernel(bf16* __restrict__ buf,
                                                     const float* __restrict__ scale,
                                                     int ld) {
    constexpr int NPT = L / 256;
    int row = blockIdx.x;
    int t = threadIdx.x;
    bf16* p = buf + (size_t)row * ld;

    float xv[NPT];
    float s = 0.f, s2 = 0.f;
#pragma unroll
    for (int i = 0; i < NPT; i++) {
        float x = bf2f(p[t + (i << 8)]);
        xv[i] = x;
        s += x;
        s2 += x * x;
    }
    __shared__ float red[2][4];
#pragma unroll
    for (int o = 32; o > 0; o >>= 1) {
        s += __shfl_down(s, o, 64);
        s2 += __shfl_down(s2, o, 64);
    }
    if ((t & 63) == 0) { red[0][t >> 6] = s; red[1][t >> 6] = s2; }
    __syncthreads();
    s  = red[0][0] + red[0][1] + red[0][2] + red[0][3];
    s2 = red[1][0] + red[1][1] + red[1][2] + red[1][3];

    float mean = s / (float)L;
    float var = s2 / (float)L - mean * mean;
    float inv = rsqrtf(var + 1e-5f);
#pragma unroll
    for (int i = 0; i < NPT; i++) {
        float y = (xv[i] - mean) * inv * scale[t + (i << 8)];
        p[t + (i << 8)] = f2bf(y);
    }
}

// ---------------- causal depthwise conv (K=4) + SiLU, strided in, compact out ----------------
__global__ __launch_bounds__(256) void conv_silu(const bf16* __restrict__ xn,
                                                 const float* __restrict__ kern,
                                                 const float* __restrict__ bias,
                                                 bf16* __restrict__ out,
                                                 int Cch, int ldin) {
    int btok = blockIdx.x;
    int tt = btok & (Tc - 1);
    for (int c = threadIdx.x; c < Cch; c += 256) {
        float acc = bias[c];
#pragma unroll
        for (int i = 0; i < 4; i++) {
            int ts = tt - 3 + i;
            if (ts >= 0)
                acc += bf2f(xn[(size_t)(btok - 3 + i) * ldin + c]) * kern[i * Cch + c];
        }
        float y = acc * sigmoidf_(acc);
        out[(size_t)btok * Cch + c] = f2bf(y);
    }
}

// ---------------- alpha / beta: sigmoid(x @ W) for W [D,16], bf16 x ----------------
__global__ __launch_bounds__(64) void alphabeta(const bf16* __restrict__ x,
                                                const float* __restrict__ aw,
                                                const float* __restrict__ bw,
                                                float* __restrict__ af,
                                                float* __restrict__ bfv) {
    int tok = blockIdx.x;
    int lane = threadIdx.x;
    const bf16* xr = x + (size_t)tok * Dc;
    float accA[16] = {};
    float accB[16] = {};
    for (int k = lane; k < Dc; k += 64) {
        float xv = bf2f(xr[k]);
        const float* awr = aw + (size_t)k * Hc;
        const float* bwr = bw + (size_t)k * Hc;
#pragma unroll
        for (int h = 0; h < 16; h++) {
            accA[h] += xv * awr[h];
            accB[h] += xv * bwr[h];
        }
    }
#pragma unroll
    for (int h = 0; h < 16; h++) {
        float a = accA[h], b = accB[h];
#pragma unroll
        for (int o = 32; o > 0; o >>= 1) {
            a += __shfl_down(a, o, 64);
            b += __shfl_down(b, o, 64);
        }
        if (lane == 0) {
            af[(size_t)tok * Hc + h] = sigmoidf_(a);
            bfv[(size_t)tok * Hc + h] = sigmoidf_(b);
        }
    }
}

// ================= chunked gated delta rule =================
// Recurrence (per b,h):  S_i = a_i S_{i-1} + k_i u_i^T,
//   u_i = b_i (v_i - a_i S_{i-1}^T k_i),  o_i = S_i^T q_i.
// Chunk (C=64) closed form with gamma_i = prod_{s<=i} a_s:
//   A_ij = b_i (g_i/g_j) k_i.k_j (j<i);  (I+A) U = diag(b)V - diag(b g) K S0
//   U = Uv - W S0,  Uv = T diag(b)V,  W = T diag(b g)K,  T = (I+A)^-1
//   O  = diag(g) Q S0 + M U,  M_ij = (g_i/g_j) q_i.k_j (j<=i)
//   S' = g_C S0 + Kbar^T U,   Kbar_j = (g_C/g_j) k_j
// prep: per chunk-head, compute T (f32 triangular solve), then M, W, Uv and
// scaled copies. In-place: qf<-Qtilde, kf<-KbarT (transposed), vc<-Uv
// (each global element is touched by exactly one block; reads staged to LDS
// before overwrite). All gamma ratios are exp2(lg_i - lg_j) <= 1 (stable).
__global__ __launch_bounds__(256) void prep(bf16* __restrict__ qf,
                                            bf16* __restrict__ kf,
                                            bf16* __restrict__ vc,
                                            const float* __restrict__ af,
                                            const float* __restrict__ bfv,
                                            bf16* __restrict__ Wb,
                                            bf16* __restrict__ Mb,
                                            float* __restrict__ gamC) {
    __shared__ __align__(16) char smem[53248];
    bf16*  Kc   = (bf16*)(smem);             // [64][72] bf16
    bf16*  Qc   = (bf16*)(smem + 9216);      // [64][72] bf16; later Tb
    float* As   = (float*)(smem + 18432);    // [64][65] f32
    bf16*  Vtb  = (bf16*)(smem + 18432);     // [128][72] bf16 (after solve)
    float* Ts   = (float*)(smem + 35072);    // [64][65] f32
    float* lg_s = (float*)(smem + 51712);    // 64 log2-cumsum
    float* bv_s = lg_s + 64;                 // b_i
    float* bg_s = lg_s + 128;                // b_i * g_i
    float* gm_s = lg_s + 192;                // g_i
    float* kr_s = lg_s + 256;                // g_C / g_i

    const int c    = blockIdx.x;
    const int bh   = blockIdx.y;
    const int b    = bh >> 4, h = bh & 15;
    const int ch   = bh * NCHK + c;
    const int tok0 = b * Tc + c * CHUNK;
    const int tid  = threadIdx.x;
    const int wave = tid >> 6, lane = tid & 63;
    const int lm = lane & 15, lq = lane >> 4, kh = lq * 8;

    // stage K, Q chunk
#pragma unroll
    for (int r = 0; r < 2; r++) {
        int idx = tid + r * 256;
        int row = idx >> 3, c8 = (idx & 7) * 8;
        *(bf16x8*)&Kc[row * 72 + c8] =
            *(const bf16x8*)&kf[(size_t)(tok0 + row) * QKDc + h * DKc + c8];
        *(bf16x8*)&Qc[row * 72 + c8] =
            *(const bf16x8*)&qf[(size_t)(tok0 + row) * QKDc + h * DKc + c8];
    }
    if (tid < 64) {
        float a  = af[(size_t)(tok0 + tid) * Hc + h];
        float bb = bfv[(size_t)(tok0 + tid) * Hc + h];
        float la = __log2f(fmaxf(a, 1e-30f));
#pragma unroll
        for (int o = 1; o < 64; o <<= 1) {       // inclusive prefix sum
            float t = __shfl_up(la, o, 64);
            if (tid >= o) la += t;
        }
        float lgC = __shfl(la, 63, 64);
        lg_s[tid] = la;
        bv_s[tid] = bb;
        float g   = exp2f(la);
        gm_s[tid] = g;
        bg_s[tid] = bb * g;
        kr_s[tid] = exp2f(lgC - la);
        if (tid == 0) gamC[ch] = exp2f(lgC);
    }
    __syncthreads();

    {   // KK^T -> A (f32 LDS, strict lower, scaled); QK^T -> M (global bf16, masked)
        bf16x8 ka[2], qa[2];
#pragma unroll
        for (int s = 0; s < 2; s++) {
            ka[s] = *(const bf16x8*)&Kc[(16 * wave + lm) * 72 + s * 32 + kh];
            qa[s] = *(const bf16x8*)&Qc[(16 * wave + lm) * 72 + s * 32 + kh];
        }
#pragma unroll
        for (int jt = 0; jt < 4; jt++) {
            f32x4 kkacc = {}, qkacc = {};
#pragma unroll
            for (int s = 0; s < 2; s++) {
                bf16x8 kbf = *(const bf16x8*)&Kc[(16 * jt + lm) * 72 + s * 32 + kh];
                kkacc = mfma16(ka[s], kbf, kkacc);
                qkacc = mfma16(qa[s], kbf, qkacc);
            }
#pragma unroll
            for (int rI = 0; rI < 4; rI++) {
                int i = 16 * wave + lq * 4 + rI;
                int j = 16 * jt + lm;
                float ratio = exp2f(lg_s[i] - lg_s[j]);
                As[i * 65 + j] = (j < i) ? bv_s[i] * ratio * kkacc[rI] : 0.f;
                Mb[((size_t)ch * 64 + i) * 64 + j] =
                    (j <= i) ? f2bf(ratio * qkacc[rI]) : f2bf(0.f);
            }
        }
    }
    {   // Qtilde -> qf (in place); KbarT -> kf (in place, transposed [d][j])
#pragma unroll
        for (int r = 0; r < 2; r++) {
            int idx = tid + r * 256;
            int row = idx >> 3, c8 = (idx & 7) * 8;
            bf16x8 v = *(const bf16x8*)&Qc[row * 72 + c8];
            float g = gm_s[row];
            bf16x8 oq;
#pragma unroll
            for (int e = 0; e < 8; e++) oq[e] = f2bf(bf2f(v[e]) * g);
            *(bf16x8*)&qf[(size_t)(tok0 + row) * QKDc + h * DKc + c8] = oq;
            bf16x8 ok;
#pragma unroll
            for (int e = 0; e < 8; e++)
                ok[e] = f2bf(kr_s[c8 + e] * bf2f(Kc[(c8 + e) * 72 + row]));
            *(bf16x8*)&kf[(size_t)(tok0 + row) * QKDc + h * DKc + c8] = ok;
        }
    }
    __syncthreads();
    // T = (I+A)^{-1}: column-parallel forward substitution (f32, no syncs needed:
    // thread cc only ever reads its own column; A rows are broadcasts)
    if (tid < 64) {
        const int cc = tid;
        for (int i = 0; i < 64; i++) {
            float s0 = 0.f, s1 = 0.f, s2 = 0.f, s3 = 0.f;
            int j = 0;
            for (; j + 3 < i; j += 4) {
                s0 += As[i * 65 + j]     * Ts[j * 65 + cc];
                s1 += As[i * 65 + j + 1] * Ts[(j + 1) * 65 + cc];
                s2 += As[i * 65 + j + 2] * Ts[(j + 2) * 65 + cc];
                s3 += As[i * 65 + j + 3] * Ts[(j + 3) * 65 + cc];
            }
            for (; j < i; j++) s0 += As[i * 65 + j] * Ts[j * 65 + cc];
            Ts[i * 65 + cc] = ((i == cc) ? 1.f : 0.f) - ((s0 + s1) + (s2 + s3));
        }
    }
    __syncthreads();
    bf16* Tb = Qc;                        // Qc dead -> reuse for bf16 T
    for (int idx = tid; idx < 4096; idx += 256) {
        int i = idx >> 6, j = idx & 63;
        Tb[i * 72 + j] = f2bf(Ts[i * 65 + j]);
    }
    __syncthreads();                      // Ts dead; Vtb may now overlay As/Ts
#pragma unroll
    for (int r = 0; r < 4; r++) {         // Vtb = (diag(b) V)^T  [128][72]
        int idx = tid + r * 256;
        int j = idx >> 4, c8 = (idx & 15) * 8;
        bf16x8 v = *(const bf16x8*)&vc[(size_t)(tok0 + j) * VDc + h * DVc + c8];
        float bb = bv_s[j];
#pragma unroll
        for (int e = 0; e < 8; e++)
            Vtb[(c8 + e) * 72 + j] = f2bf(bf2f(v[e]) * bb);
    }
    __syncthreads();
    {   // W = T diag(b g) K -> Wb;  Uv = T diag(b) V -> vc (in place)
        bf16x8 ta[2];
#pragma unroll
        for (int s = 0; s < 2; s++)
            ta[s] = *(const bf16x8*)&Tb[(16 * wave + lm) * 72 + s * 32 + kh];
#pragma unroll
        for (int dt = 0; dt < 4; dt++) {
            f32x4 wacc = {};
#pragma unroll
            for (int s = 0; s < 2; s++) {
                bf16x8 wbf;
                int d = 16 * dt + lm;
#pragma unroll
                for (int e = 0; e < 8; e++) {
                    int j = s * 32 + kh + e;
                    wbf[e] = f2bf(bg_s[j] * bf2f(Kc[j * 72 + d]));
                }
                wacc = mfma16(ta[s], wbf, wacc);
            }
#pragma unroll
            for (int rI = 0; rI < 4; rI++) {
                int i = 16 * wave + lq * 4 + rI;
                Wb[((size_t)ch * 64 + i) * 64 + 16 * dt + lm] = f2bf(wacc[rI]);
            }
        }
#pragma unroll
        for (int dt = 0; dt < 8; dt++) {
            f32x4 uacc = {};
#pragma unroll
            for (int s = 0; s < 2; s++) {
                bf16x8 vb = *(const bf16x8*)&Vtb[(16 * dt + lm) * 72 + s * 32 + kh];
                uacc = mfma16(ta[s], vb, uacc);
            }
#pragma unroll
            for (int rI = 0; rI < 4; rI++) {
                int i = 16 * wave + lq * 4 + rI;
                vc[(size_t)(tok0 + i) * VDc + h * DVc + 16 * dt + lm] = f2bf(uacc[rI]);
            }
        }
    }
}

// Sequential part: 32 chunk steps per (b,h), dv split 4 ways -> grid (4,64).
// Per chunk: P = W*S0; U = Uv - P; O = Qt*S0 + M*U; S = gC*S0 + Ut*Kbar.
// S master stays f32 in per-wave accumulators; bf16 shadow in swizzled LDS.
__global__ __launch_bounds__(256) void chunkloop(const bf16* __restrict__ qf,
                                                 const bf16* __restrict__ kf,
                                                 const bf16* __restrict__ vc,
                                                 const bf16* __restrict__ Wb,
                                                 const bf16* __restrict__ Mb,
                                                 const float* __restrict__ gamC,
                                                 bf16* __restrict__ o, int ldo) {
    const int vg = blockIdx.x;           // dv slice of 32
    const int bh = blockIdx.y;
    const int b = bh >> 4, h = bh & 15;
    const int tid = threadIdx.x;
    const int wave = tid >> 6, lane = tid & 63;
    const int lm = lane & 15, lq = lane >> 4, kh = lq * 8;

    __shared__ __align__(16) bf16 SbBuf[32 * 64];   // S^T shadow [dv][dk]
    __shared__ __align__(16) bf16 UtBuf[32 * 64];   // U^T [dv][t]

    for (int idx = tid; idx < 32 * 64; idx += 256) SbBuf[idx] = f2bf(0.f);

    f32x4 Sacc[2] = {};                  // wave's dk-tile = wave; dv tiles 0,1

    const int colK = h * DKc;
    const int colV = h * DVc + vg * 32;

    bf16x8 wa[2], qa[2], ma[2], kb[2];
    bf16 uvv[2][4];

    auto loadFrags = [&](int c, bf16x8 (&wa_)[2], bf16x8 (&qa_)[2], bf16x8 (&ma_)[2],
                         bf16x8 (&kb_)[2], bf16 (&uvv_)[2][4]) {
        const int tok0 = b * Tc + c * CHUNK;
        const size_t chb = ((size_t)bh * NCHK + c) * 64;
#pragma unroll
        for (int s = 0; s < 2; s++) {
            wa_[s] = *(const bf16x8*)&Wb[(chb + 16 * wave + lm) * 64 + s * 32 + kh];
            ma_[s] = *(const bf16x8*)&Mb[(chb + 16 * wave + lm) * 64 + s * 32 + kh];
            qa_[s] = *(const bf16x8*)&qf[(size_t)(tok0 + 16 * wave + lm) * QKDc + colK + s * 32 + kh];
            kb_[s] = *(const bf16x8*)&kf[(size_t)(tok0 + 16 * wave + lm) * QKDc + colK + s * 32 + kh];
        }
#pragma unroll
        for (int dt = 0; dt < 2; dt++)
#pragma unroll
            for (int rI = 0; rI < 4; rI++)
                uvv_[dt][rI] =
                    vc[(size_t)(tok0 + 16 * wave + lq * 4 + rI) * VDc + colV + 16 * dt + lm];
    };

    loadFrags(0, wa, qa, ma, kb, uvv);
    __syncthreads();

    for (int c = 0; c < NCHK; c++) {
        const float gC = gamC[(size_t)bh * NCHK + c];
        bf16x8 sf[2][2];
#pragma unroll
        for (int dt = 0; dt < 2; dt++)
#pragma unroll
            for (int s = 0; s < 2; s++)
                sf[dt][s] = *(const bf16x8*)swz32x64(SbBuf, 16 * dt + lm, s * 32 + kh);
        // m1: P = W * S0   (wave's t-strip x both dv tiles)
        f32x4 pacc[2] = {};
#pragma unroll
        for (int dt = 0; dt < 2; dt++)
#pragma unroll
            for (int s = 0; s < 2; s++)
                pacc[dt] = mfma16(wa[s], sf[dt][s], pacc[dt]);

        // prefetch next chunk's fragments (global only)
        bf16x8 wa2[2], qa2[2], ma2[2], kb2[2];
        bf16 uvv2[2][4];
        if (c + 1 < NCHK) loadFrags(c + 1, wa2, qa2, ma2, kb2, uvv2);

        // U = Uv - P  -> Ut (transposed, swizzled)
#pragma unroll
        for (int dt = 0; dt < 2; dt++)
#pragma unroll
            for (int rI = 0; rI < 4; rI++) {
                float u = bf2f(uvv[dt][rI]) - pacc[dt][rI];
                *swz32x64(UtBuf, 16 * dt + lm, 16 * wave + lq * 4 + rI) = f2bf(u);
            }
        __syncthreads();   // publish Ut

        bf16x8 uf[2][2];
#pragma unroll
        for (int dt = 0; dt < 2; dt++)
#pragma unroll
            for (int s = 0; s < 2; s++)
                uf[dt][s] = *(const bf16x8*)swz32x64(UtBuf, 16 * dt + lm, s * 32 + kh);

        // m2: O = Qt*S0 + M*U  -> global (strided o_core)
        f32x4 oacc[2] = {};
#pragma unroll
        for (int dt = 0; dt < 2; dt++)
#pragma unroll
            for (int s = 0; s < 2; s++) {
                oacc[dt] = mfma16(qa[s], sf[dt][s], oacc[dt]);
                oacc[dt] = mfma16(ma[s], uf[dt][s], oacc[dt]);
            }
        {
            const int tok0 = b * Tc + c * CHUNK;
#pragma unroll
            for (int dt = 0; dt < 2; dt++)
#pragma unroll
                for (int rI = 0; rI < 4; rI++)
                    o[(size_t)(tok0 + 16 * wave + lq * 4 + rI) * ldo + colV + 16 * dt + lm] =
                        f2bf(oacc[dt][rI]);
        }
        // m3: S = gC*S + U^T * Kbar  (f32 accumulators, wave's dk-tile)
#pragma unroll
        for (int dt = 0; dt < 2; dt++) {
#pragma unroll
            for (int e = 0; e < 4; e++) Sacc[dt][e] *= gC;
#pragma unroll
            for (int s = 0; s < 2; s++)
                Sacc[dt] = mfma16(uf[dt][s], kb[s], Sacc[dt]);
        }
        __syncthreads();   // all Sb/Ut reads done before shadow overwrite
#pragma unroll
        for (int dt = 0; dt < 2; dt++)
#pragma unroll
            for (int rI = 0; rI < 4; rI++)
                *swz32x64(SbBuf, 16 * dt + lq * 4 + rI, 16 * wave + lm) = f2bf(Sacc[dt][rI]);
        __syncthreads();   // publish S shadow

        if (c + 1 < NCHK) {
#pragma unroll
            for (int s = 0; s < 2; s++) { wa[s] = wa2[s]; qa[s] = qa2[s]; ma[s] = ma2[s]; kb[s] = kb2[s]; }
#pragma unroll
            for (int dt = 0; dt < 2; dt++)
#pragma unroll
                for (int rI = 0; rI < 4; rI++) uvv[dt][rI] = uvv2[dt][rI];
        }
    }
}

// ---------------- host launch ----------------
extern "C" void kernel_launch(void* const* d_in, const int* in_sizes, int n_in,
                              void* d_out, int out_size, void* d_ws, size_t ws_size,
                              hipStream_t stream) {
    const float* x        = (const float*)d_in[0];
    const float* q_w      = (const float*)d_in[1];
    const float* k_w      = (const float*)d_in[2];
    const float* v_w      = (const float*)d_in[3];
    const float* q_scale  = (const float*)d_in[4];
    const float* k_scale  = (const float*)d_in[5];
    const float* v_scale  = (const float*)d_in[6];
    const float* q_conv_k = (const float*)d_in[7];
    const float* q_conv_b = (const float*)d_in[8];
    const float* k_conv_k = (const float*)d_in[9];
    const float* k_conv_b = (const float*)d_in[10];
    const float* v_conv_k = (const float*)d_in[11];
    const float* v_conv_b = (const float*)d_in[12];
    const float* alpha_w  = (const float*)d_in[13];
    const float* beta_w   = (const float*)d_in[14];
    const float* out_w    = (const float*)d_in[15];
    const float* gate_w   = (const float*)d_in[16];

    // ---- workspace (~208 MB) ----
    char* w = (char*)d_ws;
    bf16* xb  = (bf16*)w; w += (size_t)Mc * Dc * 2;          // 16 MB
    bf16* qwT = (bf16*)w; w += (size_t)QKDc * Dc * 2;        //  2 MB  -- qwT|kwT|vwT|gwT
    bf16* kwT = (bf16*)w; w += (size_t)QKDc * Dc * 2;        //  2 MB     contiguous =
    bf16* vwT = (bf16*)w; w += (size_t)VDc * Dc * 2;         //  4 MB     [5120][1024]
    bf16* gwT = (bf16*)w; w += (size_t)Dc * Dc * 2;          //  2 MB
    bf16* owT = (bf16*)w; w += (size_t)Dc * VDc * 2;         //  4 MB
    bf16* lin_all = (bf16*)w; w += (size_t)Mc * NPRJ * 2;    // 80 MB  [M][5120] q|k|v|g
    bf16* qf = (bf16*)w; w += (size_t)Mc * QKDc * 2;         // 16 MB  (conv q -> Qtilde)
    bf16* kf = (bf16*)w; w += (size_t)Mc * QKDc * 2;         // 16 MB  (conv k -> KbarT)
    bf16* vc = (bf16*)w; w += (size_t)Mc * VDc * 2;          // 32 MB  (conv v -> Uv)
    float* af = (float*)w; w += (size_t)Mc * Hc * 4;
    float* bfv = (float*)w; w += (size_t)Mc * Hc * 4;
    const int NCH_TOT = Bc * Hc * NCHK;                      // 2048 chunk-heads
    bf16* Wb = (bf16*)w; w += (size_t)NCH_TOT * 64 * 64 * 2; // 16 MB
    bf16* Mb = (bf16*)w; w += (size_t)NCH_TOT * 64 * 64 * 2; // 16 MB
    float* gamC = (float*)w; w += (size_t)NCH_TOT * 4;       //  8 KB
    // scan output goes into lin_all cols 0:2048 (q|k sections, dead after convs)
    bf16* o_core = lin_all;

    dim3 tb(32, 8);
    cast_f32_bf16<<<(Mc * Dc / 4 + 255) / 256, 256, 0, stream>>>(x, xb, Mc * Dc / 4);
    transpose_cast<<<dim3(QKDc / 32, Dc / 32), tb, 0, stream>>>(q_w, qwT, Dc, QKDc);
    transpose_cast<<<dim3(QKDc / 32, Dc / 32), tb, 0, stream>>>(k_w, kwT, Dc, QKDc);
    transpose_cast<<<dim3(VDc / 32, Dc / 32), tb, 0, stream>>>(v_w, vwT, Dc, VDc);
    transpose_cast<<<dim3(Dc / 32, Dc / 32), tb, 0, stream>>>(gate_w, gwT, Dc, Dc);
    transpose_cast<<<dim3(Dc / 32, VDc / 32), tb, 0, stream>>>(out_w, owT, VDc, Dc);

    // fused q|k|v|gate projection: one 8192x5120x1024 GEMM (xb fetched once)
    gemm_bt<bf16><<<dim3(NPRJ / 128, Mc / 128), 256, 0, stream>>>(
        xb, qwT, lin_all, Mc, NPRJ, Dc, nullptr, Dc, NPRJ, 0);

    // norms (strided rows inside lin_all)
    zc_rms_kernel<QKDc><<<Mc, 256, 0, stream>>>(lin_all,        q_scale, NPRJ);
    zc_rms_kernel<QKDc><<<Mc, 256, 0, stream>>>(lin_all + 1024, k_scale, NPRJ);
    zc_rms_kernel<VDc><<<Mc, 256, 0, stream>>>(lin_all + 2048,  v_scale, NPRJ);

    // convs: strided in, compact bf16 out
    conv_silu<<<Mc, 256, 0, stream>>>(lin_all,        q_conv_k, q_conv_b, qf, QKDc, NPRJ);
    conv_silu<<<Mc, 256, 0, stream>>>(lin_all + 1024, k_conv_k, k_conv_b, kf, QKDc, NPRJ);
    conv_silu<<<Mc, 256, 0, stream>>>(lin_all + 2048, v_conv_k, v_conv_b, vc, VDc, NPRJ);

    alphabeta<<<Mc, 64, 0, stream>>>(xb, alpha_w, beta_w, af, bfv);

    // chunked delta rule: parallel prep (per chunk-head), then 32-deep MFMA scan
    prep<<<dim3(NCHK, Bc * Hc), 256, 0, stream>>>(qf, kf, vc, af, bfv, Wb, Mb, gamC);
    chunkloop<<<dim3(4, Bc * Hc), 256, 0, stream>>>(qf, kf, vc, Wb, Mb, gamC, o_core, NPRJ);

    // out-projection (A = o_core strided in lin_all) + fused sigmoid gate (cols 4096:5120)
    gemm_bt<float><<<dim3(Dc / 128, Mc / 128), 256, 0, stream>>>(
        o_core, owT, (float*)d_out, Mc, Dc, VDc, lin_all + 4096, NPRJ, Dc, NPRJ);
}

// Round 2
// 654.661 us; speedup vs baseline: 1.4089x; 1.1235x over previous
//
#include <hip/hip_runtime.h>

// ---------------- problem constants ----------------
#define Bc   4
#define Tc   2048
#define Dc   1024
#define Hc   16
#define DKc  64
#define DVc  128
#define QKDc 1024
#define VDc  2048
#define NPRJ 5120        // q|k|v|gate fused projection width
#define Mc   (Bc * Tc)   // 8192 tokens
#define CHUNK 64         // delta-rule chunk size
#define NCHK (Tc / CHUNK) // 32 chunks per (b,h)

typedef __bf16 bf16;
typedef __bf16 bf16x4 __attribute__((ext_vector_type(4)));
typedef __bf16 bf16x8 __attribute__((ext_vector_type(8)));
typedef float  f32x4  __attribute__((ext_vector_type(4)));

__device__ __forceinline__ float bf2f(bf16 v) { return (float)v; }
__device__ __forceinline__ bf16  f2bf(float v) { return (bf16)v; }
__device__ __forceinline__ float sigmoidf_(float x) { return 1.0f / (1.0f + __expf(-x)); }
__device__ __forceinline__ f32x4 mfma16(bf16x8 a, bf16x8 b, f32x4 c) {
    return __builtin_amdgcn_mfma_f32_16x16x32_bf16(a, b, c, 0, 0, 0);
}

// async global->LDS, 16B/lane; lds dest = wave-uniform base + lane*16
__device__ __forceinline__ void glds16(const bf16* g, void* l) {
    __builtin_amdgcn_global_load_lds((const __attribute__((address_space(1))) void*)g,
                                     (__attribute__((address_space(3))) void*)l, 16, 0, 0);
}

// XOR-swizzled addressing for [32][64] bf16 LDS tiles (bank-conflict-free b128
// column-slice reads; bijective within each row's 128B).
__device__ __forceinline__ bf16* swz32x64(bf16* base, int r, int k) {
    int byte = (((r << 6) + k) << 1) ^ ((r & 7) << 4);
    return (bf16*)((char*)base + byte);
}

// ---------------- cast fp32 -> bf16 ----------------
__global__ __launch_bounds__(256) void cast_f32_bf16(const float* __restrict__ src,
                                                     bf16* __restrict__ dst, int n4) {
    int i = blockIdx.x * 256 + threadIdx.x;
    if (i < n4) {
        float4 v = ((const float4*)src)[i];
        bf16x4 o = { f2bf(v.x), f2bf(v.y), f2bf(v.z), f2bf(v.w) };
        ((bf16x4*)dst)[i] = o;
    }
}

// ---------------- transpose + cast: fp32 [R][C] -> bf16 [C][R] ----------------
__global__ __launch_bounds__(256) void transpose_cast(const float* __restrict__ src,
                                                      bf16* __restrict__ dst,
                                                      int R, int C) {
    __shared__ float tile[32][33];
    int c0 = blockIdx.x * 32, r0 = blockIdx.y * 32;
    int tx = threadIdx.x, ty = threadIdx.y;
#pragma unroll
    for (int i = 0; i < 32; i += 8) {
        int r = r0 + ty + i, c = c0 + tx;
        tile[ty + i][tx] = (r < R && c < C) ? src[(size_t)r * C + c] : 0.0f;
    }
    __syncthreads();
#pragma unroll
    for (int i = 0; i < 32; i += 8) {
        int rr = c0 + ty + i, cc = r0 + tx;
        if (rr < C && cc < R) dst[(size_t)rr * R + cc] = f2bf(tile[tx][ty + i]);
    }
}

// ---------------- GEMM: C[M,N] = A[M,K] @ Bt[N,K]^T, strided A/C/gate ----------------
template <typename OutT>
__global__ __launch_bounds__(256) void gemm_bt(const bf16* __restrict__ A,
                                               const bf16* __restrict__ Bt,
                                               OutT* __restrict__ C,
                                               int M, int N, int K,
                                               const bf16* __restrict__ gate,
                                               int lda, int ldc, int ldg) {
    __shared__ bf16 As[128 * 32];
    __shared__ bf16 Bs[128 * 32];

    const int n0 = blockIdx.x * 128;
    const int m0 = blockIdx.y * 128;
    const int t = threadIdx.x;
    const int wid = t >> 6, lane = t & 63;
    const int wm = (wid & 1) * 64;
    const int wn = (wid >> 1) * 64;

    f32x4 acc[4][4] = {};

    const int srow = lane >> 2;          // 0..15
    const int scol = (lane & 3) * 8;     // bf16 col offset
    char* AsB = (char*)As;
    char* BsB = (char*)Bs;

    for (int k0 = 0; k0 < K; k0 += 32) {
        glds16(&A[(size_t)(m0 + wid * 16 + srow) * lda + k0 + scol],       AsB + wid * 1024);
        glds16(&A[(size_t)(m0 + 64 + wid * 16 + srow) * lda + k0 + scol],  AsB + 4096 + wid * 1024);
        glds16(&Bt[(size_t)(n0 + wid * 16 + srow) * K + k0 + scol],        BsB + wid * 1024);
        glds16(&Bt[(size_t)(n0 + 64 + wid * 16 + srow) * K + k0 + scol],   BsB + 4096 + wid * 1024);
        __syncthreads();

        const int kh = (lane >> 4) * 8;
        const int lm = lane & 15;
        bf16x8 a[4], b[4];
#pragma unroll
        for (int i = 0; i < 4; i++) a[i] = *(const bf16x8*)&As[(wm + i * 16 + lm) * 32 + kh];
#pragma unroll
        for (int j = 0; j < 4; j++) b[j] = *(const bf16x8*)&Bs[(wn + j * 16 + lm) * 32 + kh];
#pragma unroll
        for (int i = 0; i < 4; i++)
#pragma unroll
            for (int j = 0; j < 4; j++)
                acc[i][j] = __builtin_amdgcn_mfma_f32_16x16x32_bf16(a[i], b[j], acc[i][j], 0, 0, 0);
        __syncthreads();
    }

    const int lm = lane & 15, lq = lane >> 4;
#pragma unroll
    for (int i = 0; i < 4; i++) {
#pragma unroll
        for (int j = 0; j < 4; j++) {
#pragma unroll
            for (int rI = 0; rI < 4; rI++) {
                int row = m0 + wm + i * 16 + lq * 4 + rI;
                int col = n0 + wn + j * 16 + lm;
                float val = acc[i][j][rI];
                if (gate) {
                    float g = bf2f(gate[(size_t)row * ldg + col]);
                    val *= sigmoidf_(g);
                }
                C[(size_t)row * ldc + col] = (OutT)val;
            }
        }
    }
}

// ---------------- zero-centered RMSNorm in place, strided rows ----------------
template <int L>
__global__ __launch_bounds__(256) void zc_rms_kernel(bf16* __restrict__ buf,
                                                     const float* __restrict__ scale,
                                                     int ld) {
    constexpr int NPT = L / 256;
    int row = blockIdx.x;
    int t = threadIdx.x;
    bf16* p = buf + (size_t)row * ld;

    float xv[NPT];
    float s = 0.f, s2 = 0.f;
#pragma unroll
    for (int i = 0; i < NPT; i++) {
        float x = bf2f(p[t + (i << 8)]);
        xv[i] = x;
        s += x;
        s2 += x * x;
    }
    __shared__ float red[2][4];
#pragma unroll
    for (int o = 32; o > 0; o >>= 1) {
        s += __shfl_down(s, o, 64);
        s2 += __shfl_down(s2, o, 64);
    }
    if ((t & 63) == 0) { red[0][t >> 6] = s; red[1][t >> 6] = s2; }
    __syncthreads();
    s  = red[0][0] + red[0][1] + red[0][2] + red[0][3];
    s2 = red[1][0] + red[1][1] + red[1][2] + red[1][3];

    float mean = s / (float)L;
    float var = s2 / (float)L - mean * mean;
    float inv = rsqrtf(var + 1e-5f);
#pragma unroll
    for (int i = 0; i < NPT; i++) {
        float y = (xv[i] - mean) * inv * scale[t + (i << 8)];
        p[t + (i << 8)] = f2bf(y);
    }
}

// ---------------- causal depthwise conv (K=4) + SiLU, strided in, compact out ----------------
__global__ __launch_bounds__(256) void conv_silu(const bf16* __restrict__ xn,
                                                 const float* __restrict__ kern,
                                                 const float* __restrict__ bias,
                                                 bf16* __restrict__ out,
                                                 int Cch, int ldin) {
    int btok = blockIdx.x;
    int tt = btok & (Tc - 1);
    for (int c = threadIdx.x; c < Cch; c += 256) {
        float acc = bias[c];
#pragma unroll
        for (int i = 0; i < 4; i++) {
            int ts = tt - 3 + i;
            if (ts >= 0)
                acc += bf2f(xn[(size_t)(btok - 3 + i) * ldin + c]) * kern[i * Cch + c];
        }
        float y = acc * sigmoidf_(acc);
        out[(size_t)btok * Cch + c] = f2bf(y);
    }
}

// ---------------- alpha / beta: sigmoid(x @ W) for W [D,16], bf16 x ----------------
__global__ __launch_bounds__(64) void alphabeta(const bf16* __restrict__ x,
                                                const float* __restrict__ aw,
                                                const float* __restrict__ bw,
                                                float* __restrict__ af,
                                                float* __restrict__ bfv) {
    int tok = blockIdx.x;
    int lane = threadIdx.x;
    const bf16* xr = x + (size_t)tok * Dc;
    float accA[16] = {};
    float accB[16] = {};
    for (int k = lane; k < Dc; k += 64) {
        float xv = bf2f(xr[k]);
        const float* awr = aw + (size_t)k * Hc;
        const float* bwr = bw + (size_t)k * Hc;
#pragma unroll
        for (int h = 0; h < 16; h++) {
            accA[h] += xv * awr[h];
            accB[h] += xv * bwr[h];
        }
    }
#pragma unroll
    for (int h = 0; h < 16; h++) {
        float a = accA[h], b = accB[h];
#pragma unroll
        for (int o = 32; o > 0; o >>= 1) {
            a += __shfl_down(a, o, 64);
            b += __shfl_down(b, o, 64);
        }
        if (lane == 0) {
            af[(size_t)tok * Hc + h] = sigmoidf_(a);
            bfv[(size_t)tok * Hc + h] = sigmoidf_(b);
        }
    }
}

// ================= chunked gated delta rule =================
// Chunk (C=64) closed form with gamma_i = prod_{s<=i} a_s:
//   A_ij = b_i (g_i/g_j) k_i.k_j (j<i);  (I+A) U = diag(b)V - diag(b g) K S0
//   U = Uv - W S0,  Uv = T diag(b)V,  W = T diag(b g)K,  T = (I+A)^-1
//   O  = diag(g) Q S0 + M U,  M_ij = (g_i/g_j) q_i.k_j (j<=i)
//   S' = g_C S0 + Kbar^T U,   Kbar_j = (g_C/g_j) k_j
//
// T is computed by BLOCKED inversion (round-1 lesson: the 64-step column
// solve was a 1-wave, ~23K-cycle dependent chain = half the kernel):
//   - 4 diagonal 16x16 inverses fully in registers (wave0; A broadcast by
//     __shfl), 16-step chain, no LDS round-trips.
//   - off-diagonal blocks via MFMA with bf16 hi/lo split (3 mfma/product,
//     ~f32 accuracy):  T10 = -I1*A10*I0 (and T32), then the 32x32
//     T_BL = -iL2*A_BL*iL1 using transposed intermediates so every mfma
//     operand is row-major (mfma(X,Y) = X*Y^T semantics).
__global__ __launch_bounds__(256) void prep(bf16* __restrict__ qf,
                                            bf16* __restrict__ kf,
                                            bf16* __restrict__ vc,
                                            const float* __restrict__ af,
                                            const float* __restrict__ bfv,
                                            bf16* __restrict__ Wb,
                                            bf16* __restrict__ Mb,
                                            float* __restrict__ gamC) {
    __shared__ __align__(16) char smem[53248];
    bf16*  Kc   = (bf16*)(smem);             // [64][72] bf16, live whole kernel
    bf16*  Qc   = (bf16*)(smem + 9216);      // [64][72] bf16 (phase B only)
    float* DT   = (float*)(smem + 9216);     // [4][16][17] f32: I_g^T (solve)
    float* Pn   = (float*)(smem + 13568);    // [2][16][17] f32: -P^T pair L/H
    float* TT   = (float*)(smem + 15744);    // [16][17] f32: T10^T
    float* Qn   = (float*)(smem + 9216);     // [32][33] f32 (overlays DT, s3+)
    bf16*  Tb   = (bf16*)(smem + 9216);      // [64][72] bf16 T (after s4)
    float* As   = (float*)(smem + 18432);    // [64][65] f32
    bf16*  Vtb  = (bf16*)(smem + 18432);     // [128][72] bf16 (after Tb copy)
    float* Ts   = (float*)(smem + 35072);    // [64][65] f32
    float* lg_s = (float*)(smem + 51712);    // 64 log2-cumsum
    float* bv_s = lg_s + 64;                 // b_i
    float* bg_s = lg_s + 128;                // b_i * g_i
    float* gm_s = lg_s + 192;                // g_i
    float* kr_s = lg_s + 256;                // g_C / g_i

    const int c    = blockIdx.x;
    const int bh   = blockIdx.y;
    const int b    = bh >> 4, h = bh & 15;
    const int ch   = bh * NCHK + c;
    const int tok0 = b * Tc + c * CHUNK;
    const int tid  = threadIdx.x;
    const int wave = tid >> 6, lane = tid & 63;
    const int lm = lane & 15, lq = lane >> 4, kh = lq * 8;

    // ---- phase A: stage K,Q; zero Ts (upper blocks are never written); ab prefix
#pragma unroll
    for (int r = 0; r < 2; r++) {
        int idx = tid + r * 256;
        int row = idx >> 3, c8 = (idx & 7) * 8;
        *(bf16x8*)&Kc[row * 72 + c8] =
            *(const bf16x8*)&kf[(size_t)(tok0 + row) * QKDc + h * DKc + c8];
        *(bf16x8*)&Qc[row * 72 + c8] =
            *(const bf16x8*)&qf[(size_t)(tok0 + row) * QKDc + h * DKc + c8];
    }
    for (int idx = tid; idx < 64 * 65; idx += 256) Ts[idx] = 0.f;
    if (tid < 64) {
        float a  = af[(size_t)(tok0 + tid) * Hc + h];
        float bb = bfv[(size_t)(tok0 + tid) * Hc + h];
        float la = __log2f(fmaxf(a, 1e-30f));
#pragma unroll
        for (int o = 1; o < 64; o <<= 1) {       // inclusive prefix sum
            float t = __shfl_up(la, o, 64);
            if (tid >= o) la += t;
        }
        float lgC = __shfl(la, 63, 64);
        lg_s[tid] = la;
        bv_s[tid] = bb;
        float g   = exp2f(la);
        gm_s[tid] = g;
        bg_s[tid] = bb * g;
        kr_s[tid] = exp2f(lgC - la);
        if (tid == 0) gamC[ch] = exp2f(lgC);
    }
    __syncthreads();

    // ---- phase B: KK^T -> A; QK^T -> M; Qtilde/KbarT global writes
    {
        bf16x8 ka[2], qa[2];
#pragma unroll
        for (int s = 0; s < 2; s++) {
            ka[s] = *(const bf16x8*)&Kc[(16 * wave + lm) * 72 + s * 32 + kh];
            qa[s] = *(const bf16x8*)&Qc[(16 * wave + lm) * 72 + s * 32 + kh];
        }
#pragma unroll
        for (int jt = 0; jt < 4; jt++) {
            f32x4 kkacc = {}, qkacc = {};
#pragma unroll
            for (int s = 0; s < 2; s++) {
                bf16x8 kbf = *(const bf16x8*)&Kc[(16 * jt + lm) * 72 + s * 32 + kh];
                kkacc = mfma16(ka[s], kbf, kkacc);
                qkacc = mfma16(qa[s], kbf, qkacc);
            }
#pragma unroll
            for (int rI = 0; rI < 4; rI++) {
                int i = 16 * wave + lq * 4 + rI;
                int j = 16 * jt + lm;
                float ratio = exp2f(lg_s[i] - lg_s[j]);
                As[i * 65 + j] = (j < i) ? bv_s[i] * ratio * kkacc[rI] : 0.f;
                Mb[((size_t)ch * 64 + i) * 64 + j] =
                    (j <= i) ? f2bf(ratio * qkacc[rI]) : f2bf(0.f);
            }
        }
    }
    {   // Qtilde -> qf (in place); KbarT -> kf (in place, transposed [d][j])
#pragma unroll
        for (int r = 0; r < 2; r++) {
            int idx = tid + r * 256;
            int row = idx >> 3, c8 = (idx & 7) * 8;
            bf16x8 v = *(const bf16x8*)&Qc[row * 72 + c8];
            float g = gm_s[row];
            bf16x8 oq;
#pragma unroll
            for (int e = 0; e < 8; e++) oq[e] = f2bf(bf2f(v[e]) * g);
            *(bf16x8*)&qf[(size_t)(tok0 + row) * QKDc + h * DKc + c8] = oq;
            bf16x8 ok;
#pragma unroll
            for (int e = 0; e < 8; e++)
                ok[e] = f2bf(kr_s[c8 + e] * bf2f(Kc[(c8 + e) * 72 + row]));
            *(bf16x8*)&kf[(size_t)(tok0 + row) * QKDc + h * DKc + c8] = ok;
        }
    }
    __syncthreads();   // As complete; Qc dead -> DT/Pn/TT scratch usable

    // ---- phase C: 4 diagonal 16x16 inverses in registers (wave 0) ----
    // lane = 16g + j: holds column j of block g. A[i][m] fetched by shfl from
    // lane 16g+m (areg[i] is static-indexed -> stays in VGPRs, rule #20).
    if (tid < 64) {
        const int g = lane >> 4, jj = lane & 15, base = lane & 48;
        float areg[16], tcol[16];
#pragma unroll
        for (int i = 0; i < 16; i++) areg[i] = As[(16 * g + i) * 65 + 16 * g + jj];
#pragma unroll
        for (int i = 0; i < 16; i++) tcol[i] = (i == jj) ? 1.f : 0.f;
#pragma unroll
        for (int i = 1; i < 16; i++) {
            float s = 0.f;
#pragma unroll
            for (int m = 0; m < i; m++)
                s = fmaf(__shfl(areg[i], base + m, 64), tcol[m], s);
            tcol[i] = (i == jj) ? 1.f : -s;
        }
#pragma unroll
        for (int i = 0; i < 16; i++) {
            Ts[(16 * g + i) * 65 + 16 * g + jj] = tcol[i];   // I_g row-major
            DT[g * 272 + jj * 17 + i] = tcol[i];             // I_g^T row-major
        }
    }
    __syncthreads();

    // hi/lo split helper is inlined: h = bf16(x), l = bf16(x - h); 3 mfmas
    // (ah*bh + ah*bl + al*bh) give ~2^-16 relative product error.
    // ---- s1: Pn = -(I_{2w}^T * A_off^T), pairs L(w=0): A10, H(w=1): A32. K=16
    if (wave < 2) {
        const int w = wave;
        bf16x8 ah, al, bh, bl;
#pragma unroll
        for (int e = 0; e < 8; e++) {
            int k = kh + e;
            float xa = (k < 16) ? DT[2 * w * 272 + lm * 17 + k] : 0.f;
            bf16 ha = f2bf(xa); ah[e] = ha; al[e] = f2bf(xa - bf2f(ha));
            float xb = (k < 16) ? As[(16 + 32 * w + lm) * 65 + 32 * w + k] : 0.f;
            bf16 hb = f2bf(xb); bh[e] = hb; bl[e] = f2bf(xb - bf2f(hb));
        }
        f32x4 acc = {};
        acc = mfma16(ah, bh, acc); acc = mfma16(ah, bl, acc); acc = mfma16(al, bh, acc);
#pragma unroll
        for (int rI = 0; rI < 4; rI++)
            Pn[w * 272 + (lq * 4 + rI) * 17 + lm] = -acc[rI];
    }
    __syncthreads();

    // ---- s2: T10 = mfma(R(I1),R(Pn_L)) -> Ts[16:32,0:16]; T10^T -> TT;
    //          T32 = mfma(R(I3),R(Pn_H)) -> Ts[48:64,32:48]. K=16
    if (wave < 3) {
        bf16x8 ah, al, bh, bl;
#pragma unroll
        for (int e = 0; e < 8; e++) {
            int k = kh + e;
            float xa = 0.f, xb = 0.f;
            if (k < 16) {
                if (wave == 0)      { xa = Ts[(16 + lm) * 65 + 16 + k]; xb = Pn[lm * 17 + k]; }
                else if (wave == 1) { xa = Pn[lm * 17 + k];             xb = Ts[(16 + lm) * 65 + 16 + k]; }
                else                { xa = Ts[(48 + lm) * 65 + 48 + k]; xb = Pn[272 + lm * 17 + k]; }
            }
            bf16 ha = f2bf(xa); ah[e] = ha; al[e] = f2bf(xa - bf2f(ha));
            bf16 hb = f2bf(xb); bh[e] = hb; bl[e] = f2bf(xb - bf2f(hb));
        }
        f32x4 acc = {};
        acc = mfma16(ah, bh, acc); acc = mfma16(ah, bl, acc); acc = mfma16(al, bh, acc);
#pragma unroll
        for (int rI = 0; rI < 4; rI++) {
            int ro = lq * 4 + rI;
            if (wave == 0)      Ts[(16 + ro) * 65 + lm]      = acc[rI];
            else if (wave == 1) TT[ro * 17 + lm]             = acc[rI];
            else                Ts[(48 + ro) * 65 + 32 + lm] = acc[rI];
        }
    }
    __syncthreads();

    // ---- s3: Qn = -(iL1^T * A_BL^T), 32x32, K=32; tile (a,b) per wave.
    // iL1^T rows: a=0 -> [I0^T | T10^T], a=1 -> [0 | I1^T].
    {
        const int a = wave >> 1, bq = wave & 1;
        bf16x8 ah, al, bh, bl;
#pragma unroll
        for (int e = 0; e < 8; e++) {
            int k = kh + e;  // 0..31
            float xa;
            if (a == 0) xa = (k < 16) ? DT[lm * 17 + k] : TT[lm * 17 + (k - 16)];
            else        xa = (k < 16) ? 0.f : DT[272 + lm * 17 + (k - 16)];
            bf16 ha = f2bf(xa); ah[e] = ha; al[e] = f2bf(xa - bf2f(ha));
            float xb = As[(32 + 16 * bq + lm) * 65 + k];
            bf16 hb = f2bf(xb); bh[e] = hb; bl[e] = f2bf(xb - bf2f(hb));
        }
        f32x4 acc = {};
        acc = mfma16(ah, bh, acc); acc = mfma16(ah, bl, acc); acc = mfma16(al, bh, acc);
        __syncthreads();   // all DT/TT reads done before Qn overlays DT
#pragma unroll
        for (int rI = 0; rI < 4; rI++)
            Qn[(16 * a + lq * 4 + rI) * 33 + 16 * bq + lm] = -acc[rI];
    }
    __syncthreads();

    // ---- s4: T_BL = mfma(R(iL2), R(Qn)) -> Ts[32:64, 0:32]. K=32
    {
        const int a = wave >> 1, bq = wave & 1;
        bf16x8 ah, al, bh, bl;
#pragma unroll
        for (int e = 0; e < 8; e++) {
            int k = kh + e;  // 0..31
            float xa = Ts[(32 + 16 * a + lm) * 65 + 32 + k];
            bf16 ha = f2bf(xa); ah[e] = ha; al[e] = f2bf(xa - bf2f(ha));
            float xb = Qn[(16 * bq + lm) * 33 + k];
            bf16 hb = f2bf(xb); bh[e] = hb; bl[e] = f2bf(xb - bf2f(hb));
        }
        f32x4 acc = {};
        acc = mfma16(ah, bh, acc); acc = mfma16(ah, bl, acc); acc = mfma16(al, bh, acc);
#pragma unroll
        for (int rI = 0; rI < 4; rI++)
            Ts[(32 + 16 * a + lq * 4 + rI) * 65 + 16 * bq + lm] = acc[rI];
    }
    __syncthreads();

    // ---- Tb = bf16(Ts) into Qc region (solve scratch dead) ----
    for (int idx = tid; idx < 4096; idx += 256) {
        int i = idx >> 6, j = idx & 63;
        Tb[i * 72 + j] = f2bf(Ts[i * 65 + j]);
    }
    __syncthreads();                      // Ts dead; Vtb may overlay As/Ts-head
#pragma unroll
    for (int r = 0; r < 4; r++) {         // Vtb = (diag(b) V)^T  [128][72]
        int idx = tid + r * 256;
        int j = idx >> 4, c8 = (idx & 15) * 8;
        bf16x8 v = *(const bf16x8*)&vc[(size_t)(tok0 + j) * VDc + h * DVc + c8];
        float bb = bv_s[j];
#pragma unroll
        for (int e = 0; e < 8; e++)
            Vtb[(c8 + e) * 72 + j] = f2bf(bf2f(v[e]) * bb);
    }
    __syncthreads();
    {   // W = T diag(b g) K -> Wb;  Uv = T diag(b) V -> vc (in place)
        bf16x8 ta[2];
#pragma unroll
        for (int s = 0; s < 2; s++)
            ta[s] = *(const bf16x8*)&Tb[(16 * wave + lm) * 72 + s * 32 + kh];
#pragma unroll
        for (int dt = 0; dt < 4; dt++) {
            f32x4 wacc = {};
#pragma unroll
            for (int s = 0; s < 2; s++) {
                bf16x8 wbf;
                int d = 16 * dt + lm;
#pragma unroll
                for (int e = 0; e < 8; e++) {
                    int j = s * 32 + kh + e;
                    wbf[e] = f2bf(bg_s[j] * bf2f(Kc[j * 72 + d]));
                }
                wacc = mfma16(ta[s], wbf, wacc);
            }
#pragma unroll
            for (int rI = 0; rI < 4; rI++) {
                int i = 16 * wave + lq * 4 + rI;
                Wb[((size_t)ch * 64 + i) * 64 + 16 * dt + lm] = f2bf(wacc[rI]);
            }
        }
#pragma unroll
        for (int dt = 0; dt < 8; dt++) {
            f32x4 uacc = {};
#pragma unroll
            for (int s = 0; s < 2; s++) {
                bf16x8 vb = *(const bf16x8*)&Vtb[(16 * dt + lm) * 72 + s * 32 + kh];
                uacc = mfma16(ta[s], vb, uacc);
            }
#pragma unroll
            for (int rI = 0; rI < 4; rI++) {
                int i = 16 * wave + lq * 4 + rI;
                vc[(size_t)(tok0 + i) * VDc + h * DVc + 16 * dt + lm] = f2bf(uacc[rI]);
            }
        }
    }
}

// Sequential part: 32 chunk steps per (b,h), dv split 4 ways -> grid (4,64).
// Per chunk: P = W*S0; U = Uv - P; O = Qt*S0 + M*U; S = gC*S0 + Ut*Kbar.
// S master stays f32 in per-wave accumulators; bf16 shadow in swizzled LDS.
__global__ __launch_bounds__(256) void chunkloop(const bf16* __restrict__ qf,
                                                 const bf16* __restrict__ kf,
                                                 const bf16* __restrict__ vc,
                                                 const bf16* __restrict__ Wb,
                                                 const bf16* __restrict__ Mb,
                                                 const float* __restrict__ gamC,
                                                 bf16* __restrict__ o, int ldo) {
    const int vg = blockIdx.x;           // dv slice of 32
    const int bh = blockIdx.y;
    const int b = bh >> 4, h = bh & 15;
    const int tid = threadIdx.x;
    const int wave = tid >> 6, lane = tid & 63;
    const int lm = lane & 15, lq = lane >> 4, kh = lq * 8;

    __shared__ __align__(16) bf16 SbBuf[32 * 64];   // S^T shadow [dv][dk]
    __shared__ __align__(16) bf16 UtBuf[32 * 64];   // U^T [dv][t]

    for (int idx = tid; idx < 32 * 64; idx += 256) SbBuf[idx] = f2bf(0.f);

    f32x4 Sacc[2] = {};                  // wave's dk-tile = wave; dv tiles 0,1

    const int colK = h * DKc;
    const int colV = h * DVc + vg * 32;

    bf16x8 wa[2], qa[2], ma[2], kb[2];
    bf16 uvv[2][4];

    auto loadFrags = [&](int c, bf16x8 (&wa_)[2], bf16x8 (&qa_)[2], bf16x8 (&ma_)[2],
                         bf16x8 (&kb_)[2], bf16 (&uvv_)[2][4]) {
        const int tok0 = b * Tc + c * CHUNK;
        const size_t chb = ((size_t)bh * NCHK + c) * 64;
#pragma unroll
        for (int s = 0; s < 2; s++) {
            wa_[s] = *(const bf16x8*)&Wb[(chb + 16 * wave + lm) * 64 + s * 32 + kh];
            ma_[s] = *(const bf16x8*)&Mb[(chb + 16 * wave + lm) * 64 + s * 32 + kh];
            qa_[s] = *(const bf16x8*)&qf[(size_t)(tok0 + 16 * wave + lm) * QKDc + colK + s * 32 + kh];
            kb_[s] = *(const bf16x8*)&kf[(size_t)(tok0 + 16 * wave + lm) * QKDc + colK + s * 32 + kh];
        }
#pragma unroll
        for (int dt = 0; dt < 2; dt++)
#pragma unroll
            for (int rI = 0; rI < 4; rI++)
                uvv_[dt][rI] =
                    vc[(size_t)(tok0 + 16 * wave + lq * 4 + rI) * VDc + colV + 16 * dt + lm];
    };

    loadFrags(0, wa, qa, ma, kb, uvv);
    __syncthreads();

    for (int c = 0; c < NCHK; c++) {
        const float gC = gamC[(size_t)bh * NCHK + c];
        bf16x8 sf[2][2];
#pragma unroll
        for (int dt = 0; dt < 2; dt++)
#pragma unroll
            for (int s = 0; s < 2; s++)
                sf[dt][s] = *(const bf16x8*)swz32x64(SbBuf, 16 * dt + lm, s * 32 + kh);
        // m1: P = W * S0   (wave's t-strip x both dv tiles)
        f32x4 pacc[2] = {};
#pragma unroll
        for (int dt = 0; dt < 2; dt++)
#pragma unroll
            for (int s = 0; s < 2; s++)
                pacc[dt] = mfma16(wa[s], sf[dt][s], pacc[dt]);

        // prefetch next chunk's fragments (global only)
        bf16x8 wa2[2], qa2[2], ma2[2], kb2[2];
        bf16 uvv2[2][4];
        if (c + 1 < NCHK) loadFrags(c + 1, wa2, qa2, ma2, kb2, uvv2);

        // U = Uv - P  -> Ut (transposed, swizzled)
#pragma unroll
        for (int dt = 0; dt < 2; dt++)
#pragma unroll
            for (int rI = 0; rI < 4; rI++) {
                float u = bf2f(uvv[dt][rI]) - pacc[dt][rI];
                *swz32x64(UtBuf, 16 * dt + lm, 16 * wave + lq * 4 + rI) = f2bf(u);
            }
        __syncthreads();   // publish Ut

        bf16x8 uf[2][2];
#pragma unroll
        for (int dt = 0; dt < 2; dt++)
#pragma unroll
            for (int s = 0; s < 2; s++)
                uf[dt][s] = *(const bf16x8*)swz32x64(UtBuf, 16 * dt + lm, s * 32 + kh);

        // m2: O = Qt*S0 + M*U  -> global (strided o_core)
        f32x4 oacc[2] = {};
#pragma unroll
        for (int dt = 0; dt < 2; dt++)
#pragma unroll
            for (int s = 0; s < 2; s++) {
                oacc[dt] = mfma16(qa[s], sf[dt][s], oacc[dt]);
                oacc[dt] = mfma16(ma[s], uf[dt][s], oacc[dt]);
            }
        {
            const int tok0 = b * Tc + c * CHUNK;
#pragma unroll
            for (int dt = 0; dt < 2; dt++)
#pragma unroll
                for (int rI = 0; rI < 4; rI++)
                    o[(size_t)(tok0 + 16 * wave + lq * 4 + rI) * ldo + colV + 16 * dt + lm] =
                        f2bf(oacc[dt][rI]);
        }
        // m3: S = gC*S + U^T * Kbar  (f32 accumulators, wave's dk-tile)
#pragma unroll
        for (int dt = 0; dt < 2; dt++) {
#pragma unroll
            for (int e = 0; e < 4; e++) Sacc[dt][e] *= gC;
#pragma unroll
            for (int s = 0; s < 2; s++)
                Sacc[dt] = mfma16(uf[dt][s], kb[s], Sacc[dt]);
        }
        __syncthreads();   // all Sb/Ut reads done before shadow overwrite
#pragma unroll
        for (int dt = 0; dt < 2; dt++)
#pragma unroll
            for (int rI = 0; rI < 4; rI++)
                *swz32x64(SbBuf, 16 * dt + lq * 4 + rI, 16 * wave + lm) = f2bf(Sacc[dt][rI]);
        __syncthreads();   // publish S shadow

        if (c + 1 < NCHK) {
#pragma unroll
            for (int s = 0; s < 2; s++) { wa[s] = wa2[s]; qa[s] = qa2[s]; ma[s] = ma2[s]; kb[s] = kb2[s]; }
#pragma unroll
            for (int dt = 0; dt < 2; dt++)
#pragma unroll
                for (int rI = 0; rI < 4; rI++) uvv[dt][rI] = uvv2[dt][rI];
        }
    }
}

// ---------------- host launch ----------------
extern "C" void kernel_launch(void* const* d_in, const int* in_sizes, int n_in,
                              void* d_out, int out_size, void* d_ws, size_t ws_size,
                              hipStream_t stream) {
    const float* x        = (const float*)d_in[0];
    const float* q_w      = (const float*)d_in[1];
    const float* k_w      = (const float*)d_in[2];
    const float* v_w      = (const float*)d_in[3];
    const float* q_scale  = (const float*)d_in[4];
    const float* k_scale  = (const float*)d_in[5];
    const float* v_scale  = (const float*)d_in[6];
    const float* q_conv_k = (const float*)d_in[7];
    const float* q_conv_b = (const float*)d_in[8];
    const float* k_conv_k = (const float*)d_in[9];
    const float* k_conv_b = (const float*)d_in[10];
    const float* v_conv_k = (const float*)d_in[11];
    const float* v_conv_b = (const float*)d_in[12];
    const float* alpha_w  = (const float*)d_in[13];
    const float* beta_w   = (const float*)d_in[14];
    const float* out_w    = (const float*)d_in[15];
    const float* gate_w   = (const float*)d_in[16];

    // ---- workspace (~208 MB) ----
    char* w = (char*)d_ws;
    bf16* xb  = (bf16*)w; w += (size_t)Mc * Dc * 2;          // 16 MB
    bf16* qwT = (bf16*)w; w += (size_t)QKDc * Dc * 2;        //  2 MB  -- qwT|kwT|vwT|gwT
    bf16* kwT = (bf16*)w; w += (size_t)QKDc * Dc * 2;        //  2 MB     contiguous =
    bf16* vwT = (bf16*)w; w += (size_t)VDc * Dc * 2;         //  4 MB     [5120][1024]
    bf16* gwT = (bf16*)w; w += (size_t)Dc * Dc * 2;          //  2 MB
    bf16* owT = (bf16*)w; w += (size_t)Dc * VDc * 2;         //  4 MB
    bf16* lin_all = (bf16*)w; w += (size_t)Mc * NPRJ * 2;    // 80 MB  [M][5120] q|k|v|g
    bf16* qf = (bf16*)w; w += (size_t)Mc * QKDc * 2;         // 16 MB  (conv q -> Qtilde)
    bf16* kf = (bf16*)w; w += (size_t)Mc * QKDc * 2;         // 16 MB  (conv k -> KbarT)
    bf16* vc = (bf16*)w; w += (size_t)Mc * VDc * 2;          // 32 MB  (conv v -> Uv)
    float* af = (float*)w; w += (size_t)Mc * Hc * 4;
    float* bfv = (float*)w; w += (size_t)Mc * Hc * 4;
    const int NCH_TOT = Bc * Hc * NCHK;                      // 2048 chunk-heads
    bf16* Wb = (bf16*)w; w += (size_t)NCH_TOT * 64 * 64 * 2; // 16 MB
    bf16* Mb = (bf16*)w; w += (size_t)NCH_TOT * 64 * 64 * 2; // 16 MB
    float* gamC = (float*)w; w += (size_t)NCH_TOT * 4;       //  8 KB
    // scan output goes into lin_all cols 0:2048 (q|k sections, dead after convs)
    bf16* o_core = lin_all;

    dim3 tb(32, 8);
    cast_f32_bf16<<<(Mc * Dc / 4 + 255) / 256, 256, 0, stream>>>(x, xb, Mc * Dc / 4);
    transpose_cast<<<dim3(QKDc / 32, Dc / 32), tb, 0, stream>>>(q_w, qwT, Dc, QKDc);
    transpose_cast<<<dim3(QKDc / 32, Dc / 32), tb, 0, stream>>>(k_w, kwT, Dc, QKDc);
    transpose_cast<<<dim3(VDc / 32, Dc / 32), tb, 0, stream>>>(v_w, vwT, Dc, VDc);
    transpose_cast<<<dim3(Dc / 32, Dc / 32), tb, 0, stream>>>(gate_w, gwT, Dc, Dc);
    transpose_cast<<<dim3(Dc / 32, VDc / 32), tb, 0, stream>>>(out_w, owT, VDc, Dc);

    // fused q|k|v|gate projection: one 8192x5120x1024 GEMM (xb fetched once)
    gemm_bt<bf16><<<dim3(NPRJ / 128, Mc / 128), 256, 0, stream>>>(
        xb, qwT, lin_all, Mc, NPRJ, Dc, nullptr, Dc, NPRJ, 0);

    // norms (strided rows inside lin_all)
    zc_rms_kernel<QKDc><<<Mc, 256, 0, stream>>>(lin_all,        q_scale, NPRJ);
    zc_rms_kernel<QKDc><<<Mc, 256, 0, stream>>>(lin_all + 1024, k_scale, NPRJ);
    zc_rms_kernel<VDc><<<Mc, 256, 0, stream>>>(lin_all + 2048,  v_scale, NPRJ);

    // convs: strided in, compact bf16 out
    conv_silu<<<Mc, 256, 0, stream>>>(lin_all,        q_conv_k, q_conv_b, qf, QKDc, NPRJ);
    conv_silu<<<Mc, 256, 0, stream>>>(lin_all + 1024, k_conv_k, k_conv_b, kf, QKDc, NPRJ);
    conv_silu<<<Mc, 256, 0, stream>>>(lin_all + 2048, v_conv_k, v_conv_b, vc, VDc, NPRJ);

    alphabeta<<<Mc, 64, 0, stream>>>(xb, alpha_w, beta_w, af, bfv);

    // chunked delta rule: parallel prep (per chunk-head), then 32-deep MFMA scan
    prep<<<dim3(NCHK, Bc * Hc), 256, 0, stream>>>(qf, kf, vc, af, bfv, Wb, Mb, gamC);
    chunkloop<<<dim3(4, Bc * Hc), 256, 0, stream>>>(qf, kf, vc, Wb, Mb, gamC, o_core, NPRJ);

    // out-projection (A = o_core strided in lin_all) + fused sigmoid gate (cols 4096:5120)
    gemm_bt<float><<<dim3(Dc / 128, Mc / 128), 256, 0, stream>>>(
        o_core, owT, (float*)d_out, Mc, Dc, VDc, lin_all + 4096, NPRJ, Dc, NPRJ);
}

// Round 3
// 616.247 us; speedup vs baseline: 1.4967x; 1.0623x over previous
//
#include <hip/hip_runtime.h>

// ---------------- problem constants ----------------
#define Bc   4
#define Tc   2048
#define Dc   1024
#define Hc   16
#define DKc  64
#define DVc  128
#define QKDc 1024
#define VDc  2048
#define NPRJ 5120        // q|k|v|gate fused projection width
#define Mc   (Bc * Tc)   // 8192 tokens
#define CHUNK 64         // delta-rule chunk size
#define NCHK (Tc / CHUNK) // 32 chunks per (b,h)

typedef __bf16 bf16;
typedef __bf16 bf16x4 __attribute__((ext_vector_type(4)));
typedef __bf16 bf16x8 __attribute__((ext_vector_type(8)));
typedef float  f32x4  __attribute__((ext_vector_type(4)));

__device__ __forceinline__ float bf2f(bf16 v) { return (float)v; }
__device__ __forceinline__ bf16  f2bf(float v) { return (bf16)v; }
__device__ __forceinline__ float sigmoidf_(float x) { return 1.0f / (1.0f + __expf(-x)); }
__device__ __forceinline__ f32x4 mfma16(bf16x8 a, bf16x8 b, f32x4 c) {
    return __builtin_amdgcn_mfma_f32_16x16x32_bf16(a, b, c, 0, 0, 0);
}

// async global->LDS, 16B/lane; lds dest = wave-uniform base + lane*16
__device__ __forceinline__ void glds16(const bf16* g, void* l) {
    __builtin_amdgcn_global_load_lds((const __attribute__((address_space(1))) void*)g,
                                     (__attribute__((address_space(3))) void*)l, 16, 0, 0);
}

// XOR-swizzled addressing for [32][64] bf16 LDS tiles (bank-conflict-free b128
// column-slice reads; bijective within each row's 128B).
__device__ __forceinline__ bf16* swz32x64(bf16* base, int r, int k) {
    int byte = (((r << 6) + k) << 1) ^ ((r & 7) << 4);
    return (bf16*)((char*)base + byte);
}

// ---------------- cast fp32 -> bf16 ----------------
__global__ __launch_bounds__(256) void cast_f32_bf16(const float* __restrict__ src,
                                                     bf16* __restrict__ dst, int n4) {
    int i = blockIdx.x * 256 + threadIdx.x;
    if (i < n4) {
        float4 v = ((const float4*)src)[i];
        bf16x4 o = { f2bf(v.x), f2bf(v.y), f2bf(v.z), f2bf(v.w) };
        ((bf16x4*)dst)[i] = o;
    }
}

// ---------------- transpose + cast: fp32 [R][C] -> bf16 [C][R] ----------------
__global__ __launch_bounds__(256) void transpose_cast(const float* __restrict__ src,
                                                      bf16* __restrict__ dst,
                                                      int R, int C) {
    __shared__ float tile[32][33];
    int c0 = blockIdx.x * 32, r0 = blockIdx.y * 32;
    int tx = threadIdx.x, ty = threadIdx.y;
#pragma unroll
    for (int i = 0; i < 32; i += 8) {
        int r = r0 + ty + i, c = c0 + tx;
        tile[ty + i][tx] = (r < R && c < C) ? src[(size_t)r * C + c] : 0.0f;
    }
    __syncthreads();
#pragma unroll
    for (int i = 0; i < 32; i += 8) {
        int rr = c0 + ty + i, cc = r0 + tx;
        if (rr < C && cc < R) dst[(size_t)rr * R + cc] = f2bf(tile[tx][ty + i]);
    }
}

// ============ pipelined 256x256 GEMM: lin_all[M,5120] = xb[M,1024] @ W^T ============
// BK=32, ring of 4 K-tile LDS slots (A 16K + B 16K each = 128 KiB), 8 waves.
// Counted vmcnt: stage K-tile t+2 while computing t; vmcnt(4) at tile boundary
// keeps t+2's 4 loads in flight across the barrier (never drains to 0 in-loop).
// Ring-4 guarantees in-flight writes never target a slot being read.
// LDS XOR swizzle: physical 16B-slot = logical ^ (row&3); applied to global
// source (glds writes linearly) and to ds_read addressing (rule #21).
#define GP_NT 20          // N tiles (5120/256)
#define GP_MT 32          // M tiles (8192/256)
#define GP_NKT 32         // K tiles (1024/32)
__global__ __launch_bounds__(512) void gemm_pipe(const bf16* __restrict__ A,
                                                 const bf16* __restrict__ Bt,
                                                 bf16* __restrict__ C) {
    __shared__ __align__(16) char lds[131072];
    const int tid = threadIdx.x;
    const int wid = tid >> 6, lane = tid & 63;
    const int lm = lane & 15, lq = lane >> 4;
    const int wm = wid >> 2, wn = wid & 3;

    // bijective XCD swizzle (640 blocks, 640/8 = 80)
    const int id = blockIdx.x;
    const int nid = (id & 7) * ((GP_NT * GP_MT) / 8) + (id >> 3);
    const int tn = nid % GP_NT, tm = nid / GP_NT;
    const int n0 = tn * 256, m0 = tm * 256;

    // staging source addresses (per thread): chunk r*512+tid -> row r*128+(tid>>2),
    // physical slot tid&3 holds logical slot (tid&3)^(row&3)
    const int r0 = tid >> 2;
    const int lsx = ((tid & 3) ^ (r0 & 3)) << 3;
    const bf16* sA0 = A  + (size_t)(m0 + r0) * Dc + lsx;
    const bf16* sA1 = sA0 + (size_t)128 * Dc;
    const bf16* sB0 = Bt + (size_t)(n0 + r0) * Dc + lsx;
    const bf16* sB1 = sB0 + (size_t)128 * Dc;

    auto stageA = [&](int kt) {
        char* d = lds + ((kt & 3) << 15) + wid * 1024;
        glds16(sA0 + kt * 32, d);
        glds16(sA1 + kt * 32, d + 8192);
    };
    auto stageB = [&](int kt) {
        char* d = lds + ((kt & 3) << 15) + 16384 + wid * 1024;
        glds16(sB0 + kt * 32, d);
        glds16(sB1 + kt * 32, d + 8192);
    };

    f32x4 acc[8][4] = {};
    const int sx = (lq ^ (lm & 3)) << 3;          // swizzled K-slot for reads
    const int aoff = wm * 4096 + lm * 32 + sx;    // elem offset in A region
    const int boff = wn * 2048 + lm * 32 + sx;    // elem offset in B region

    stageA(0); stageB(0); stageA(1); stageB(1);
    asm volatile("s_waitcnt vmcnt(4)" ::: "memory");
    asm volatile("s_barrier" ::: "memory");

    for (int kt = 0; kt < GP_NKT; kt++) {
        const bf16* sA = (const bf16*)(lds + ((kt & 3) << 15));
        const bf16* sB = (const bf16*)(lds + ((kt & 3) << 15) + 16384);
        bf16x8 aF[4], bF[4], aG[4];
#pragma unroll
        for (int i = 0; i < 4; i++) aF[i] = *(const bf16x8*)&sA[aoff + i * 512];
#pragma unroll
        for (int j = 0; j < 4; j++) bF[j] = *(const bf16x8*)&sB[boff + j * 512];
        if (kt + 2 < GP_NKT) stageA(kt + 2);
        asm volatile("s_waitcnt lgkmcnt(0)" ::: "memory");
        __builtin_amdgcn_sched_barrier(0);
        __builtin_amdgcn_s_setprio(1);
#pragma unroll
        for (int i = 0; i < 4; i++)
#pragma unroll
            for (int j = 0; j < 4; j++)
                acc[i][j] = mfma16(aF[i], bF[j], acc[i][j]);
        __builtin_amdgcn_s_setprio(0);
#pragma unroll
        for (int i = 0; i < 4; i++) aG[i] = *(const bf16x8*)&sA[aoff + (i + 4) * 512];
        if (kt + 2 < GP_NKT) stageB(kt + 2);
        asm volatile("s_waitcnt lgkmcnt(0)" ::: "memory");
        __builtin_amdgcn_sched_barrier(0);
        __builtin_amdgcn_s_setprio(1);
#pragma unroll
        for (int i = 0; i < 4; i++)
#pragma unroll
            for (int j = 0; j < 4; j++)
                acc[i + 4][j] = mfma16(aG[i], bF[j], acc[i + 4][j]);
        __builtin_amdgcn_s_setprio(0);
        if (kt + 2 < GP_NKT) asm volatile("s_waitcnt vmcnt(4)" ::: "memory");
        else                 asm volatile("s_waitcnt vmcnt(0)" ::: "memory");
        asm volatile("s_barrier" ::: "memory");
    }

    const int rbase = m0 + wm * 128 + lq * 4;
    const int cbase = n0 + wn * 64 + lm;
#pragma unroll
    for (int i = 0; i < 8; i++)
#pragma unroll
        for (int j = 0; j < 4; j++)
#pragma unroll
            for (int rI = 0; rI < 4; rI++)
                C[(size_t)(rbase + i * 16 + rI) * NPRJ + cbase + j * 16] =
                    f2bf(acc[i][j][rI]);
}

// ---------------- GEMM: C[M,N] = A[M,K] @ Bt[N,K]^T, strided A/C/gate ----------------
template <typename OutT>
__global__ __launch_bounds__(256) void gemm_bt(const bf16* __restrict__ A,
                                               const bf16* __restrict__ Bt,
                                               OutT* __restrict__ C,
                                               int M, int N, int K,
                                               const bf16* __restrict__ gate,
                                               int lda, int ldc, int ldg) {
    __shared__ bf16 As[128 * 32];
    __shared__ bf16 Bs[128 * 32];

    const int n0 = blockIdx.x * 128;
    const int m0 = blockIdx.y * 128;
    const int t = threadIdx.x;
    const int wid = t >> 6, lane = t & 63;
    const int wm = (wid & 1) * 64;
    const int wn = (wid >> 1) * 64;

    f32x4 acc[4][4] = {};

    const int srow = lane >> 2;          // 0..15
    const int scol = (lane & 3) * 8;     // bf16 col offset
    char* AsB = (char*)As;
    char* BsB = (char*)Bs;

    for (int k0 = 0; k0 < K; k0 += 32) {
        glds16(&A[(size_t)(m0 + wid * 16 + srow) * lda + k0 + scol],       AsB + wid * 1024);
        glds16(&A[(size_t)(m0 + 64 + wid * 16 + srow) * lda + k0 + scol],  AsB + 4096 + wid * 1024);
        glds16(&Bt[(size_t)(n0 + wid * 16 + srow) * K + k0 + scol],        BsB + wid * 1024);
        glds16(&Bt[(size_t)(n0 + 64 + wid * 16 + srow) * K + k0 + scol],   BsB + 4096 + wid * 1024);
        __syncthreads();

        const int kh = (lane >> 4) * 8;
        const int lm = lane & 15;
        bf16x8 a[4], b[4];
#pragma unroll
        for (int i = 0; i < 4; i++) a[i] = *(const bf16x8*)&As[(wm + i * 16 + lm) * 32 + kh];
#pragma unroll
        for (int j = 0; j < 4; j++) b[j] = *(const bf16x8*)&Bs[(wn + j * 16 + lm) * 32 + kh];
#pragma unroll
        for (int i = 0; i < 4; i++)
#pragma unroll
            for (int j = 0; j < 4; j++)
                acc[i][j] = __builtin_amdgcn_mfma_f32_16x16x32_bf16(a[i], b[j], acc[i][j], 0, 0, 0);
        __syncthreads();
    }

    const int lm = lane & 15, lq = lane >> 4;
#pragma unroll
    for (int i = 0; i < 4; i++) {
#pragma unroll
        for (int j = 0; j < 4; j++) {
#pragma unroll
            for (int rI = 0; rI < 4; rI++) {
                int row = m0 + wm + i * 16 + lq * 4 + rI;
                int col = n0 + wn + j * 16 + lm;
                float val = acc[i][j][rI];
                if (gate) {
                    float g = bf2f(gate[(size_t)row * ldg + col]);
                    val *= sigmoidf_(g);
                }
                C[(size_t)row * ldc + col] = (OutT)val;
            }
        }
    }
}

// ---------------- zero-centered RMSNorm in place, strided rows ----------------
template <int L>
__global__ __launch_bounds__(256) void zc_rms_kernel(bf16* __restrict__ buf,
                                                     const float* __restrict__ scale,
                                                     int ld) {
    constexpr int NPT = L / 256;
    int row = blockIdx.x;
    int t = threadIdx.x;
    bf16* p = buf + (size_t)row * ld;

    float xv[NPT];
    float s = 0.f, s2 = 0.f;
#pragma unroll
    for (int i = 0; i < NPT; i++) {
        float x = bf2f(p[t + (i << 8)]);
        xv[i] = x;
        s += x;
        s2 += x * x;
    }
    __shared__ float red[2][4];
#pragma unroll
    for (int o = 32; o > 0; o >>= 1) {
        s += __shfl_down(s, o, 64);
        s2 += __shfl_down(s2, o, 64);
    }
    if ((t & 63) == 0) { red[0][t >> 6] = s; red[1][t >> 6] = s2; }
    __syncthreads();
    s  = red[0][0] + red[0][1] + red[0][2] + red[0][3];
    s2 = red[1][0] + red[1][1] + red[1][2] + red[1][3];

    float mean = s / (float)L;
    float var = s2 / (float)L - mean * mean;
    float inv = rsqrtf(var + 1e-5f);
#pragma unroll
    for (int i = 0; i < NPT; i++) {
        float y = (xv[i] - mean) * inv * scale[t + (i << 8)];
        p[t + (i << 8)] = f2bf(y);
    }
}

// ---------------- causal depthwise conv (K=4) + SiLU, strided in, compact out ----------------
__global__ __launch_bounds__(256) void conv_silu(const bf16* __restrict__ xn,
                                                 const float* __restrict__ kern,
                                                 const float* __restrict__ bias,
                                                 bf16* __restrict__ out,
                                                 int Cch, int ldin) {
    int btok = blockIdx.x;
    int tt = btok & (Tc - 1);
    for (int c = threadIdx.x; c < Cch; c += 256) {
        float acc = bias[c];
#pragma unroll
        for (int i = 0; i < 4; i++) {
            int ts = tt - 3 + i;
            if (ts >= 0)
                acc += bf2f(xn[(size_t)(btok - 3 + i) * ldin + c]) * kern[i * Cch + c];
        }
        float y = acc * sigmoidf_(acc);
        out[(size_t)btok * Cch + c] = f2bf(y);
    }
}

// ---------------- alpha/beta via MFMA: sigmoid(x @ [aw|bw]), hi/lo-split weights ----------------
// 64 blocks x 128 rows. Weights staged per K-tile (128) as hi/lo bf16 pairs ->
// f32-grade weight precision (products exact in bf16 MFMA, residual via lo term).
__global__ __launch_bounds__(256) void alphabeta_mfma(const bf16* __restrict__ x,
                                                      const float* __restrict__ aw,
                                                      const float* __restrict__ bw,
                                                      float* __restrict__ af,
                                                      float* __restrict__ bfv) {
    __shared__ bf16 whi[32][136];
    __shared__ bf16 wlo[32][136];
    const int tid = threadIdx.x, wave = tid >> 6, lane = tid & 63;
    const int lm = lane & 15, lq = lane >> 4;
    const int m0 = blockIdx.x * 128;
    f32x4 acc[2][2] = {};

    for (int k0 = 0; k0 < Dc; k0 += 128) {
        for (int idx = tid; idx < 4096; idx += 256) {
            int n = idx & 31, kk = idx >> 5;
            float v = (n < 16) ? aw[(size_t)(k0 + kk) * Hc + n]
                               : bw[(size_t)(k0 + kk) * Hc + (n - 16)];
            bf16 h = f2bf(v);
            whi[n][kk] = h;
            wlo[n][kk] = f2bf(v - bf2f(h));
        }
        __syncthreads();
#pragma unroll
        for (int ks = 0; ks < 4; ks++) {
            bf16x8 bh[2], bl[2];
#pragma unroll
            for (int j = 0; j < 2; j++) {
                bh[j] = *(const bf16x8*)&whi[j * 16 + lm][ks * 32 + lq * 8];
                bl[j] = *(const bf16x8*)&wlo[j * 16 + lm][ks * 32 + lq * 8];
            }
#pragma unroll
            for (int ii = 0; ii < 2; ii++) {
                int row = m0 + wave * 32 + ii * 16 + lm;
                bf16x8 a = *(const bf16x8*)&x[(size_t)row * Dc + k0 + ks * 32 + lq * 8];
#pragma unroll
                for (int j = 0; j < 2; j++) {
                    acc[ii][j] = mfma16(a, bh[j], acc[ii][j]);
                    acc[ii][j] = mfma16(a, bl[j], acc[ii][j]);
                }
            }
        }
        __syncthreads();
    }
#pragma unroll
    for (int ii = 0; ii < 2; ii++)
#pragma unroll
        for (int rI = 0; rI < 4; rI++) {
            int row = m0 + wave * 32 + ii * 16 + lq * 4 + rI;
            af[(size_t)row * Hc + lm]  = sigmoidf_(acc[ii][0][rI]);
            bfv[(size_t)row * Hc + lm] = sigmoidf_(acc[ii][1][rI]);
        }
}

// ================= chunked gated delta rule =================
// Chunk (C=64) closed form with gamma_i = prod_{s<=i} a_s:
//   A_ij = b_i (g_i/g_j) k_i.k_j (j<i);  (I+A) U = diag(b)V - diag(b g) K S0
//   U = Uv - W S0,  Uv = T diag(b)V,  W = T diag(b g)K,  T = (I+A)^-1
//   O  = diag(g) Q S0 + M U,  M_ij = (g_i/g_j) q_i.k_j (j<=i)
//   S' = g_C S0 + Kbar^T U,   Kbar_j = (g_C/g_j) k_j
// T via BLOCKED inversion (round-1 lesson: 64-step solve was a 1-wave ~23K-cycle
// chain): 4 diagonal 16x16 register inverses + MFMA off-diagonal combines with
// bf16 hi/lo split (~f32 accuracy).
__global__ __launch_bounds__(256) void prep(bf16* __restrict__ qf,
                                            bf16* __restrict__ kf,
                                            bf16* __restrict__ vc,
                                            const float* __restrict__ af,
                                            const float* __restrict__ bfv,
                                            bf16* __restrict__ Wb,
                                            bf16* __restrict__ Mb,
                                            float* __restrict__ gamC) {
    __shared__ __align__(16) char smem[53248];
    bf16*  Kc   = (bf16*)(smem);             // [64][72] bf16, live whole kernel
    bf16*  Qc   = (bf16*)(smem + 9216);      // [64][72] bf16 (phase B only)
    float* DT   = (float*)(smem + 9216);     // [4][16][17] f32: I_g^T (solve)
    float* Pn   = (float*)(smem + 13568);    // [2][16][17] f32: -P^T pair L/H
    float* TT   = (float*)(smem + 15744);    // [16][17] f32: T10^T
    float* Qn   = (float*)(smem + 9216);     // [32][33] f32 (overlays DT, s3+)
    bf16*  Tb   = (bf16*)(smem + 9216);      // [64][72] bf16 T (after s4)
    float* As   = (float*)(smem + 18432);    // [64][65] f32
    bf16*  Vtb  = (bf16*)(smem + 18432);     // [128][72] bf16 (after Tb copy)
    float* Ts   = (float*)(smem + 35072);    // [64][65] f32
    float* lg_s = (float*)(smem + 51712);    // 64 log2-cumsum
    float* bv_s = lg_s + 64;                 // b_i
    float* bg_s = lg_s + 128;                // b_i * g_i
    float* gm_s = lg_s + 192;                // g_i
    float* kr_s = lg_s + 256;                // g_C / g_i

    const int c    = blockIdx.x;
    const int bh   = blockIdx.y;
    const int b    = bh >> 4, h = bh & 15;
    const int ch   = bh * NCHK + c;
    const int tok0 = b * Tc + c * CHUNK;
    const int tid  = threadIdx.x;
    const int wave = tid >> 6, lane = tid & 63;
    const int lm = lane & 15, lq = lane >> 4, kh = lq * 8;

    // ---- phase A: stage K,Q; zero Ts (upper blocks are never written); ab prefix
#pragma unroll
    for (int r = 0; r < 2; r++) {
        int idx = tid + r * 256;
        int row = idx >> 3, c8 = (idx & 7) * 8;
        *(bf16x8*)&Kc[row * 72 + c8] =
            *(const bf16x8*)&kf[(size_t)(tok0 + row) * QKDc + h * DKc + c8];
        *(bf16x8*)&Qc[row * 72 + c8] =
            *(const bf16x8*)&qf[(size_t)(tok0 + row) * QKDc + h * DKc + c8];
    }
    for (int idx = tid; idx < 64 * 65; idx += 256) Ts[idx] = 0.f;
    if (tid < 64) {
        float a  = af[(size_t)(tok0 + tid) * Hc + h];
        float bb = bfv[(size_t)(tok0 + tid) * Hc + h];
        float la = __log2f(fmaxf(a, 1e-30f));
#pragma unroll
        for (int o = 1; o < 64; o <<= 1) {       // inclusive prefix sum
            float t = __shfl_up(la, o, 64);
            if (tid >= o) la += t;
        }
        float lgC = __shfl(la, 63, 64);
        lg_s[tid] = la;
        bv_s[tid] = bb;
        float g   = exp2f(la);
        gm_s[tid] = g;
        bg_s[tid] = bb * g;
        kr_s[tid] = exp2f(lgC - la);
        if (tid == 0) gamC[ch] = exp2f(lgC);
    }
    __syncthreads();

    // ---- phase B: KK^T -> A; QK^T -> M; Qtilde/KbarT global writes
    {
        bf16x8 ka[2], qa[2];
#pragma unroll
        for (int s = 0; s < 2; s++) {
            ka[s] = *(const bf16x8*)&Kc[(16 * wave + lm) * 72 + s * 32 + kh];
            qa[s] = *(const bf16x8*)&Qc[(16 * wave + lm) * 72 + s * 32 + kh];
        }
#pragma unroll
        for (int jt = 0; jt < 4; jt++) {
            f32x4 kkacc = {}, qkacc = {};
#pragma unroll
            for (int s = 0; s < 2; s++) {
                bf16x8 kbf = *(const bf16x8*)&Kc[(16 * jt + lm) * 72 + s * 32 + kh];
                kkacc = mfma16(ka[s], kbf, kkacc);
                qkacc = mfma16(qa[s], kbf, qkacc);
            }
#pragma unroll
            for (int rI = 0; rI < 4; rI++) {
                int i = 16 * wave + lq * 4 + rI;
                int j = 16 * jt + lm;
                float ratio = exp2f(lg_s[i] - lg_s[j]);
                As[i * 65 + j] = (j < i) ? bv_s[i] * ratio * kkacc[rI] : 0.f;
                Mb[((size_t)ch * 64 + i) * 64 + j] =
                    (j <= i) ? f2bf(ratio * qkacc[rI]) : f2bf(0.f);
            }
        }
    }
    {   // Qtilde -> qf (in place); KbarT -> kf (in place, transposed [d][j])
#pragma unroll
        for (int r = 0; r < 2; r++) {
            int idx = tid + r * 256;
            int row = idx >> 3, c8 = (idx & 7) * 8;
            bf16x8 v = *(const bf16x8*)&Qc[row * 72 + c8];
            float g = gm_s[row];
            bf16x8 oq;
#pragma unroll
            for (int e = 0; e < 8; e++) oq[e] = f2bf(bf2f(v[e]) * g);
            *(bf16x8*)&qf[(size_t)(tok0 + row) * QKDc + h * DKc + c8] = oq;
            bf16x8 ok;
#pragma unroll
            for (int e = 0; e < 8; e++)
                ok[e] = f2bf(kr_s[c8 + e] * bf2f(Kc[(c8 + e) * 72 + row]));
            *(bf16x8*)&kf[(size_t)(tok0 + row) * QKDc + h * DKc + c8] = ok;
        }
    }
    __syncthreads();   // As complete; Qc dead -> DT/Pn/TT scratch usable

    // ---- phase C: 4 diagonal 16x16 inverses in registers (wave 0) ----
    if (tid < 64) {
        const int g = lane >> 4, jj = lane & 15, base = lane & 48;
        float areg[16], tcol[16];
#pragma unroll
        for (int i = 0; i < 16; i++) areg[i] = As[(16 * g + i) * 65 + 16 * g + jj];
#pragma unroll
        for (int i = 0; i < 16; i++) tcol[i] = (i == jj) ? 1.f : 0.f;
#pragma unroll
        for (int i = 1; i < 16; i++) {
            float s = 0.f;
#pragma unroll
            for (int m = 0; m < i; m++)
                s = fmaf(__shfl(areg[i], base + m, 64), tcol[m], s);
            tcol[i] = (i == jj) ? 1.f : -s;
        }
#pragma unroll
        for (int i = 0; i < 16; i++) {
            Ts[(16 * g + i) * 65 + 16 * g + jj] = tcol[i];   // I_g row-major
            DT[g * 272 + jj * 17 + i] = tcol[i];             // I_g^T row-major
        }
    }
    __syncthreads();

    // ---- s1: Pn = -(I_{2w}^T * A_off^T), pairs L(w=0): A10, H(w=1): A32. K=16
    if (wave < 2) {
        const int w = wave;
        bf16x8 ah, al, bh, bl;
#pragma unroll
        for (int e = 0; e < 8; e++) {
            int k = kh + e;
            float xa = (k < 16) ? DT[2 * w * 272 + lm * 17 + k] : 0.f;
            bf16 ha = f2bf(xa); ah[e] = ha; al[e] = f2bf(xa - bf2f(ha));
            float xb = (k < 16) ? As[(16 + 32 * w + lm) * 65 + 32 * w + k] : 0.f;
            bf16 hb = f2bf(xb); bh[e] = hb; bl[e] = f2bf(xb - bf2f(hb));
        }
        f32x4 acc = {};
        acc = mfma16(ah, bh, acc); acc = mfma16(ah, bl, acc); acc = mfma16(al, bh, acc);
#pragma unroll
        for (int rI = 0; rI < 4; rI++)
            Pn[w * 272 + (lq * 4 + rI) * 17 + lm] = -acc[rI];
    }
    __syncthreads();

    // ---- s2: T10 -> Ts[16:32,0:16]; T10^T -> TT; T32 -> Ts[48:64,32:48]. K=16
    if (wave < 3) {
        bf16x8 ah, al, bh, bl;
#pragma unroll
        for (int e = 0; e < 8; e++) {
            int k = kh + e;
            float xa = 0.f, xb = 0.f;
            if (k < 16) {
                if (wave == 0)      { xa = Ts[(16 + lm) * 65 + 16 + k]; xb = Pn[lm * 17 + k]; }
                else if (wave == 1) { xa = Pn[lm * 17 + k];             xb = Ts[(16 + lm) * 65 + 16 + k]; }
                else                { xa = Ts[(48 + lm) * 65 + 48 + k]; xb = Pn[272 + lm * 17 + k]; }
            }
            bf16 ha = f2bf(xa); ah[e] = ha; al[e] = f2bf(xa - bf2f(ha));
            bf16 hb = f2bf(xb); bh[e] = hb; bl[e] = f2bf(xb - bf2f(hb));
        }
        f32x4 acc = {};
        acc = mfma16(ah, bh, acc); acc = mfma16(ah, bl, acc); acc = mfma16(al, bh, acc);
#pragma unroll
        for (int rI = 0; rI < 4; rI++) {
            int ro = lq * 4 + rI;
            if (wave == 0)      Ts[(16 + ro) * 65 + lm]      = acc[rI];
            else if (wave == 1) TT[ro * 17 + lm]             = acc[rI];
            else                Ts[(48 + ro) * 65 + 32 + lm] = acc[rI];
        }
    }
    __syncthreads();

    // ---- s3: Qn = -(iL1^T * A_BL^T), 32x32, K=32; tile (a,b) per wave.
    {
        const int a = wave >> 1, bq = wave & 1;
        bf16x8 ah, al, bh, bl;
#pragma unroll
        for (int e = 0; e < 8; e++) {
            int k = kh + e;  // 0..31
            float xa;
            if (a == 0) xa = (k < 16) ? DT[lm * 17 + k] : TT[lm * 17 + (k - 16)];
            else        xa = (k < 16) ? 0.f : DT[272 + lm * 17 + (k - 16)];
            bf16 ha = f2bf(xa); ah[e] = ha; al[e] = f2bf(xa - bf2f(ha));
            float xb = As[(32 + 16 * bq + lm) * 65 + k];
            bf16 hb = f2bf(xb); bh[e] = hb; bl[e] = f2bf(xb - bf2f(hb));
        }
        f32x4 acc = {};
        acc = mfma16(ah, bh, acc); acc = mfma16(ah, bl, acc); acc = mfma16(al, bh, acc);
        __syncthreads();   // all DT/TT reads done before Qn overlays DT
#pragma unroll
        for (int rI = 0; rI < 4; rI++)
            Qn[(16 * a + lq * 4 + rI) * 33 + 16 * bq + lm] = -acc[rI];
    }
    __syncthreads();

    // ---- s4: T_BL = mfma(R(iL2), R(Qn)) -> Ts[32:64, 0:32]. K=32
    {
        const int a = wave >> 1, bq = wave & 1;
        bf16x8 ah, al, bh, bl;
#pragma unroll
        for (int e = 0; e < 8; e++) {
            int k = kh + e;  // 0..31
            float xa = Ts[(32 + 16 * a + lm) * 65 + 32 + k];
            bf16 ha = f2bf(xa); ah[e] = ha; al[e] = f2bf(xa - bf2f(ha));
            float xb = Qn[(16 * bq + lm) * 33 + k];
            bf16 hb = f2bf(xb); bh[e] = hb; bl[e] = f2bf(xb - bf2f(hb));
        }
        f32x4 acc = {};
        acc = mfma16(ah, bh, acc); acc = mfma16(ah, bl, acc); acc = mfma16(al, bh, acc);
#pragma unroll
        for (int rI = 0; rI < 4; rI++)
            Ts[(32 + 16 * a + lq * 4 + rI) * 65 + 16 * bq + lm] = acc[rI];
    }
    __syncthreads();

    // ---- Tb = bf16(Ts) into Qc region (solve scratch dead) ----
    for (int idx = tid; idx < 4096; idx += 256) {
        int i = idx >> 6, j = idx & 63;
        Tb[i * 72 + j] = f2bf(Ts[i * 65 + j]);
    }
    __syncthreads();                      // Ts dead; Vtb may overlay As/Ts-head
#pragma unroll
    for (int r = 0; r < 4; r++) {         // Vtb = (diag(b) V)^T  [128][72]
        int idx = tid + r * 256;
        int j = idx >> 4, c8 = (idx & 15) * 8;
        bf16x8 v = *(const bf16x8*)&vc[(size_t)(tok0 + j) * VDc + h * DVc + c8];
        float bb = bv_s[j];
#pragma unroll
        for (int e = 0; e < 8; e++)
            Vtb[(c8 + e) * 72 + j] = f2bf(bf2f(v[e]) * bb);
    }
    __syncthreads();
    {   // W = T diag(b g) K -> Wb;  Uv = T diag(b) V -> vc (in place)
        bf16x8 ta[2];
#pragma unroll
        for (int s = 0; s < 2; s++)
            ta[s] = *(const bf16x8*)&Tb[(16 * wave + lm) * 72 + s * 32 + kh];
#pragma unroll
        for (int dt = 0; dt < 4; dt++) {
            f32x4 wacc = {};
#pragma unroll
            for (int s = 0; s < 2; s++) {
                bf16x8 wbf;
                int d = 16 * dt + lm;
#pragma unroll
                for (int e = 0; e < 8; e++) {
                    int j = s * 32 + kh + e;
                    wbf[e] = f2bf(bg_s[j] * bf2f(Kc[j * 72 + d]));
                }
                wacc = mfma16(ta[s], wbf, wacc);
            }
#pragma unroll
            for (int rI = 0; rI < 4; rI++) {
                int i = 16 * wave + lq * 4 + rI;
                Wb[((size_t)ch * 64 + i) * 64 + 16 * dt + lm] = f2bf(wacc[rI]);
            }
        }
#pragma unroll
        for (int dt = 0; dt < 8; dt++) {
            f32x4 uacc = {};
#pragma unroll
            for (int s = 0; s < 2; s++) {
                bf16x8 vb = *(const bf16x8*)&Vtb[(16 * dt + lm) * 72 + s * 32 + kh];
                uacc = mfma16(ta[s], vb, uacc);
            }
#pragma unroll
            for (int rI = 0; rI < 4; rI++) {
                int i = 16 * wave + lq * 4 + rI;
                vc[(size_t)(tok0 + i) * VDc + h * DVc + 16 * dt + lm] = f2bf(uacc[rI]);
            }
        }
    }
}

// Sequential part: 32 chunk steps per (b,h), dv split 4 ways -> grid (4,64).
__global__ __launch_bounds__(256) void chunkloop(const bf16* __restrict__ qf,
                                                 const bf16* __restrict__ kf,
                                                 const bf16* __restrict__ vc,
                                                 const bf16* __restrict__ Wb,
                                                 const bf16* __restrict__ Mb,
                                                 const float* __restrict__ gamC,
                                                 bf16* __restrict__ o, int ldo) {
    const int vg = blockIdx.x;           // dv slice of 32
    const int bh = blockIdx.y;
    const int b = bh >> 4, h = bh & 15;
    const int tid = threadIdx.x;
    const int wave = tid >> 6, lane = tid & 63;
    const int lm = lane & 15, lq = lane >> 4, kh = lq * 8;

    __shared__ __align__(16) bf16 SbBuf[32 * 64];   // S^T shadow [dv][dk]
    __shared__ __align__(16) bf16 UtBuf[32 * 64];   // U^T [dv][t]

    for (int idx = tid; idx < 32 * 64; idx += 256) SbBuf[idx] = f2bf(0.f);

    f32x4 Sacc[2] = {};                  // wave's dk-tile = wave; dv tiles 0,1

    const int colK = h * DKc;
    const int colV = h * DVc + vg * 32;

    bf16x8 wa[2], qa[2], ma[2], kb[2];
    bf16 uvv[2][4];

    auto loadFrags = [&](int c, bf16x8 (&wa_)[2], bf16x8 (&qa_)[2], bf16x8 (&ma_)[2],
                         bf16x8 (&kb_)[2], bf16 (&uvv_)[2][4]) {
        const int tok0 = b * Tc + c * CHUNK;
        const size_t chb = ((size_t)bh * NCHK + c) * 64;
#pragma unroll
        for (int s = 0; s < 2; s++) {
            wa_[s] = *(const bf16x8*)&Wb[(chb + 16 * wave + lm) * 64 + s * 32 + kh];
            ma_[s] = *(const bf16x8*)&Mb[(chb + 16 * wave + lm) * 64 + s * 32 + kh];
            qa_[s] = *(const bf16x8*)&qf[(size_t)(tok0 + 16 * wave + lm) * QKDc + colK + s * 32 + kh];
            kb_[s] = *(const bf16x8*)&kf[(size_t)(tok0 + 16 * wave + lm) * QKDc + colK + s * 32 + kh];
        }
#pragma unroll
        for (int dt = 0; dt < 2; dt++)
#pragma unroll
            for (int rI = 0; rI < 4; rI++)
                uvv_[dt][rI] =
                    vc[(size_t)(tok0 + 16 * wave + lq * 4 + rI) * VDc + colV + 16 * dt + lm];
    };

    loadFrags(0, wa, qa, ma, kb, uvv);
    __syncthreads();

    for (int c = 0; c < NCHK; c++) {
        const float gC = gamC[(size_t)bh * NCHK + c];
        bf16x8 sf[2][2];
#pragma unroll
        for (int dt = 0; dt < 2; dt++)
#pragma unroll
            for (int s = 0; s < 2; s++)
                sf[dt][s] = *(const bf16x8*)swz32x64(SbBuf, 16 * dt + lm, s * 32 + kh);
        // m1: P = W * S0
        f32x4 pacc[2] = {};
#pragma unroll
        for (int dt = 0; dt < 2; dt++)
#pragma unroll
            for (int s = 0; s < 2; s++)
                pacc[dt] = mfma16(wa[s], sf[dt][s], pacc[dt]);

        // prefetch next chunk's fragments (global only)
        bf16x8 wa2[2], qa2[2], ma2[2], kb2[2];
        bf16 uvv2[2][4];
        if (c + 1 < NCHK) loadFrags(c + 1, wa2, qa2, ma2, kb2, uvv2);

        // U = Uv - P  -> Ut (transposed, swizzled)
#pragma unroll
        for (int dt = 0; dt < 2; dt++)
#pragma unroll
            for (int rI = 0; rI < 4; rI++) {
                float u = bf2f(uvv[dt][rI]) - pacc[dt][rI];
                *swz32x64(UtBuf, 16 * dt + lm, 16 * wave + lq * 4 + rI) = f2bf(u);
            }
        __syncthreads();   // publish Ut

        bf16x8 uf[2][2];
#pragma unroll
        for (int dt = 0; dt < 2; dt++)
#pragma unroll
            for (int s = 0; s < 2; s++)
                uf[dt][s] = *(const bf16x8*)swz32x64(UtBuf, 16 * dt + lm, s * 32 + kh);

        // m2: O = Qt*S0 + M*U  -> global (strided o_core)
        f32x4 oacc[2] = {};
#pragma unroll
        for (int dt = 0; dt < 2; dt++)
#pragma unroll
            for (int s = 0; s < 2; s++) {
                oacc[dt] = mfma16(qa[s], sf[dt][s], oacc[dt]);
                oacc[dt] = mfma16(ma[s], uf[dt][s], oacc[dt]);
            }
        {
            const int tok0 = b * Tc + c * CHUNK;
#pragma unroll
            for (int dt = 0; dt < 2; dt++)
#pragma unroll
                for (int rI = 0; rI < 4; rI++)
                    o[(size_t)(tok0 + 16 * wave + lq * 4 + rI) * ldo + colV + 16 * dt + lm] =
                        f2bf(oacc[dt][rI]);
        }
        // m3: S = gC*S + U^T * Kbar  (f32 accumulators, wave's dk-tile)
#pragma unroll
        for (int dt = 0; dt < 2; dt++) {
#pragma unroll
            for (int e = 0; e < 4; e++) Sacc[dt][e] *= gC;
#pragma unroll
            for (int s = 0; s < 2; s++)
                Sacc[dt] = mfma16(uf[dt][s], kb[s], Sacc[dt]);
        }
        __syncthreads();   // all Sb/Ut reads done before shadow overwrite
#pragma unroll
        for (int dt = 0; dt < 2; dt++)
#pragma unroll
            for (int rI = 0; rI < 4; rI++)
                *swz32x64(SbBuf, 16 * dt + lq * 4 + rI, 16 * wave + lm) = f2bf(Sacc[dt][rI]);
        __syncthreads();   // publish S shadow

        if (c + 1 < NCHK) {
#pragma unroll
            for (int s = 0; s < 2; s++) { wa[s] = wa2[s]; qa[s] = qa2[s]; ma[s] = ma2[s]; kb[s] = kb2[s]; }
#pragma unroll
            for (int dt = 0; dt < 2; dt++)
#pragma unroll
                for (int rI = 0; rI < 4; rI++) uvv[dt][rI] = uvv2[dt][rI];
        }
    }
}

// ---------------- host launch ----------------
extern "C" void kernel_launch(void* const* d_in, const int* in_sizes, int n_in,
                              void* d_out, int out_size, void* d_ws, size_t ws_size,
                              hipStream_t stream) {
    const float* x        = (const float*)d_in[0];
    const float* q_w      = (const float*)d_in[1];
    const float* k_w      = (const float*)d_in[2];
    const float* v_w      = (const float*)d_in[3];
    const float* q_scale  = (const float*)d_in[4];
    const float* k_scale  = (const float*)d_in[5];
    const float* v_scale  = (const float*)d_in[6];
    const float* q_conv_k = (const float*)d_in[7];
    const float* q_conv_b = (const float*)d_in[8];
    const float* k_conv_k = (const float*)d_in[9];
    const float* k_conv_b = (const float*)d_in[10];
    const float* v_conv_k = (const float*)d_in[11];
    const float* v_conv_b = (const float*)d_in[12];
    const float* alpha_w  = (const float*)d_in[13];
    const float* beta_w   = (const float*)d_in[14];
    const float* out_w    = (const float*)d_in[15];
    const float* gate_w   = (const float*)d_in[16];

    // ---- workspace (~208 MB) ----
    char* w = (char*)d_ws;
    bf16* xb  = (bf16*)w; w += (size_t)Mc * Dc * 2;          // 16 MB
    bf16* qwT = (bf16*)w; w += (size_t)QKDc * Dc * 2;        //  2 MB  -- qwT|kwT|vwT|gwT
    bf16* kwT = (bf16*)w; w += (size_t)QKDc * Dc * 2;        //  2 MB     contiguous =
    bf16* vwT = (bf16*)w; w += (size_t)VDc * Dc * 2;         //  4 MB     [5120][1024]
    bf16* gwT = (bf16*)w; w += (size_t)Dc * Dc * 2;          //  2 MB
    bf16* owT = (bf16*)w; w += (size_t)Dc * VDc * 2;         //  4 MB
    bf16* lin_all = (bf16*)w; w += (size_t)Mc * NPRJ * 2;    // 80 MB  [M][5120] q|k|v|g
    bf16* qf = (bf16*)w; w += (size_t)Mc * QKDc * 2;         // 16 MB  (conv q -> Qtilde)
    bf16* kf = (bf16*)w; w += (size_t)Mc * QKDc * 2;         // 16 MB  (conv k -> KbarT)
    bf16* vc = (bf16*)w; w += (size_t)Mc * VDc * 2;          // 32 MB  (conv v -> Uv)
    float* af = (float*)w; w += (size_t)Mc * Hc * 4;
    float* bfv = (float*)w; w += (size_t)Mc * Hc * 4;
    const int NCH_TOT = Bc * Hc * NCHK;                      // 2048 chunk-heads
    bf16* Wb = (bf16*)w; w += (size_t)NCH_TOT * 64 * 64 * 2; // 16 MB
    bf16* Mb = (bf16*)w; w += (size_t)NCH_TOT * 64 * 64 * 2; // 16 MB
    float* gamC = (float*)w; w += (size_t)NCH_TOT * 4;       //  8 KB
    // scan output goes into lin_all cols 0:2048 (q|k sections, dead after convs)
    bf16* o_core = lin_all;

    dim3 tb(32, 8);
    cast_f32_bf16<<<(Mc * Dc / 4 + 255) / 256, 256, 0, stream>>>(x, xb, Mc * Dc / 4);
    transpose_cast<<<dim3(QKDc / 32, Dc / 32), tb, 0, stream>>>(q_w, qwT, Dc, QKDc);
    transpose_cast<<<dim3(QKDc / 32, Dc / 32), tb, 0, stream>>>(k_w, kwT, Dc, QKDc);
    transpose_cast<<<dim3(VDc / 32, Dc / 32), tb, 0, stream>>>(v_w, vwT, Dc, VDc);
    transpose_cast<<<dim3(Dc / 32, Dc / 32), tb, 0, stream>>>(gate_w, gwT, Dc, Dc);
    transpose_cast<<<dim3(Dc / 32, VDc / 32), tb, 0, stream>>>(out_w, owT, VDc, Dc);

    // fused q|k|v|gate projection: pipelined 256x256 GEMM, counted-vmcnt ring
    gemm_pipe<<<GP_NT * GP_MT, 512, 0, stream>>>(xb, qwT, lin_all);

    // norms (strided rows inside lin_all)
    zc_rms_kernel<QKDc><<<Mc, 256, 0, stream>>>(lin_all,        q_scale, NPRJ);
    zc_rms_kernel<QKDc><<<Mc, 256, 0, stream>>>(lin_all + 1024, k_scale, NPRJ);
    zc_rms_kernel<VDc><<<Mc, 256, 0, stream>>>(lin_all + 2048,  v_scale, NPRJ);

    // convs: strided in, compact bf16 out
    conv_silu<<<Mc, 256, 0, stream>>>(lin_all,        q_conv_k, q_conv_b, qf, QKDc, NPRJ);
    conv_silu<<<Mc, 256, 0, stream>>>(lin_all + 1024, k_conv_k, k_conv_b, kf, QKDc, NPRJ);
    conv_silu<<<Mc, 256, 0, stream>>>(lin_all + 2048, v_conv_k, v_conv_b, vc, VDc, NPRJ);

    // alpha/beta via MFMA (hi/lo-split weights, f32-grade)
    alphabeta_mfma<<<Mc / 128, 256, 0, stream>>>(xb, alpha_w, beta_w, af, bfv);

    // chunked delta rule: parallel prep (per chunk-head), then 32-deep MFMA scan
    prep<<<dim3(NCHK, Bc * Hc), 256, 0, stream>>>(qf, kf, vc, af, bfv, Wb, Mb, gamC);
    chunkloop<<<dim3(4, Bc * Hc), 256, 0, stream>>>(qf, kf, vc, Wb, Mb, gamC, o_core, NPRJ);

    // out-projection (A = o_core strided in lin_all) + fused sigmoid gate (cols 4096:5120)
    gemm_bt<float><<<dim3(Dc / 128, Mc / 128), 256, 0, stream>>>(
        o_core, owT, (float*)d_out, Mc, Dc, VDc, lin_all + 4096, NPRJ, Dc, NPRJ);
}

// Round 4
// 562.591 us; speedup vs baseline: 1.6395x; 1.0954x over previous
//
#include <hip/hip_runtime.h>

// ---------------- problem constants ----------------
#define Bc   4
#define Tc   2048
#define Dc   1024
#define Hc   16
#define DKc  64
#define DVc  128
#define QKDc 1024
#define VDc  2048
#define NPRJ 5120        // q|k|v|gate fused projection width
#define Mc   (Bc * Tc)   // 8192 tokens
#define CHUNK 64         // delta-rule chunk size
#define NCHK (Tc / CHUNK) // 32 chunks per (b,h)

typedef __bf16 bf16;
typedef __bf16 bf16x4 __attribute__((ext_vector_type(4)));
typedef __bf16 bf16x8 __attribute__((ext_vector_type(8)));
typedef float  f32x4  __attribute__((ext_vector_type(4)));

__device__ __forceinline__ float bf2f(bf16 v) { return (float)v; }
__device__ __forceinline__ bf16  f2bf(float v) { return (bf16)v; }
__device__ __forceinline__ float sigmoidf_(float x) { return 1.0f / (1.0f + __expf(-x)); }
__device__ __forceinline__ f32x4 mfma16(bf16x8 a, bf16x8 b, f32x4 c) {
    return __builtin_amdgcn_mfma_f32_16x16x32_bf16(a, b, c, 0, 0, 0);
}

// async global->LDS, 16B/lane; lds dest = wave-uniform base + lane*16
__device__ __forceinline__ void glds16(const bf16* g, void* l) {
    __builtin_amdgcn_global_load_lds((const __attribute__((address_space(1))) void*)g,
                                     (__attribute__((address_space(3))) void*)l, 16, 0, 0);
}

// XOR-swizzled addressing for [32][64] bf16 LDS tiles (bank-conflict-free b128
// column-slice reads; bijective within each row's 128B).
__device__ __forceinline__ bf16* swz32x64(bf16* base, int r, int k) {
    int byte = (((r << 6) + k) << 1) ^ ((r & 7) << 4);
    return (bf16*)((char*)base + byte);
}

// ---------------- cast fp32 -> bf16 ----------------
__global__ __launch_bounds__(256) void cast_f32_bf16(const float* __restrict__ src,
                                                     bf16* __restrict__ dst, int n4) {
    int i = blockIdx.x * 256 + threadIdx.x;
    if (i < n4) {
        float4 v = ((const float4*)src)[i];
        bf16x4 o = { f2bf(v.x), f2bf(v.y), f2bf(v.z), f2bf(v.w) };
        ((bf16x4*)dst)[i] = o;
    }
}

// ---------------- transpose + cast: fp32 [R][C] -> bf16 [C][R] ----------------
__global__ __launch_bounds__(256) void transpose_cast(const float* __restrict__ src,
                                                      bf16* __restrict__ dst,
                                                      int R, int C) {
    __shared__ float tile[32][33];
    int c0 = blockIdx.x * 32, r0 = blockIdx.y * 32;
    int tx = threadIdx.x, ty = threadIdx.y;
#pragma unroll
    for (int i = 0; i < 32; i += 8) {
        int r = r0 + ty + i, c = c0 + tx;
        tile[ty + i][tx] = (r < R && c < C) ? src[(size_t)r * C + c] : 0.0f;
    }
    __syncthreads();
#pragma unroll
    for (int i = 0; i < 32; i += 8) {
        int rr = c0 + ty + i, cc = r0 + tx;
        if (rr < C && cc < R) dst[(size_t)rr * R + cc] = f2bf(tile[tx][ty + i]);
    }
}

// ============ pipelined 256x256 GEMM: lin_all[M,5120] = xb[M,1024] @ W^T ============
// BK=32, ring of 4 K-tile LDS slots (A 16K + B 16K each = 128 KiB), 8 waves.
// Counted vmcnt: stage K-tile t+2 while computing t; vmcnt(4) at tile boundary
// keeps t+2's 4 loads in flight across the barrier (never drains to 0 in-loop).
// Ring-4 guarantees in-flight writes never target a slot being read.
// Round-3: fine 2-phase interleave per K-tile (T3): each phase = {ds_read
// subtile, stage 1 half, barrier, lgkmcnt(0), setprio(1), 16 MFMA, setprio(0),
// barrier} -- the per-phase wave role-split is what makes setprio pay (m218b).
#define GP_NT 20          // N tiles (5120/256)
#define GP_MT 32          // M tiles (8192/256)
#define GP_NKT 32         // K tiles (1024/32)
__global__ __launch_bounds__(512, 2) void gemm_pipe(const bf16* __restrict__ A,
                                                    const bf16* __restrict__ Bt,
                                                    bf16* __restrict__ C) {
    __shared__ __align__(16) char lds[131072];
    const int tid = threadIdx.x;
    const int wid = tid >> 6, lane = tid & 63;
    const int lm = lane & 15, lq = lane >> 4;
    const int wm = wid >> 2, wn = wid & 3;

    // bijective XCD swizzle (640 blocks, 640/8 = 80)
    const int id = blockIdx.x;
    const int nid = (id & 7) * ((GP_NT * GP_MT) / 8) + (id >> 3);
    const int tn = nid % GP_NT, tm = nid / GP_NT;
    const int n0 = tn * 256, m0 = tm * 256;

    // staging source addresses (per thread): chunk r*512+tid -> row r*128+(tid>>2),
    // physical slot tid&3 holds logical slot (tid&3)^(row&3)
    const int r0 = tid >> 2;
    const int lsx = ((tid & 3) ^ (r0 & 3)) << 3;
    const bf16* sA0 = A  + (size_t)(m0 + r0) * Dc + lsx;
    const bf16* sA1 = sA0 + (size_t)128 * Dc;
    const bf16* sB0 = Bt + (size_t)(n0 + r0) * Dc + lsx;
    const bf16* sB1 = sB0 + (size_t)128 * Dc;

    auto stageA = [&](int kt) {
        char* d = lds + ((kt & 3) << 15) + wid * 1024;
        glds16(sA0 + kt * 32, d);
        glds16(sA1 + kt * 32, d + 8192);
    };
    auto stageB = [&](int kt) {
        char* d = lds + ((kt & 3) << 15) + 16384 + wid * 1024;
        glds16(sB0 + kt * 32, d);
        glds16(sB1 + kt * 32, d + 8192);
    };

    f32x4 acc[8][4] = {};
    const int sx = (lq ^ (lm & 3)) << 3;          // swizzled K-slot for reads
    const int aoff = wm * 4096 + lm * 32 + sx;    // elem offset in A region
    const int boff = wn * 2048 + lm * 32 + sx;    // elem offset in B region

    stageA(0); stageB(0); stageA(1); stageB(1);
    asm volatile("s_waitcnt vmcnt(4)" ::: "memory");
    __builtin_amdgcn_s_barrier();

    for (int kt = 0; kt < GP_NKT; kt++) {
        const bf16* sA = (const bf16*)(lds + ((kt & 3) << 15));
        const bf16* sB = (const bf16*)(lds + ((kt & 3) << 15) + 16384);
        bf16x8 aF[4], bF[4], aG[4];
        // ---- phase 1: read aF/bF subtiles, stage A(kt+2), MFMA half 1 ----
#pragma unroll
        for (int i = 0; i < 4; i++) aF[i] = *(const bf16x8*)&sA[aoff + i * 512];
#pragma unroll
        for (int j = 0; j < 4; j++) bF[j] = *(const bf16x8*)&sB[boff + j * 512];
        if (kt + 2 < GP_NKT) stageA(kt + 2);
        __builtin_amdgcn_s_barrier();
        asm volatile("s_waitcnt lgkmcnt(0)" ::: "memory");
        __builtin_amdgcn_sched_barrier(0);
        __builtin_amdgcn_s_setprio(1);
#pragma unroll
        for (int i = 0; i < 4; i++)
#pragma unroll
            for (int j = 0; j < 4; j++)
                acc[i][j] = mfma16(aF[i], bF[j], acc[i][j]);
        __builtin_amdgcn_s_setprio(0);
        __builtin_amdgcn_s_barrier();
        // ---- phase 2: read aG subtile, stage B(kt+2), MFMA half 2 ----
#pragma unroll
        for (int i = 0; i < 4; i++) aG[i] = *(const bf16x8*)&sA[aoff + (i + 4) * 512];
        if (kt + 2 < GP_NKT) stageB(kt + 2);
        __builtin_amdgcn_s_barrier();
        asm volatile("s_waitcnt lgkmcnt(0)" ::: "memory");
        __builtin_amdgcn_sched_barrier(0);
        __builtin_amdgcn_s_setprio(1);
#pragma unroll
        for (int i = 0; i < 4; i++)
#pragma unroll
            for (int j = 0; j < 4; j++)
                acc[i + 4][j] = mfma16(aG[i], bF[j], acc[i + 4][j]);
        __builtin_amdgcn_s_setprio(0);
        if (kt + 2 < GP_NKT) asm volatile("s_waitcnt vmcnt(4)" ::: "memory");
        else                 asm volatile("s_waitcnt vmcnt(0)" ::: "memory");
        __builtin_amdgcn_s_barrier();
    }

    const int rbase = m0 + wm * 128 + lq * 4;
    const int cbase = n0 + wn * 64 + lm;
#pragma unroll
    for (int i = 0; i < 8; i++)
#pragma unroll
        for (int j = 0; j < 4; j++)
#pragma unroll
            for (int rI = 0; rI < 4; rI++)
                C[(size_t)(rbase + i * 16 + rI) * NPRJ + cbase + j * 16] =
                    f2bf(acc[i][j][rI]);
}

// ---------------- GEMM: C[M,N] = A[M,K] @ Bt[N,K]^T, strided A/C/gate ----------------
template <typename OutT>
__global__ __launch_bounds__(256) void gemm_bt(const bf16* __restrict__ A,
                                               const bf16* __restrict__ Bt,
                                               OutT* __restrict__ C,
                                               int M, int N, int K,
                                               const bf16* __restrict__ gate,
                                               int lda, int ldc, int ldg) {
    __shared__ bf16 As[128 * 32];
    __shared__ bf16 Bs[128 * 32];

    const int n0 = blockIdx.x * 128;
    const int m0 = blockIdx.y * 128;
    const int t = threadIdx.x;
    const int wid = t >> 6, lane = t & 63;
    const int wm = (wid & 1) * 64;
    const int wn = (wid >> 1) * 64;

    f32x4 acc[4][4] = {};

    const int srow = lane >> 2;          // 0..15
    const int scol = (lane & 3) * 8;     // bf16 col offset
    char* AsB = (char*)As;
    char* BsB = (char*)Bs;

    for (int k0 = 0; k0 < K; k0 += 32) {
        glds16(&A[(size_t)(m0 + wid * 16 + srow) * lda + k0 + scol],       AsB + wid * 1024);
        glds16(&A[(size_t)(m0 + 64 + wid * 16 + srow) * lda + k0 + scol],  AsB + 4096 + wid * 1024);
        glds16(&Bt[(size_t)(n0 + wid * 16 + srow) * K + k0 + scol],        BsB + wid * 1024);
        glds16(&Bt[(size_t)(n0 + 64 + wid * 16 + srow) * K + k0 + scol],   BsB + 4096 + wid * 1024);
        __syncthreads();

        const int kh = (lane >> 4) * 8;
        const int lm = lane & 15;
        bf16x8 a[4], b[4];
#pragma unroll
        for (int i = 0; i < 4; i++) a[i] = *(const bf16x8*)&As[(wm + i * 16 + lm) * 32 + kh];
#pragma unroll
        for (int j = 0; j < 4; j++) b[j] = *(const bf16x8*)&Bs[(wn + j * 16 + lm) * 32 + kh];
#pragma unroll
        for (int i = 0; i < 4; i++)
#pragma unroll
            for (int j = 0; j < 4; j++)
                acc[i][j] = __builtin_amdgcn_mfma_f32_16x16x32_bf16(a[i], b[j], acc[i][j], 0, 0, 0);
        __syncthreads();
    }

    const int lm = lane & 15, lq = lane >> 4;
#pragma unroll
    for (int i = 0; i < 4; i++) {
#pragma unroll
        for (int j = 0; j < 4; j++) {
#pragma unroll
            for (int rI = 0; rI < 4; rI++) {
                int row = m0 + wm + i * 16 + lq * 4 + rI;
                int col = n0 + wn + j * 16 + lm;
                float val = acc[i][j][rI];
                if (gate) {
                    float g = bf2f(gate[(size_t)row * ldg + col]);
                    val *= sigmoidf_(g);
                }
                C[(size_t)row * ldc + col] = (OutT)val;
            }
        }
    }
}

// ---------------- zero-centered RMSNorm in place, strided rows (vectorized) ----------------
// blockDim = L/8 (128 or 256); bf16x8 + float4 loads (G13).
template <int L>
__global__ __launch_bounds__(256) void zc_rms_v(bf16* __restrict__ buf,
                                                const float* __restrict__ scale,
                                                int ld) {
    constexpr int NW = L / 8 / 64;       // waves per block: 2 (L=1024) or 4 (L=2048)
    const int row = blockIdx.x, t = threadIdx.x;
    bf16* p = buf + (size_t)row * ld;
    bf16x8 v = *(const bf16x8*)&p[t * 8];
    float xv[8], s = 0.f, s2 = 0.f;
#pragma unroll
    for (int e = 0; e < 8; e++) { xv[e] = bf2f(v[e]); s += xv[e]; s2 += xv[e] * xv[e]; }
    __shared__ float red[2][NW];
#pragma unroll
    for (int o = 32; o > 0; o >>= 1) {
        s += __shfl_down(s, o, 64);
        s2 += __shfl_down(s2, o, 64);
    }
    if ((t & 63) == 0) { red[0][t >> 6] = s; red[1][t >> 6] = s2; }
    __syncthreads();
    s = 0.f; s2 = 0.f;
#pragma unroll
    for (int wv = 0; wv < NW; wv++) { s += red[0][wv]; s2 += red[1][wv]; }
    float mean = s / (float)L;
    float inv = rsqrtf(s2 / (float)L - mean * mean + 1e-5f);
    float4 s0 = *(const float4*)&scale[t * 8];
    float4 s1 = *(const float4*)&scale[t * 8 + 4];
    float sc[8] = { s0.x, s0.y, s0.z, s0.w, s1.x, s1.y, s1.z, s1.w };
    bf16x8 o;
#pragma unroll
    for (int e = 0; e < 8; e++) o[e] = f2bf((xv[e] - mean) * inv * sc[e]);
    *(bf16x8*)&p[t * 8] = o;
}

// ---------------- causal depthwise conv (K=4) + SiLU, vectorized x8 ----------------
// blockDim = CCH/8 (128 or 256), grid = Mc; strided in, compact out.
template <int CCH>
__global__ __launch_bounds__(256) void conv_silu_v(const bf16* __restrict__ xn,
                                                   const float* __restrict__ kern,
                                                   const float* __restrict__ bias,
                                                   bf16* __restrict__ out, int ldin) {
    const int btok = blockIdx.x;
    const int tt = btok & (Tc - 1);
    const int c8 = threadIdx.x * 8;
    float4 b0 = *(const float4*)&bias[c8], b1 = *(const float4*)&bias[c8 + 4];
    float acc[8] = { b0.x, b0.y, b0.z, b0.w, b1.x, b1.y, b1.z, b1.w };
#pragma unroll
    for (int i = 0; i < 4; i++) {
        if (tt - 3 + i >= 0) {
            bf16x8 xv = *(const bf16x8*)&xn[(size_t)(btok - 3 + i) * ldin + c8];
            float4 k0 = *(const float4*)&kern[i * CCH + c8];
            float4 k1 = *(const float4*)&kern[i * CCH + c8 + 4];
            float kk[8] = { k0.x, k0.y, k0.z, k0.w, k1.x, k1.y, k1.z, k1.w };
#pragma unroll
            for (int e = 0; e < 8; e++) acc[e] += bf2f(xv[e]) * kk[e];
        }
    }
    bf16x8 o;
#pragma unroll
    for (int e = 0; e < 8; e++) {
        float y = acc[e] * sigmoidf_(acc[e]);
        o[e] = f2bf(y);
    }
    *(bf16x8*)&out[(size_t)btok * CCH + c8] = o;
}

// ---------------- alpha/beta via MFMA: sigmoid(x @ [aw|bw]), hi/lo-split weights ----------------
__global__ __launch_bounds__(256) void alphabeta_mfma(const bf16* __restrict__ x,
                                                      const float* __restrict__ aw,
                                                      const float* __restrict__ bw,
                                                      float* __restrict__ af,
                                                      float* __restrict__ bfv) {
    __shared__ bf16 whi[32][136];
    __shared__ bf16 wlo[32][136];
    const int tid = threadIdx.x, wave = tid >> 6, lane = tid & 63;
    const int lm = lane & 15, lq = lane >> 4;
    const int m0 = blockIdx.x * 128;
    f32x4 acc[2][2] = {};

    for (int k0 = 0; k0 < Dc; k0 += 128) {
        for (int idx = tid; idx < 4096; idx += 256) {
            int n = idx & 31, kk = idx >> 5;
            float v = (n < 16) ? aw[(size_t)(k0 + kk) * Hc + n]
                               : bw[(size_t)(k0 + kk) * Hc + (n - 16)];
            bf16 h = f2bf(v);
            whi[n][kk] = h;
            wlo[n][kk] = f2bf(v - bf2f(h));
        }
        __syncthreads();
#pragma unroll
        for (int ks = 0; ks < 4; ks++) {
            bf16x8 bh[2], bl[2];
#pragma unroll
            for (int j = 0; j < 2; j++) {
                bh[j] = *(const bf16x8*)&whi[j * 16 + lm][ks * 32 + lq * 8];
                bl[j] = *(const bf16x8*)&wlo[j * 16 + lm][ks * 32 + lq * 8];
            }
#pragma unroll
            for (int ii = 0; ii < 2; ii++) {
                int row = m0 + wave * 32 + ii * 16 + lm;
                bf16x8 a = *(const bf16x8*)&x[(size_t)row * Dc + k0 + ks * 32 + lq * 8];
#pragma unroll
                for (int j = 0; j < 2; j++) {
                    acc[ii][j] = mfma16(a, bh[j], acc[ii][j]);
                    acc[ii][j] = mfma16(a, bl[j], acc[ii][j]);
                }
            }
        }
        __syncthreads();
    }
#pragma unroll
    for (int ii = 0; ii < 2; ii++)
#pragma unroll
        for (int rI = 0; rI < 4; rI++) {
            int row = m0 + wave * 32 + ii * 16 + lq * 4 + rI;
            af[(size_t)row * Hc + lm]  = sigmoidf_(acc[ii][0][rI]);
            bfv[(size_t)row * Hc + lm] = sigmoidf_(acc[ii][1][rI]);
        }
}

// ================= chunked gated delta rule =================
// Chunk (C=64) closed form with gamma_i = prod_{s<=i} a_s:
//   A_ij = b_i (g_i/g_j) k_i.k_j (j<i);  (I+A) U = diag(b)V - diag(b g) K S0
//   U = Uv - W S0,  Uv = T diag(b)V,  W = T diag(b g)K,  T = (I+A)^-1
//   O  = diag(g) Q S0 + M U,  M_ij = (g_i/g_j) q_i.k_j (j<=i)
//   S' = g_C S0 + Kbar^T U,   Kbar_j = (g_C/g_j) k_j
// T via BLOCKED inversion: 4 diagonal 16x16 register inverses + MFMA
// off-diagonal combines with bf16 hi/lo split (~f32 accuracy).
__global__ __launch_bounds__(256) void prep(bf16* __restrict__ qf,
                                            bf16* __restrict__ kf,
                                            bf16* __restrict__ vc,
                                            const float* __restrict__ af,
                                            const float* __restrict__ bfv,
                                            bf16* __restrict__ Wb,
                                            bf16* __restrict__ Mb,
                                            float* __restrict__ gamC) {
    __shared__ __align__(16) char smem[53248];
    bf16*  Kc   = (bf16*)(smem);             // [64][72] bf16, live whole kernel
    bf16*  Qc   = (bf16*)(smem + 9216);      // [64][72] bf16 (phase B only)
    float* DT   = (float*)(smem + 9216);     // [4][16][17] f32: I_g^T (solve)
    float* Pn   = (float*)(smem + 13568);    // [2][16][17] f32: -P^T pair L/H
    float* TT   = (float*)(smem + 15744);    // [16][17] f32: T10^T
    float* Qn   = (float*)(smem + 9216);     // [32][33] f32 (overlays DT, s3+)
    bf16*  Tb   = (bf16*)(smem + 9216);      // [64][72] bf16 T (after s4)
    float* As   = (float*)(smem + 18432);    // [64][65] f32
    bf16*  Vtb  = (bf16*)(smem + 18432);     // [128][72] bf16 (after Tb copy)
    float* Ts   = (float*)(smem + 35072);    // [64][65] f32
    float* lg_s = (float*)(smem + 51712);    // 64 log2-cumsum
    float* bv_s = lg_s + 64;                 // b_i
    float* bg_s = lg_s + 128;                // b_i * g_i
    float* gm_s = lg_s + 192;                // g_i
    float* kr_s = lg_s + 256;                // g_C / g_i

    const int c    = blockIdx.x;
    const int bh   = blockIdx.y;
    const int b    = bh >> 4, h = bh & 15;
    const int ch   = bh * NCHK + c;
    const int tok0 = b * Tc + c * CHUNK;
    const int tid  = threadIdx.x;
    const int wave = tid >> 6, lane = tid & 63;
    const int lm = lane & 15, lq = lane >> 4, kh = lq * 8;

    // ---- phase A: stage K,Q; zero Ts (upper blocks are never written); ab prefix
#pragma unroll
    for (int r = 0; r < 2; r++) {
        int idx = tid + r * 256;
        int row = idx >> 3, c8 = (idx & 7) * 8;
        *(bf16x8*)&Kc[row * 72 + c8] =
            *(const bf16x8*)&kf[(size_t)(tok0 + row) * QKDc + h * DKc + c8];
        *(bf16x8*)&Qc[row * 72 + c8] =
            *(const bf16x8*)&qf[(size_t)(tok0 + row) * QKDc + h * DKc + c8];
    }
    for (int idx = tid; idx < 64 * 65; idx += 256) Ts[idx] = 0.f;
    if (tid < 64) {
        float a  = af[(size_t)(tok0 + tid) * Hc + h];
        float bb = bfv[(size_t)(tok0 + tid) * Hc + h];
        float la = __log2f(fmaxf(a, 1e-30f));
#pragma unroll
        for (int o = 1; o < 64; o <<= 1) {       // inclusive prefix sum
            float t = __shfl_up(la, o, 64);
            if (tid >= o) la += t;
        }
        float lgC = __shfl(la, 63, 64);
        lg_s[tid] = la;
        bv_s[tid] = bb;
        float g   = exp2f(la);
        gm_s[tid] = g;
        bg_s[tid] = bb * g;
        kr_s[tid] = exp2f(lgC - la);
        if (tid == 0) gamC[ch] = exp2f(lgC);
    }
    __syncthreads();

    // ---- phase B: KK^T -> A; QK^T -> M; Qtilde/KbarT global writes
    {
        bf16x8 ka[2], qa[2];
#pragma unroll
        for (int s = 0; s < 2; s++) {
            ka[s] = *(const bf16x8*)&Kc[(16 * wave + lm) * 72 + s * 32 + kh];
            qa[s] = *(const bf16x8*)&Qc[(16 * wave + lm) * 72 + s * 32 + kh];
        }
#pragma unroll
        for (int jt = 0; jt < 4; jt++) {
            f32x4 kkacc = {}, qkacc = {};
#pragma unroll
            for (int s = 0; s < 2; s++) {
                bf16x8 kbf = *(const bf16x8*)&Kc[(16 * jt + lm) * 72 + s * 32 + kh];
                kkacc = mfma16(ka[s], kbf, kkacc);
                qkacc = mfma16(qa[s], kbf, qkacc);
            }
#pragma unroll
            for (int rI = 0; rI < 4; rI++) {
                int i = 16 * wave + lq * 4 + rI;
                int j = 16 * jt + lm;
                float ratio = exp2f(lg_s[i] - lg_s[j]);
                As[i * 65 + j] = (j < i) ? bv_s[i] * ratio * kkacc[rI] : 0.f;
                Mb[((size_t)ch * 64 + i) * 64 + j] =
                    (j <= i) ? f2bf(ratio * qkacc[rI]) : f2bf(0.f);
            }
        }
    }
    {   // Qtilde -> qf (in place); KbarT -> kf (in place, transposed [d][j])
#pragma unroll
        for (int r = 0; r < 2; r++) {
            int idx = tid + r * 256;
            int row = idx >> 3, c8 = (idx & 7) * 8;
            bf16x8 v = *(const bf16x8*)&Qc[row * 72 + c8];
            float g = gm_s[row];
            bf16x8 oq;
#pragma unroll
            for (int e = 0; e < 8; e++) oq[e] = f2bf(bf2f(v[e]) * g);
            *(bf16x8*)&qf[(size_t)(tok0 + row) * QKDc + h * DKc + c8] = oq;
            bf16x8 ok;
#pragma unroll
            for (int e = 0; e < 8; e++)
                ok[e] = f2bf(kr_s[c8 + e] * bf2f(Kc[(c8 + e) * 72 + row]));
            *(bf16x8*)&kf[(size_t)(tok0 + row) * QKDc + h * DKc + c8] = ok;
        }
    }
    __syncthreads();   // As complete; Qc dead -> DT/Pn/TT scratch usable

    // ---- phase C: 4 diagonal 16x16 inverses in registers (wave 0) ----
    if (tid < 64) {
        const int g = lane >> 4, jj = lane & 15, base = lane & 48;
        float areg[16], tcol[16];
#pragma unroll
        for (int i = 0; i < 16; i++) areg[i] = As[(16 * g + i) * 65 + 16 * g + jj];
#pragma unroll
        for (int i = 0; i < 16; i++) tcol[i] = (i == jj) ? 1.f : 0.f;
#pragma unroll
        for (int i = 1; i < 16; i++) {
            float s = 0.f;
#pragma unroll
            for (int m = 0; m < i; m++)
                s = fmaf(__shfl(areg[i], base + m, 64), tcol[m], s);
            tcol[i] = (i == jj) ? 1.f : -s;
        }
#pragma unroll
        for (int i = 0; i < 16; i++) {
            Ts[(16 * g + i) * 65 + 16 * g + jj] = tcol[i];   // I_g row-major
            DT[g * 272 + jj * 17 + i] = tcol[i];             // I_g^T row-major
        }
    }
    __syncthreads();

    // ---- s1: Pn = -(I_{2w}^T * A_off^T), pairs L(w=0): A10, H(w=1): A32. K=16
    if (wave < 2) {
        const int w = wave;
        bf16x8 ah, al, bh, bl;
#pragma unroll
        for (int e = 0; e < 8; e++) {
            int k = kh + e;
            float xa = (k < 16) ? DT[2 * w * 272 + lm * 17 + k] : 0.f;
            bf16 ha = f2bf(xa); ah[e] = ha; al[e] = f2bf(xa - bf2f(ha));
            float xb = (k < 16) ? As[(16 + 32 * w + lm) * 65 + 32 * w + k] : 0.f;
            bf16 hb = f2bf(xb); bh[e] = hb; bl[e] = f2bf(xb - bf2f(hb));
        }
        f32x4 acc = {};
        acc = mfma16(ah, bh, acc); acc = mfma16(ah, bl, acc); acc = mfma16(al, bh, acc);
#pragma unroll
        for (int rI = 0; rI < 4; rI++)
            Pn[w * 272 + (lq * 4 + rI) * 17 + lm] = -acc[rI];
    }
    __syncthreads();

    // ---- s2: T10 -> Ts[16:32,0:16]; T10^T -> TT; T32 -> Ts[48:64,32:48]. K=16
    if (wave < 3) {
        bf16x8 ah, al, bh, bl;
#pragma unroll
        for (int e = 0; e < 8; e++) {
            int k = kh + e;
            float xa = 0.f, xb = 0.f;
            if (k < 16) {
                if (wave == 0)      { xa = Ts[(16 + lm) * 65 + 16 + k]; xb = Pn[lm * 17 + k]; }
                else if (wave == 1) { xa = Pn[lm * 17 + k];             xb = Ts[(16 + lm) * 65 + 16 + k]; }
                else                { xa = Ts[(48 + lm) * 65 + 48 + k]; xb = Pn[272 + lm * 17 + k]; }
            }
            bf16 ha = f2bf(xa); ah[e] = ha; al[e] = f2bf(xa - bf2f(ha));
            bf16 hb = f2bf(xb); bh[e] = hb; bl[e] = f2bf(xb - bf2f(hb));
        }
        f32x4 acc = {};
        acc = mfma16(ah, bh, acc); acc = mfma16(ah, bl, acc); acc = mfma16(al, bh, acc);
#pragma unroll
        for (int rI = 0; rI < 4; rI++) {
            int ro = lq * 4 + rI;
            if (wave == 0)      Ts[(16 + ro) * 65 + lm]      = acc[rI];
            else if (wave == 1) TT[ro * 17 + lm]             = acc[rI];
            else                Ts[(48 + ro) * 65 + 32 + lm] = acc[rI];
        }
    }
    __syncthreads();

    // ---- s3: Qn = -(iL1^T * A_BL^T), 32x32, K=32; tile (a,b) per wave.
    {
        const int a = wave >> 1, bq = wave & 1;
        bf16x8 ah, al, bh, bl;
#pragma unroll
        for (int e = 0; e < 8; e++) {
            int k = kh + e;  // 0..31
            float xa;
            if (a == 0) xa = (k < 16) ? DT[lm * 17 + k] : TT[lm * 17 + (k - 16)];
            else        xa = (k < 16) ? 0.f : DT[272 + lm * 17 + (k - 16)];
            bf16 ha = f2bf(xa); ah[e] = ha; al[e] = f2bf(xa - bf2f(ha));
            float xb = As[(32 + 16 * bq + lm) * 65 + k];
            bf16 hb = f2bf(xb); bh[e] = hb; bl[e] = f2bf(xb - bf2f(hb));
        }
        f32x4 acc = {};
        acc = mfma16(ah, bh, acc); acc = mfma16(ah, bl, acc); acc = mfma16(al, bh, acc);
        __syncthreads();   // all DT/TT reads done before Qn overlays DT
#pragma unroll
        for (int rI = 0; rI < 4; rI++)
            Qn[(16 * a + lq * 4 + rI) * 33 + 16 * bq + lm] = -acc[rI];
    }
    __syncthreads();

    // ---- s4: T_BL = mfma(R(iL2), R(Qn)) -> Ts[32:64, 0:32]. K=32
    {
        const int a = wave >> 1, bq = wave & 1;
        bf16x8 ah, al, bh, bl;
#pragma unroll
        for (int e = 0; e < 8; e++) {
            int k = kh + e;  // 0..31
            float xa = Ts[(32 + 16 * a + lm) * 65 + 32 + k];
            bf16 ha = f2bf(xa); ah[e] = ha; al[e] = f2bf(xa - bf2f(ha));
            float xb = Qn[(16 * bq + lm) * 33 + k];
            bf16 hb = f2bf(xb); bh[e] = hb; bl[e] = f2bf(xb - bf2f(hb));
        }
        f32x4 acc = {};
        acc = mfma16(ah, bh, acc); acc = mfma16(ah, bl, acc); acc = mfma16(al, bh, acc);
#pragma unroll
        for (int rI = 0; rI < 4; rI++)
            Ts[(32 + 16 * a + lq * 4 + rI) * 65 + 16 * bq + lm] = acc[rI];
    }
    __syncthreads();

    // ---- Tb = bf16(Ts) into Qc region (solve scratch dead) ----
    for (int idx = tid; idx < 4096; idx += 256) {
        int i = idx >> 6, j = idx & 63;
        Tb[i * 72 + j] = f2bf(Ts[i * 65 + j]);
    }
    __syncthreads();                      // Ts dead; Vtb may overlay As/Ts-head
#pragma unroll
    for (int r = 0; r < 4; r++) {         // Vtb = (diag(b) V)^T  [128][72]
        int idx = tid + r * 256;
        int j = idx >> 4, c8 = (idx & 15) * 8;
        bf16x8 v = *(const bf16x8*)&vc[(size_t)(tok0 + j) * VDc + h * DVc + c8];
        float bb = bv_s[j];
#pragma unroll
        for (int e = 0; e < 8; e++)
            Vtb[(c8 + e) * 72 + j] = f2bf(bf2f(v[e]) * bb);
    }
    __syncthreads();
    {   // W = T diag(b g) K -> Wb;  Uv = T diag(b) V -> vc (in place)
        bf16x8 ta[2];
#pragma unroll
        for (int s = 0; s < 2; s++)
            ta[s] = *(const bf16x8*)&Tb[(16 * wave + lm) * 72 + s * 32 + kh];
#pragma unroll
        for (int dt = 0; dt < 4; dt++) {
            f32x4 wacc = {};
#pragma unroll
            for (int s = 0; s < 2; s++) {
                bf16x8 wbf;
                int d = 16 * dt + lm;
#pragma unroll
                for (int e = 0; e < 8; e++) {
                    int j = s * 32 + kh + e;
                    wbf[e] = f2bf(bg_s[j] * bf2f(Kc[j * 72 + d]));
                }
                wacc = mfma16(ta[s], wbf, wacc);
            }
#pragma unroll
            for (int rI = 0; rI < 4; rI++) {
                int i = 16 * wave + lq * 4 + rI;
                Wb[((size_t)ch * 64 + i) * 64 + 16 * dt + lm] = f2bf(wacc[rI]);
            }
        }
#pragma unroll
        for (int dt = 0; dt < 8; dt++) {
            f32x4 uacc = {};
#pragma unroll
            for (int s = 0; s < 2; s++) {
                bf16x8 vb = *(const bf16x8*)&Vtb[(16 * dt + lm) * 72 + s * 32 + kh];
                uacc = mfma16(ta[s], vb, uacc);
            }
#pragma unroll
            for (int rI = 0; rI < 4; rI++) {
                int i = 16 * wave + lq * 4 + rI;
                vc[(size_t)(tok0 + i) * VDc + h * DVc + 16 * dt + lm] = f2bf(uacc[rI]);
            }
        }
    }
}

// Sequential part: 32 chunk steps per (b,h), dv split 4 ways -> grid (4,64).
__global__ __launch_bounds__(256) void chunkloop(const bf16* __restrict__ qf,
                                                 const bf16* __restrict__ kf,
                                                 const bf16* __restrict__ vc,
                                                 const bf16* __restrict__ Wb,
                                                 const bf16* __restrict__ Mb,
                                                 const float* __restrict__ gamC,
                                                 bf16* __restrict__ o, int ldo) {
    const int vg = blockIdx.x;           // dv slice of 32
    const int bh = blockIdx.y;
    const int b = bh >> 4, h = bh & 15;
    const int tid = threadIdx.x;
    const int wave = tid >> 6, lane = tid & 63;
    const int lm = lane & 15, lq = lane >> 4, kh = lq * 8;

    __shared__ __align__(16) bf16 SbBuf[32 * 64];   // S^T shadow [dv][dk]
    __shared__ __align__(16) bf16 UtBuf[32 * 64];   // U^T [dv][t]

    for (int idx = tid; idx < 32 * 64; idx += 256) SbBuf[idx] = f2bf(0.f);

    f32x4 Sacc[2] = {};                  // wave's dk-tile = wave; dv tiles 0,1

    const int colK = h * DKc;
    const int colV = h * DVc + vg * 32;

    bf16x8 wa[2], qa[2], ma[2], kb[2];
    bf16 uvv[2][4];

    auto loadFrags = [&](int c, bf16x8 (&wa_)[2], bf16x8 (&qa_)[2], bf16x8 (&ma_)[2],
                         bf16x8 (&kb_)[2], bf16 (&uvv_)[2][4]) {
        const int tok0 = b * Tc + c * CHUNK;
        const size_t chb = ((size_t)bh * NCHK + c) * 64;
#pragma unroll
        for (int s = 0; s < 2; s++) {
            wa_[s] = *(const bf16x8*)&Wb[(chb + 16 * wave + lm) * 64 + s * 32 + kh];
            ma_[s] = *(const bf16x8*)&Mb[(chb + 16 * wave + lm) * 64 + s * 32 + kh];
            qa_[s] = *(const bf16x8*)&qf[(size_t)(tok0 + 16 * wave + lm) * QKDc + colK + s * 32 + kh];
            kb_[s] = *(const bf16x8*)&kf[(size_t)(tok0 + 16 * wave + lm) * QKDc + colK + s * 32 + kh];
        }
#pragma unroll
        for (int dt = 0; dt < 2; dt++)
#pragma unroll
            for (int rI = 0; rI < 4; rI++)
                uvv_[dt][rI] =
                    vc[(size_t)(tok0 + 16 * wave + lq * 4 + rI) * VDc + colV + 16 * dt + lm];
    };

    loadFrags(0, wa, qa, ma, kb, uvv);
    __syncthreads();

    for (int c = 0; c < NCHK; c++) {
        const float gC = gamC[(size_t)bh * NCHK + c];
        bf16x8 sf[2][2];
#pragma unroll
        for (int dt = 0; dt < 2; dt++)
#pragma unroll
            for (int s = 0; s < 2; s++)
                sf[dt][s] = *(const bf16x8*)swz32x64(SbBuf, 16 * dt + lm, s * 32 + kh);
        // m1: P = W * S0
        f32x4 pacc[2] = {};
#pragma unroll
        for (int dt = 0; dt < 2; dt++)
#pragma unroll
            for (int s = 0; s < 2; s++)
                pacc[dt] = mfma16(wa[s], sf[dt][s], pacc[dt]);

        // prefetch next chunk's fragments (global only)
        bf16x8 wa2[2], qa2[2], ma2[2], kb2[2];
        bf16 uvv2[2][4];
        if (c + 1 < NCHK) loadFrags(c + 1, wa2, qa2, ma2, kb2, uvv2);

        // U = Uv - P  -> Ut (transposed, swizzled)
#pragma unroll
        for (int dt = 0; dt < 2; dt++)
#pragma unroll
            for (int rI = 0; rI < 4; rI++) {
                float u = bf2f(uvv[dt][rI]) - pacc[dt][rI];
                *swz32x64(UtBuf, 16 * dt + lm, 16 * wave + lq * 4 + rI) = f2bf(u);
            }
        __syncthreads();   // publish Ut

        bf16x8 uf[2][2];
#pragma unroll
        for (int dt = 0; dt < 2; dt++)
#pragma unroll
            for (int s = 0; s < 2; s++)
                uf[dt][s] = *(const bf16x8*)swz32x64(UtBuf, 16 * dt + lm, s * 32 + kh);

        // m2: O = Qt*S0 + M*U  -> global (strided o_core)
        f32x4 oacc[2] = {};
#pragma unroll
        for (int dt = 0; dt < 2; dt++)
#pragma unroll
            for (int s = 0; s < 2; s++) {
                oacc[dt] = mfma16(qa[s], sf[dt][s], oacc[dt]);
                oacc[dt] = mfma16(ma[s], uf[dt][s], oacc[dt]);
            }
        {
            const int tok0 = b * Tc + c * CHUNK;
#pragma unroll
            for (int dt = 0; dt < 2; dt++)
#pragma unroll
                for (int rI = 0; rI < 4; rI++)
                    o[(size_t)(tok0 + 16 * wave + lq * 4 + rI) * ldo + colV + 16 * dt + lm] =
                        f2bf(oacc[dt][rI]);
        }
        // m3: S = gC*S + U^T * Kbar  (f32 accumulators, wave's dk-tile)
#pragma unroll
        for (int dt = 0; dt < 2; dt++) {
#pragma unroll
            for (int e = 0; e < 4; e++) Sacc[dt][e] *= gC;
#pragma unroll
            for (int s = 0; s < 2; s++)
                Sacc[dt] = mfma16(uf[dt][s], kb[s], Sacc[dt]);
        }
        __syncthreads();   // all Sb/Ut reads done before shadow overwrite
#pragma unroll
        for (int dt = 0; dt < 2; dt++)
#pragma unroll
            for (int rI = 0; rI < 4; rI++)
                *swz32x64(SbBuf, 16 * dt + lq * 4 + rI, 16 * wave + lm) = f2bf(Sacc[dt][rI]);
        __syncthreads();   // publish S shadow

        if (c + 1 < NCHK) {
#pragma unroll
            for (int s = 0; s < 2; s++) { wa[s] = wa2[s]; qa[s] = qa2[s]; ma[s] = ma2[s]; kb[s] = kb2[s]; }
#pragma unroll
            for (int dt = 0; dt < 2; dt++)
#pragma unroll
                for (int rI = 0; rI < 4; rI++) uvv[dt][rI] = uvv2[dt][rI];
        }
    }
}

// ---------------- host launch ----------------
extern "C" void kernel_launch(void* const* d_in, const int* in_sizes, int n_in,
                              void* d_out, int out_size, void* d_ws, size_t ws_size,
                              hipStream_t stream) {
    const float* x        = (const float*)d_in[0];
    const float* q_w      = (const float*)d_in[1];
    const float* k_w      = (const float*)d_in[2];
    const float* v_w      = (const float*)d_in[3];
    const float* q_scale  = (const float*)d_in[4];
    const float* k_scale  = (const float*)d_in[5];
    const float* v_scale  = (const float*)d_in[6];
    const float* q_conv_k = (const float*)d_in[7];
    const float* q_conv_b = (const float*)d_in[8];
    const float* k_conv_k = (const float*)d_in[9];
    const float* k_conv_b = (const float*)d_in[10];
    const float* v_conv_k = (const float*)d_in[11];
    const float* v_conv_b = (const float*)d_in[12];
    const float* alpha_w  = (const float*)d_in[13];
    const float* beta_w   = (const float*)d_in[14];
    const float* out_w    = (const float*)d_in[15];
    const float* gate_w   = (const float*)d_in[16];

    // ---- workspace (~208 MB) ----
    char* w = (char*)d_ws;
    bf16* xb  = (bf16*)w; w += (size_t)Mc * Dc * 2;          // 16 MB
    bf16* qwT = (bf16*)w; w += (size_t)QKDc * Dc * 2;        //  2 MB  -- qwT|kwT|vwT|gwT
    bf16* kwT = (bf16*)w; w += (size_t)QKDc * Dc * 2;        //  2 MB     contiguous =
    bf16* vwT = (bf16*)w; w += (size_t)VDc * Dc * 2;         //  4 MB     [5120][1024]
    bf16* gwT = (bf16*)w; w += (size_t)Dc * Dc * 2;          //  2 MB
    bf16* owT = (bf16*)w; w += (size_t)Dc * VDc * 2;         //  4 MB
    bf16* lin_all = (bf16*)w; w += (size_t)Mc * NPRJ * 2;    // 80 MB  [M][5120] q|k|v|g
    bf16* qf = (bf16*)w; w += (size_t)Mc * QKDc * 2;         // 16 MB  (conv q -> Qtilde)
    bf16* kf = (bf16*)w; w += (size_t)Mc * QKDc * 2;         // 16 MB  (conv k -> KbarT)
    bf16* vc = (bf16*)w; w += (size_t)Mc * VDc * 2;          // 32 MB  (conv v -> Uv)
    float* af = (float*)w; w += (size_t)Mc * Hc * 4;
    float* bfv = (float*)w; w += (size_t)Mc * Hc * 4;
    const int NCH_TOT = Bc * Hc * NCHK;                      // 2048 chunk-heads
    bf16* Wb = (bf16*)w; w += (size_t)NCH_TOT * 64 * 64 * 2; // 16 MB
    bf16* Mb = (bf16*)w; w += (size_t)NCH_TOT * 64 * 64 * 2; // 16 MB
    float* gamC = (float*)w; w += (size_t)NCH_TOT * 4;       //  8 KB
    // scan output goes into lin_all cols 0:2048 (q|k sections, dead after convs)
    bf16* o_core = lin_all;

    dim3 tb(32, 8);
    cast_f32_bf16<<<(Mc * Dc / 4 + 255) / 256, 256, 0, stream>>>(x, xb, Mc * Dc / 4);
    transpose_cast<<<dim3(QKDc / 32, Dc / 32), tb, 0, stream>>>(q_w, qwT, Dc, QKDc);
    transpose_cast<<<dim3(QKDc / 32, Dc / 32), tb, 0, stream>>>(k_w, kwT, Dc, QKDc);
    transpose_cast<<<dim3(VDc / 32, Dc / 32), tb, 0, stream>>>(v_w, vwT, Dc, VDc);
    transpose_cast<<<dim3(Dc / 32, Dc / 32), tb, 0, stream>>>(gate_w, gwT, Dc, Dc);
    transpose_cast<<<dim3(Dc / 32, VDc / 32), tb, 0, stream>>>(out_w, owT, VDc, Dc);

    // fused q|k|v|gate projection: pipelined 256x256 GEMM, fine 2-phase schedule
    gemm_pipe<<<GP_NT * GP_MT, 512, 0, stream>>>(xb, qwT, lin_all);

    // norms (strided rows inside lin_all), vectorized x8
    zc_rms_v<QKDc><<<Mc, QKDc / 8, 0, stream>>>(lin_all,        q_scale, NPRJ);
    zc_rms_v<QKDc><<<Mc, QKDc / 8, 0, stream>>>(lin_all + 1024, k_scale, NPRJ);
    zc_rms_v<VDc><<<Mc, VDc / 8, 0, stream>>>(lin_all + 2048,   v_scale, NPRJ);

    // convs: strided in, compact bf16 out, vectorized x8
    conv_silu_v<QKDc><<<Mc, QKDc / 8, 0, stream>>>(lin_all,        q_conv_k, q_conv_b, qf, NPRJ);
    conv_silu_v<QKDc><<<Mc, QKDc / 8, 0, stream>>>(lin_all + 1024, k_conv_k, k_conv_b, kf, NPRJ);
    conv_silu_v<VDc><<<Mc, VDc / 8, 0, stream>>>(lin_all + 2048,   v_conv_k, v_conv_b, vc, NPRJ);

    // alpha/beta via MFMA (hi/lo-split weights, f32-grade)
    alphabeta_mfma<<<Mc / 128, 256, 0, stream>>>(xb, alpha_w, beta_w, af, bfv);

    // chunked delta rule: parallel prep (per chunk-head), then 32-deep MFMA scan
    prep<<<dim3(NCHK, Bc * Hc), 256, 0, stream>>>(qf, kf, vc, af, bfv, Wb, Mb, gamC);
    chunkloop<<<dim3(4, Bc * Hc), 256, 0, stream>>>(qf, kf, vc, Wb, Mb, gamC, o_core, NPRJ);

    // out-projection (A = o_core strided in lin_all) + fused sigmoid gate (cols 4096:5120)
    gemm_bt<float><<<dim3(Dc / 128, Mc / 128), 256, 0, stream>>>(
        o_core, owT, (float*)d_out, Mc, Dc, VDc, lin_all + 4096, NPRJ, Dc, NPRJ);
}

// Round 5
// 524.492 us; speedup vs baseline: 1.7586x; 1.0726x over previous
//
#include <hip/hip_runtime.h>

// ---------------- problem constants ----------------
#define Bc   4
#define Tc   2048
#define Dc   1024
#define Hc   16
#define DKc  64
#define DVc  128
#define QKDc 1024
#define VDc  2048
#define NPRJ 5120        // q|k|v|gate fused projection width
#define Mc   (Bc * Tc)   // 8192 tokens
#define CHUNK 64         // delta-rule chunk size
#define NCHK (Tc / CHUNK) // 32 chunks per (b,h)

typedef __bf16 bf16;
typedef __bf16 bf16x4 __attribute__((ext_vector_type(4)));
typedef __bf16 bf16x8 __attribute__((ext_vector_type(8)));
typedef float  f32x4  __attribute__((ext_vector_type(4)));

__device__ __forceinline__ float bf2f(bf16 v) { return (float)v; }
__device__ __forceinline__ bf16  f2bf(float v) { return (bf16)v; }
__device__ __forceinline__ float sigmoidf_(float x) { return 1.0f / (1.0f + __expf(-x)); }
__device__ __forceinline__ f32x4 mfma16(bf16x8 a, bf16x8 b, f32x4 c) {
    return __builtin_amdgcn_mfma_f32_16x16x32_bf16(a, b, c, 0, 0, 0);
}

// async global->LDS, 16B/lane; lds dest = wave-uniform base + lane*16
__device__ __forceinline__ void glds16(const bf16* g, void* l) {
    __builtin_amdgcn_global_load_lds((const __attribute__((address_space(1))) void*)g,
                                     (__attribute__((address_space(3))) void*)l, 16, 0, 0);
}

// XOR-swizzled addressing for [32][64] bf16 LDS tiles (bank-conflict-free b128
// column-slice reads; bijective within each row's 128B).
__device__ __forceinline__ bf16* swz32x64(bf16* base, int r, int k) {
    int byte = (((r << 6) + k) << 1) ^ ((r & 7) << 4);
    return (bf16*)((char*)base + byte);
}

// ---------------- cast fp32 -> bf16 ----------------
__global__ __launch_bounds__(256) void cast_f32_bf16(const float* __restrict__ src,
                                                     bf16* __restrict__ dst, int n4) {
    int i = blockIdx.x * 256 + threadIdx.x;
    if (i < n4) {
        float4 v = ((const float4*)src)[i];
        bf16x4 o = { f2bf(v.x), f2bf(v.y), f2bf(v.z), f2bf(v.w) };
        ((bf16x4*)dst)[i] = o;
    }
}

// ---------------- transpose + cast: fp32 [R][C] -> bf16 [C][R] ----------------
__global__ __launch_bounds__(256) void transpose_cast(const float* __restrict__ src,
                                                      bf16* __restrict__ dst,
                                                      int R, int C) {
    __shared__ float tile[32][33];
    int c0 = blockIdx.x * 32, r0 = blockIdx.y * 32;
    int tx = threadIdx.x, ty = threadIdx.y;
#pragma unroll
    for (int i = 0; i < 32; i += 8) {
        int r = r0 + ty + i, c = c0 + tx;
        tile[ty + i][tx] = (r < R && c < C) ? src[(size_t)r * C + c] : 0.0f;
    }
    __syncthreads();
#pragma unroll
    for (int i = 0; i < 32; i += 8) {
        int rr = c0 + ty + i, cc = r0 + tx;
        if (rr < C && cc < R) dst[(size_t)rr * R + cc] = f2bf(tile[tx][ty + i]);
    }
}

// ============ pipelined 256x256 GEMM: lin_all[M,5120] = xb[M,1024] @ W^T ============
// BK=32, ring of 4 K-tile LDS slots (A 16K + B 16K each = 128 KiB), 8 waves.
// Round-4 lessons: (r3) extra mid-iteration barriers regress — ONE barrier per
// K-tile lets waves slip and overlap naturally; (r4) drop in-loop lgkmcnt(0)
// drains — the compiler emits counted lgkm waits (m97) interleaving ds_reads
// into the MFMA cluster; prefetch depth 3 (ring-4: write slot kt+3 == kt-1 is
// post-barrier safe; vmcnt(8) keeps kt+2/kt+3's 8 loads in flight).
#define GP_NT 20          // N tiles (5120/256)
#define GP_MT 32          // M tiles (8192/256)
#define GP_NKT 32         // K tiles (1024/32)
__global__ __launch_bounds__(512, 2) void gemm_pipe(const bf16* __restrict__ A,
                                                    const bf16* __restrict__ Bt,
                                                    bf16* __restrict__ C) {
    __shared__ __align__(16) char lds[131072];
    const int tid = threadIdx.x;
    const int wid = tid >> 6, lane = tid & 63;
    const int lm = lane & 15, lq = lane >> 4;
    const int wm = wid >> 2, wn = wid & 3;

    // bijective XCD swizzle (640 blocks, 640/8 = 80)
    const int id = blockIdx.x;
    const int nid = (id & 7) * ((GP_NT * GP_MT) / 8) + (id >> 3);
    const int tn = nid % GP_NT, tm = nid / GP_NT;
    const int n0 = tn * 256, m0 = tm * 256;

    // staging source addresses (per thread): chunk r*512+tid -> row r*128+(tid>>2),
    // physical slot tid&3 holds logical slot (tid&3)^(row&3)
    const int r0 = tid >> 2;
    const int lsx = ((tid & 3) ^ (r0 & 3)) << 3;
    const bf16* sA0 = A  + (size_t)(m0 + r0) * Dc + lsx;
    const bf16* sA1 = sA0 + (size_t)128 * Dc;
    const bf16* sB0 = Bt + (size_t)(n0 + r0) * Dc + lsx;
    const bf16* sB1 = sB0 + (size_t)128 * Dc;

    auto stageA = [&](int kt) {
        char* d = lds + ((kt & 3) << 15) + wid * 1024;
        glds16(sA0 + kt * 32, d);
        glds16(sA1 + kt * 32, d + 8192);
    };
    auto stageB = [&](int kt) {
        char* d = lds + ((kt & 3) << 15) + 16384 + wid * 1024;
        glds16(sB0 + kt * 32, d);
        glds16(sB1 + kt * 32, d + 8192);
    };

    f32x4 acc[8][4] = {};
    const int sx = (lq ^ (lm & 3)) << 3;          // swizzled K-slot for reads
    const int aoff = wm * 4096 + lm * 32 + sx;    // elem offset in A region
    const int boff = wn * 2048 + lm * 32 + sx;    // elem offset in B region

    stageA(0); stageB(0); stageA(1); stageB(1); stageA(2); stageB(2);
    asm volatile("s_waitcnt vmcnt(8)" ::: "memory");
    asm volatile("s_barrier" ::: "memory");

    for (int kt = 0; kt < GP_NKT; kt++) {
        const bf16* sA = (const bf16*)(lds + ((kt & 3) << 15));
        const bf16* sB = (const bf16*)(lds + ((kt & 3) << 15) + 16384);
        bf16x8 aF[4], bF[4], aG[4];
#pragma unroll
        for (int i = 0; i < 4; i++) aF[i] = *(const bf16x8*)&sA[aoff + i * 512];
#pragma unroll
        for (int j = 0; j < 4; j++) bF[j] = *(const bf16x8*)&sB[boff + j * 512];
#pragma unroll
        for (int i = 0; i < 4; i++) aG[i] = *(const bf16x8*)&sA[aoff + (i + 4) * 512];
        if (kt + 3 < GP_NKT) { stageA(kt + 3); stageB(kt + 3); }
        __builtin_amdgcn_s_setprio(1);
#pragma unroll
        for (int i = 0; i < 4; i++)
#pragma unroll
            for (int j = 0; j < 4; j++)
                acc[i][j] = mfma16(aF[i], bF[j], acc[i][j]);
#pragma unroll
        for (int i = 0; i < 4; i++)
#pragma unroll
            for (int j = 0; j < 4; j++)
                acc[i + 4][j] = mfma16(aG[i], bF[j], acc[i + 4][j]);
        __builtin_amdgcn_s_setprio(0);
        if (kt + 3 < GP_NKT)      asm volatile("s_waitcnt vmcnt(8)" ::: "memory");
        else if (kt + 2 < GP_NKT) asm volatile("s_waitcnt vmcnt(4)" ::: "memory");
        else                      asm volatile("s_waitcnt vmcnt(0)" ::: "memory");
        asm volatile("s_barrier" ::: "memory");
    }

    const int rbase = m0 + wm * 128 + lq * 4;
    const int cbase = n0 + wn * 64 + lm;
#pragma unroll
    for (int i = 0; i < 8; i++)
#pragma unroll
        for (int j = 0; j < 4; j++)
#pragma unroll
            for (int rI = 0; rI < 4; rI++)
                C[(size_t)(rbase + i * 16 + rI) * NPRJ + cbase + j * 16] =
                    f2bf(acc[i][j][rI]);
}

// ============ pipelined out-projection: d_out[M,1024] = o_core @ owT^T, gated ============
// 128(M)x256(N) tiles -> exactly 256 blocks (no tail). BK=32, ring-4 (24 KB/slot,
// 96 KiB), depth-3 prefetch (3 loads/K-tile -> vmcnt(6)/(3)/(0)). Gate fused.
#define GO_NKT 64         // K tiles (2048/32)
__global__ __launch_bounds__(512, 2) void gemm_pipe_out(const bf16* __restrict__ A,
                                                        const bf16* __restrict__ Bt,
                                                        float* __restrict__ C,
                                                        const bf16* __restrict__ gate) {
    __shared__ __align__(16) char lds[98304];
    const int tid = threadIdx.x;
    const int wid = tid >> 6, lane = tid & 63;
    const int lm = lane & 15, lq = lane >> 4;
    const int wm = wid >> 2, wn = wid & 3;     // 2M x 4N waves, per-wave 64x64

    const int id = blockIdx.x;                  // 256 blocks
    const int nid = (id & 7) * 32 + (id >> 3);  // bijective XCD swizzle
    const int tm = nid >> 2, tn = nid & 3;      // 64 M-tiles x 4 N-tiles
    const int m0 = tm * 128, n0 = tn * 256;

    const int r0 = tid >> 2;
    const int lsx = ((tid & 3) ^ (r0 & 3)) << 3;
    const bf16* sAp = A  + (size_t)(m0 + r0) * NPRJ + lsx;      // strided o_core
    const bf16* sB0 = Bt + (size_t)(n0 + r0) * VDc + lsx;
    const bf16* sB1 = sB0 + (size_t)128 * VDc;

    auto stageA = [&](int kt) {
        glds16(sAp + kt * 32, lds + (kt & 3) * 24576 + wid * 1024);
    };
    auto stageB = [&](int kt) {
        char* d = lds + (kt & 3) * 24576 + 8192 + wid * 1024;
        glds16(sB0 + kt * 32, d);
        glds16(sB1 + kt * 32, d + 8192);
    };

    f32x4 acc[4][4] = {};
    const int sx = (lq ^ (lm & 3)) << 3;
    const int aoff = wm * 2048 + lm * 32 + sx;    // A region: 128 rows
    const int boff = wn * 2048 + lm * 32 + sx;    // B region: 256 rows

    stageA(0); stageB(0); stageA(1); stageB(1); stageA(2); stageB(2);
    asm volatile("s_waitcnt vmcnt(6)" ::: "memory");
    asm volatile("s_barrier" ::: "memory");

    for (int kt = 0; kt < GO_NKT; kt++) {
        const bf16* sA = (const bf16*)(lds + (kt & 3) * 24576);
        const bf16* sB = sA + 4096;
        bf16x8 a[4], b[4];
#pragma unroll
        for (int i = 0; i < 4; i++) a[i] = *(const bf16x8*)&sA[aoff + i * 512];
#pragma unroll
        for (int j = 0; j < 4; j++) b[j] = *(const bf16x8*)&sB[boff + j * 512];
        if (kt + 3 < GO_NKT) { stageA(kt + 3); stageB(kt + 3); }
        __builtin_amdgcn_s_setprio(1);
#pragma unroll
        for (int i = 0; i < 4; i++)
#pragma unroll
            for (int j = 0; j < 4; j++)
                acc[i][j] = mfma16(a[i], b[j], acc[i][j]);
        __builtin_amdgcn_s_setprio(0);
        if (kt + 3 < GO_NKT)      asm volatile("s_waitcnt vmcnt(6)" ::: "memory");
        else if (kt + 2 < GO_NKT) asm volatile("s_waitcnt vmcnt(3)" ::: "memory");
        else                      asm volatile("s_waitcnt vmcnt(0)" ::: "memory");
        asm volatile("s_barrier" ::: "memory");
    }

    const int rbase = m0 + wm * 64 + lq * 4;
    const int cbase = n0 + wn * 64 + lm;
#pragma unroll
    for (int i = 0; i < 4; i++)
#pragma unroll
        for (int j = 0; j < 4; j++)
#pragma unroll
            for (int rI = 0; rI < 4; rI++) {
                int row = rbase + i * 16 + rI;
                int col = cbase + j * 16;
                float g = bf2f(gate[(size_t)row * NPRJ + col]);
                C[(size_t)row * Dc + col] = acc[i][j][rI] * sigmoidf_(g);
            }
}

// ---------------- zero-centered RMSNorm in place, strided rows (vectorized) ----------------
// blockDim = L/8 (128 or 256); bf16x8 + float4 loads (G13).
template <int L>
__global__ __launch_bounds__(256) void zc_rms_v(bf16* __restrict__ buf,
                                                const float* __restrict__ scale,
                                                int ld) {
    constexpr int NW = L / 8 / 64;       // waves per block: 2 (L=1024) or 4 (L=2048)
    const int row = blockIdx.x, t = threadIdx.x;
    bf16* p = buf + (size_t)row * ld;
    bf16x8 v = *(const bf16x8*)&p[t * 8];
    float xv[8], s = 0.f, s2 = 0.f;
#pragma unroll
    for (int e = 0; e < 8; e++) { xv[e] = bf2f(v[e]); s += xv[e]; s2 += xv[e] * xv[e]; }
    __shared__ float red[2][NW];
#pragma unroll
    for (int o = 32; o > 0; o >>= 1) {
        s += __shfl_down(s, o, 64);
        s2 += __shfl_down(s2, o, 64);
    }
    if ((t & 63) == 0) { red[0][t >> 6] = s; red[1][t >> 6] = s2; }
    __syncthreads();
    s = 0.f; s2 = 0.f;
#pragma unroll
    for (int wv = 0; wv < NW; wv++) { s += red[0][wv]; s2 += red[1][wv]; }
    float mean = s / (float)L;
    float inv = rsqrtf(s2 / (float)L - mean * mean + 1e-5f);
    float4 s0 = *(const float4*)&scale[t * 8];
    float4 s1 = *(const float4*)&scale[t * 8 + 4];
    float sc[8] = { s0.x, s0.y, s0.z, s0.w, s1.x, s1.y, s1.z, s1.w };
    bf16x8 o;
#pragma unroll
    for (int e = 0; e < 8; e++) o[e] = f2bf((xv[e] - mean) * inv * sc[e]);
    *(bf16x8*)&p[t * 8] = o;
}

// ---------------- causal depthwise conv (K=4) + SiLU, vectorized x8 ----------------
template <int CCH>
__global__ __launch_bounds__(256) void conv_silu_v(const bf16* __restrict__ xn,
                                                   const float* __restrict__ kern,
                                                   const float* __restrict__ bias,
                                                   bf16* __restrict__ out, int ldin) {
    const int btok = blockIdx.x;
    const int tt = btok & (Tc - 1);
    const int c8 = threadIdx.x * 8;
    float4 b0 = *(const float4*)&bias[c8], b1 = *(const float4*)&bias[c8 + 4];
    float acc[8] = { b0.x, b0.y, b0.z, b0.w, b1.x, b1.y, b1.z, b1.w };
#pragma unroll
    for (int i = 0; i < 4; i++) {
        if (tt - 3 + i >= 0) {
            bf16x8 xv = *(const bf16x8*)&xn[(size_t)(btok - 3 + i) * ldin + c8];
            float4 k0 = *(const float4*)&kern[i * CCH + c8];
            float4 k1 = *(const float4*)&kern[i * CCH + c8 + 4];
            float kk[8] = { k0.x, k0.y, k0.z, k0.w, k1.x, k1.y, k1.z, k1.w };
#pragma unroll
            for (int e = 0; e < 8; e++) acc[e] += bf2f(xv[e]) * kk[e];
        }
    }
    bf16x8 o;
#pragma unroll
    for (int e = 0; e < 8; e++) {
        float y = acc[e] * sigmoidf_(acc[e]);
        o[e] = f2bf(y);
    }
    *(bf16x8*)&out[(size_t)btok * CCH + c8] = o;
}

// ---------------- alpha/beta via MFMA: sigmoid(x @ [aw|bw]), hi/lo-split weights ----------------
__global__ __launch_bounds__(256) void alphabeta_mfma(const bf16* __restrict__ x,
                                                      const float* __restrict__ aw,
                                                      const float* __restrict__ bw,
                                                      float* __restrict__ af,
                                                      float* __restrict__ bfv) {
    __shared__ bf16 whi[32][136];
    __shared__ bf16 wlo[32][136];
    const int tid = threadIdx.x, wave = tid >> 6, lane = tid & 63;
    const int lm = lane & 15, lq = lane >> 4;
    const int m0 = blockIdx.x * 128;
    f32x4 acc[2][2] = {};

    for (int k0 = 0; k0 < Dc; k0 += 128) {
        for (int idx = tid; idx < 4096; idx += 256) {
            int n = idx & 31, kk = idx >> 5;
            float v = (n < 16) ? aw[(size_t)(k0 + kk) * Hc + n]
                               : bw[(size_t)(k0 + kk) * Hc + (n - 16)];
            bf16 h = f2bf(v);
            whi[n][kk] = h;
            wlo[n][kk] = f2bf(v - bf2f(h));
        }
        __syncthreads();
#pragma unroll
        for (int ks = 0; ks < 4; ks++) {
            bf16x8 bh[2], bl[2];
#pragma unroll
            for (int j = 0; j < 2; j++) {
                bh[j] = *(const bf16x8*)&whi[j * 16 + lm][ks * 32 + lq * 8];
                bl[j] = *(const bf16x8*)&wlo[j * 16 + lm][ks * 32 + lq * 8];
            }
#pragma unroll
            for (int ii = 0; ii < 2; ii++) {
                int row = m0 + wave * 32 + ii * 16 + lm;
                bf16x8 a = *(const bf16x8*)&x[(size_t)row * Dc + k0 + ks * 32 + lq * 8];
#pragma unroll
                for (int j = 0; j < 2; j++) {
                    acc[ii][j] = mfma16(a, bh[j], acc[ii][j]);
                    acc[ii][j] = mfma16(a, bl[j], acc[ii][j]);
                }
            }
        }
        __syncthreads();
    }
#pragma unroll
    for (int ii = 0; ii < 2; ii++)
#pragma unroll
        for (int rI = 0; rI < 4; rI++) {
            int row = m0 + wave * 32 + ii * 16 + lq * 4 + rI;
            af[(size_t)row * Hc + lm]  = sigmoidf_(acc[ii][0][rI]);
            bfv[(size_t)row * Hc + lm] = sigmoidf_(acc[ii][1][rI]);
        }
}

// ================= chunked gated delta rule =================
// Chunk (C=64) closed form with gamma_i = prod_{s<=i} a_s:
//   A_ij = b_i (g_i/g_j) k_i.k_j (j<i);  (I+A) U = diag(b)V - diag(b g) K S0
//   U = Uv - W S0,  Uv = T diag(b)V,  W = T diag(b g)K,  T = (I+A)^-1
//   O  = diag(g) Q S0 + M U,  M_ij = (g_i/g_j) q_i.k_j (j<=i)
//   S' = g_C S0 + Kbar^T U,   Kbar_j = (g_C/g_j) k_j
// T via BLOCKED inversion: 4 diagonal 16x16 register inverses + MFMA
// off-diagonal combines with bf16 hi/lo split (~f32 accuracy).
__global__ __launch_bounds__(256) void prep(bf16* __restrict__ qf,
                                            bf16* __restrict__ kf,
                                            bf16* __restrict__ vc,
                                            const float* __restrict__ af,
                                            const float* __restrict__ bfv,
                                            bf16* __restrict__ Wb,
                                            bf16* __restrict__ Mb,
                                            float* __restrict__ gamC) {
    __shared__ __align__(16) char smem[53248];
    bf16*  Kc   = (bf16*)(smem);             // [64][72] bf16, live whole kernel
    bf16*  Qc   = (bf16*)(smem + 9216);      // [64][72] bf16 (phase B only)
    float* DT   = (float*)(smem + 9216);     // [4][16][17] f32: I_g^T (solve)
    float* Pn   = (float*)(smem + 13568);    // [2][16][17] f32: -P^T pair L/H
    float* TT   = (float*)(smem + 15744);    // [16][17] f32: T10^T
    float* Qn   = (float*)(smem + 9216);     // [32][33] f32 (overlays DT, s3+)
    bf16*  Tb   = (bf16*)(smem + 9216);      // [64][72] bf16 T (after s4)
    float* As   = (float*)(smem + 18432);    // [64][65] f32
    bf16*  Vtb  = (bf16*)(smem + 18432);     // [128][72] bf16 (after Tb copy)
    float* Ts   = (float*)(smem + 35072);    // [64][65] f32
    float* lg_s = (float*)(smem + 51712);    // 64 log2-cumsum
    float* bv_s = lg_s + 64;                 // b_i
    float* bg_s = lg_s + 128;                // b_i * g_i
    float* gm_s = lg_s + 192;                // g_i
    float* kr_s = lg_s + 256;                // g_C / g_i

    const int c    = blockIdx.x;
    const int bh   = blockIdx.y;
    const int b    = bh >> 4, h = bh & 15;
    const int ch   = bh * NCHK + c;
    const int tok0 = b * Tc + c * CHUNK;
    const int tid  = threadIdx.x;
    const int wave = tid >> 6, lane = tid & 63;
    const int lm = lane & 15, lq = lane >> 4, kh = lq * 8;

    // ---- phase A: stage K,Q; zero Ts (upper blocks are never written); ab prefix
#pragma unroll
    for (int r = 0; r < 2; r++) {
        int idx = tid + r * 256;
        int row = idx >> 3, c8 = (idx & 7) * 8;
        *(bf16x8*)&Kc[row * 72 + c8] =
            *(const bf16x8*)&kf[(size_t)(tok0 + row) * QKDc + h * DKc + c8];
        *(bf16x8*)&Qc[row * 72 + c8] =
            *(const bf16x8*)&qf[(size_t)(tok0 + row) * QKDc + h * DKc + c8];
    }
    for (int idx = tid; idx < 64 * 65; idx += 256) Ts[idx] = 0.f;
    if (tid < 64) {
        float a  = af[(size_t)(tok0 + tid) * Hc + h];
        float bb = bfv[(size_t)(tok0 + tid) * Hc + h];
        float la = __log2f(fmaxf(a, 1e-30f));
#pragma unroll
        for (int o = 1; o < 64; o <<= 1) {       // inclusive prefix sum
            float t = __shfl_up(la, o, 64);
            if (tid >= o) la += t;
        }
        float lgC = __shfl(la, 63, 64);
        lg_s[tid] = la;
        bv_s[tid] = bb;
        float g   = exp2f(la);
        gm_s[tid] = g;
        bg_s[tid] = bb * g;
        kr_s[tid] = exp2f(lgC - la);
        if (tid == 0) gamC[ch] = exp2f(lgC);
    }
    __syncthreads();

    // ---- phase B: KK^T -> A; QK^T -> M; Qtilde/KbarT global writes
    {
        bf16x8 ka[2], qa[2];
#pragma unroll
        for (int s = 0; s < 2; s++) {
            ka[s] = *(const bf16x8*)&Kc[(16 * wave + lm) * 72 + s * 32 + kh];
            qa[s] = *(const bf16x8*)&Qc[(16 * wave + lm) * 72 + s * 32 + kh];
        }
#pragma unroll
        for (int jt = 0; jt < 4; jt++) {
            f32x4 kkacc = {}, qkacc = {};
#pragma unroll
            for (int s = 0; s < 2; s++) {
                bf16x8 kbf = *(const bf16x8*)&Kc[(16 * jt + lm) * 72 + s * 32 + kh];
                kkacc = mfma16(ka[s], kbf, kkacc);
                qkacc = mfma16(qa[s], kbf, qkacc);
            }
#pragma unroll
            for (int rI = 0; rI < 4; rI++) {
                int i = 16 * wave + lq * 4 + rI;
                int j = 16 * jt + lm;
                float ratio = exp2f(lg_s[i] - lg_s[j]);
                As[i * 65 + j] = (j < i) ? bv_s[i] * ratio * kkacc[rI] : 0.f;
                Mb[((size_t)ch * 64 + i) * 64 + j] =
                    (j <= i) ? f2bf(ratio * qkacc[rI]) : f2bf(0.f);
            }
        }
    }
    {   // Qtilde -> qf (in place); KbarT -> kf (in place, transposed [d][j])
#pragma unroll
        for (int r = 0; r < 2; r++) {
            int idx = tid + r * 256;
            int row = idx >> 3, c8 = (idx & 7) * 8;
            bf16x8 v = *(const bf16x8*)&Qc[row * 72 + c8];
            float g = gm_s[row];
            bf16x8 oq;
#pragma unroll
            for (int e = 0; e < 8; e++) oq[e] = f2bf(bf2f(v[e]) * g);
            *(bf16x8*)&qf[(size_t)(tok0 + row) * QKDc + h * DKc + c8] = oq;
            bf16x8 ok;
#pragma unroll
            for (int e = 0; e < 8; e++)
                ok[e] = f2bf(kr_s[c8 + e] * bf2f(Kc[(c8 + e) * 72 + row]));
            *(bf16x8*)&kf[(size_t)(tok0 + row) * QKDc + h * DKc + c8] = ok;
        }
    }
    __syncthreads();   // As complete; Qc dead -> DT/Pn/TT scratch usable

    // ---- phase C: 4 diagonal 16x16 inverses in registers (wave 0) ----
    if (tid < 64) {
        const int g = lane >> 4, jj = lane & 15, base = lane & 48;
        float areg[16], tcol[16];
#pragma unroll
        for (int i = 0; i < 16; i++) areg[i] = As[(16 * g + i) * 65 + 16 * g + jj];
#pragma unroll
        for (int i = 0; i < 16; i++) tcol[i] = (i == jj) ? 1.f : 0.f;
#pragma unroll
        for (int i = 1; i < 16; i++) {
            float s = 0.f;
#pragma unroll
            for (int m = 0; m < i; m++)
                s = fmaf(__shfl(areg[i], base + m, 64), tcol[m], s);
            tcol[i] = (i == jj) ? 1.f : -s;
        }
#pragma unroll
        for (int i = 0; i < 16; i++) {
            Ts[(16 * g + i) * 65 + 16 * g + jj] = tcol[i];   // I_g row-major
            DT[g * 272 + jj * 17 + i] = tcol[i];             // I_g^T row-major
        }
    }
    __syncthreads();

    // ---- s1: Pn = -(I_{2w}^T * A_off^T), pairs L(w=0): A10, H(w=1): A32. K=16
    if (wave < 2) {
        const int w = wave;
        bf16x8 ah, al, bh, bl;
#pragma unroll
        for (int e = 0; e < 8; e++) {
            int k = kh + e;
            float xa = (k < 16) ? DT[2 * w * 272 + lm * 17 + k] : 0.f;
            bf16 ha = f2bf(xa); ah[e] = ha; al[e] = f2bf(xa - bf2f(ha));
            float xb = (k < 16) ? As[(16 + 32 * w + lm) * 65 + 32 * w + k] : 0.f;
            bf16 hb = f2bf(xb); bh[e] = hb; bl[e] = f2bf(xb - bf2f(hb));
        }
        f32x4 acc = {};
        acc = mfma16(ah, bh, acc); acc = mfma16(ah, bl, acc); acc = mfma16(al, bh, acc);
#pragma unroll
        for (int rI = 0; rI < 4; rI++)
            Pn[w * 272 + (lq * 4 + rI) * 17 + lm] = -acc[rI];
    }
    __syncthreads();

    // ---- s2: T10 -> Ts[16:32,0:16]; T10^T -> TT; T32 -> Ts[48:64,32:48]. K=16
    if (wave < 3) {
        bf16x8 ah, al, bh, bl;
#pragma unroll
        for (int e = 0; e < 8; e++) {
            int k = kh + e;
            float xa = 0.f, xb = 0.f;
            if (k < 16) {
                if (wave == 0)      { xa = Ts[(16 + lm) * 65 + 16 + k]; xb = Pn[lm * 17 + k]; }
                else if (wave == 1) { xa = Pn[lm * 17 + k];             xb = Ts[(16 + lm) * 65 + 16 + k]; }
                else                { xa = Ts[(48 + lm) * 65 + 48 + k]; xb = Pn[272 + lm * 17 + k]; }
            }
            bf16 ha = f2bf(xa); ah[e] = ha; al[e] = f2bf(xa - bf2f(ha));
            bf16 hb = f2bf(xb); bh[e] = hb; bl[e] = f2bf(xb - bf2f(hb));
        }
        f32x4 acc = {};
        acc = mfma16(ah, bh, acc); acc = mfma16(ah, bl, acc); acc = mfma16(al, bh, acc);
#pragma unroll
        for (int rI = 0; rI < 4; rI++) {
            int ro = lq * 4 + rI;
            if (wave == 0)      Ts[(16 + ro) * 65 + lm]      = acc[rI];
            else if (wave == 1) TT[ro * 17 + lm]             = acc[rI];
            else                Ts[(48 + ro) * 65 + 32 + lm] = acc[rI];
        }
    }
    __syncthreads();

    // ---- s3: Qn = -(iL1^T * A_BL^T), 32x32, K=32; tile (a,b) per wave.
    {
        const int a = wave >> 1, bq = wave & 1;
        bf16x8 ah, al, bh, bl;
#pragma unroll
        for (int e = 0; e < 8; e++) {
            int k = kh + e;  // 0..31
            float xa;
            if (a == 0) xa = (k < 16) ? DT[lm * 17 + k] : TT[lm * 17 + (k - 16)];
            else        xa = (k < 16) ? 0.f : DT[272 + lm * 17 + (k - 16)];
            bf16 ha = f2bf(xa); ah[e] = ha; al[e] = f2bf(xa - bf2f(ha));
            float xb = As[(32 + 16 * bq + lm) * 65 + k];
            bf16 hb = f2bf(xb); bh[e] = hb; bl[e] = f2bf(xb - bf2f(hb));
        }
        f32x4 acc = {};
        acc = mfma16(ah, bh, acc); acc = mfma16(ah, bl, acc); acc = mfma16(al, bh, acc);
        __syncthreads();   // all DT/TT reads done before Qn overlays DT
#pragma unroll
        for (int rI = 0; rI < 4; rI++)
            Qn[(16 * a + lq * 4 + rI) * 33 + 16 * bq + lm] = -acc[rI];
    }
    __syncthreads();

    // ---- s4: T_BL = mfma(R(iL2), R(Qn)) -> Ts[32:64, 0:32]. K=32
    {
        const int a = wave >> 1, bq = wave & 1;
        bf16x8 ah, al, bh, bl;
#pragma unroll
        for (int e = 0; e < 8; e++) {
            int k = kh + e;  // 0..31
            float xa = Ts[(32 + 16 * a + lm) * 65 + 32 + k];
            bf16 ha = f2bf(xa); ah[e] = ha; al[e] = f2bf(xa - bf2f(ha));
            float xb = Qn[(16 * bq + lm) * 33 + k];
            bf16 hb = f2bf(xb); bh[e] = hb; bl[e] = f2bf(xb - bf2f(hb));
        }
        f32x4 acc = {};
        acc = mfma16(ah, bh, acc); acc = mfma16(ah, bl, acc); acc = mfma16(al, bh, acc);
#pragma unroll
        for (int rI = 0; rI < 4; rI++)
            Ts[(32 + 16 * a + lq * 4 + rI) * 65 + 16 * bq + lm] = acc[rI];
    }
    __syncthreads();

    // ---- Tb = bf16(Ts) into Qc region (solve scratch dead) ----
    for (int idx = tid; idx < 4096; idx += 256) {
        int i = idx >> 6, j = idx & 63;
        Tb[i * 72 + j] = f2bf(Ts[i * 65 + j]);
    }
    __syncthreads();                      // Ts dead; Vtb may overlay As/Ts-head
#pragma unroll
    for (int r = 0; r < 4; r++) {         // Vtb = (diag(b) V)^T  [128][72]
        int idx = tid + r * 256;
        int j = idx >> 4, c8 = (idx & 15) * 8;
        bf16x8 v = *(const bf16x8*)&vc[(size_t)(tok0 + j) * VDc + h * DVc + c8];
        float bb = bv_s[j];
#pragma unroll
        for (int e = 0; e < 8; e++)
            Vtb[(c8 + e) * 72 + j] = f2bf(bf2f(v[e]) * bb);
    }
    __syncthreads();
    {   // W = T diag(b g) K -> Wb;  Uv = T diag(b) V -> vc (in place)
        bf16x8 ta[2];
#pragma unroll
        for (int s = 0; s < 2; s++)
            ta[s] = *(const bf16x8*)&Tb[(16 * wave + lm) * 72 + s * 32 + kh];
#pragma unroll
        for (int dt = 0; dt < 4; dt++) {
            f32x4 wacc = {};
#pragma unroll
            for (int s = 0; s < 2; s++) {
                bf16x8 wbf;
                int d = 16 * dt + lm;
#pragma unroll
                for (int e = 0; e < 8; e++) {
                    int j = s * 32 + kh + e;
                    wbf[e] = f2bf(bg_s[j] * bf2f(Kc[j * 72 + d]));
                }
                wacc = mfma16(ta[s], wbf, wacc);
            }
#pragma unroll
            for (int rI = 0; rI < 4; rI++) {
                int i = 16 * wave + lq * 4 + rI;
                Wb[((size_t)ch * 64 + i) * 64 + 16 * dt + lm] = f2bf(wacc[rI]);
            }
        }
#pragma unroll
        for (int dt = 0; dt < 8; dt++) {
            f32x4 uacc = {};
#pragma unroll
            for (int s = 0; s < 2; s++) {
                bf16x8 vb = *(const bf16x8*)&Vtb[(16 * dt + lm) * 72 + s * 32 + kh];
                uacc = mfma16(ta[s], vb, uacc);
            }
#pragma unroll
            for (int rI = 0; rI < 4; rI++) {
                int i = 16 * wave + lq * 4 + rI;
                vc[(size_t)(tok0 + i) * VDc + h * DVc + 16 * dt + lm] = f2bf(uacc[rI]);
            }
        }
    }
}

// Sequential part: 32 chunk steps per (b,h), dv split 4 ways -> grid (4,64).
__global__ __launch_bounds__(256) void chunkloop(const bf16* __restrict__ qf,
                                                 const bf16* __restrict__ kf,
                                                 const bf16* __restrict__ vc,
                                                 const bf16* __restrict__ Wb,
                                                 const bf16* __restrict__ Mb,
                                                 const float* __restrict__ gamC,
                                                 bf16* __restrict__ o, int ldo) {
    const int vg = blockIdx.x;           // dv slice of 32
    const int bh = blockIdx.y;
    const int b = bh >> 4, h = bh & 15;
    const int tid = threadIdx.x;
    const int wave = tid >> 6, lane = tid & 63;
    const int lm = lane & 15, lq = lane >> 4, kh = lq * 8;

    __shared__ __align__(16) bf16 SbBuf[32 * 64];   // S^T shadow [dv][dk]
    __shared__ __align__(16) bf16 UtBuf[32 * 64];   // U^T [dv][t]

    for (int idx = tid; idx < 32 * 64; idx += 256) SbBuf[idx] = f2bf(0.f);

    f32x4 Sacc[2] = {};                  // wave's dk-tile = wave; dv tiles 0,1

    const int colK = h * DKc;
    const int colV = h * DVc + vg * 32;

    bf16x8 wa[2], qa[2], ma[2], kb[2];
    bf16 uvv[2][4];

    auto loadFrags = [&](int c, bf16x8 (&wa_)[2], bf16x8 (&qa_)[2], bf16x8 (&ma_)[2],
                         bf16x8 (&kb_)[2], bf16 (&uvv_)[2][4]) {
        const int tok0 = b * Tc + c * CHUNK;
        const size_t chb = ((size_t)bh * NCHK + c) * 64;
#pragma unroll
        for (int s = 0; s < 2; s++) {
            wa_[s] = *(const bf16x8*)&Wb[(chb + 16 * wave + lm) * 64 + s * 32 + kh];
            ma_[s] = *(const bf16x8*)&Mb[(chb + 16 * wave + lm) * 64 + s * 32 + kh];
            qa_[s] = *(const bf16x8*)&qf[(size_t)(tok0 + 16 * wave + lm) * QKDc + colK + s * 32 + kh];
            kb_[s] = *(const bf16x8*)&kf[(size_t)(tok0 + 16 * wave + lm) * QKDc + colK + s * 32 + kh];
        }
#pragma unroll
        for (int dt = 0; dt < 2; dt++)
#pragma unroll
            for (int rI = 0; rI < 4; rI++)
                uvv_[dt][rI] =
                    vc[(size_t)(tok0 + 16 * wave + lq * 4 + rI) * VDc + colV + 16 * dt + lm];
    };

    loadFrags(0, wa, qa, ma, kb, uvv);
    __syncthreads();

    for (int c = 0; c < NCHK; c++) {
        const float gC = gamC[(size_t)bh * NCHK + c];
        bf16x8 sf[2][2];
#pragma unroll
        for (int dt = 0; dt < 2; dt++)
#pragma unroll
            for (int s = 0; s < 2; s++)
                sf[dt][s] = *(const bf16x8*)swz32x64(SbBuf, 16 * dt + lm, s * 32 + kh);
        // m1: P = W * S0
        f32x4 pacc[2] = {};
#pragma unroll
        for (int dt = 0; dt < 2; dt++)
#pragma unroll
            for (int s = 0; s < 2; s++)
                pacc[dt] = mfma16(wa[s], sf[dt][s], pacc[dt]);

        // prefetch next chunk's fragments (global only)
        bf16x8 wa2[2], qa2[2], ma2[2], kb2[2];
        bf16 uvv2[2][4];
        if (c + 1 < NCHK) loadFrags(c + 1, wa2, qa2, ma2, kb2, uvv2);

        // U = Uv - P  -> Ut (transposed, swizzled)
#pragma unroll
        for (int dt = 0; dt < 2; dt++)
#pragma unroll
            for (int rI = 0; rI < 4; rI++) {
                float u = bf2f(uvv[dt][rI]) - pacc[dt][rI];
                *swz32x64(UtBuf, 16 * dt + lm, 16 * wave + lq * 4 + rI) = f2bf(u);
            }
        __syncthreads();   // publish Ut

        bf16x8 uf[2][2];
#pragma unroll
        for (int dt = 0; dt < 2; dt++)
#pragma unroll
            for (int s = 0; s < 2; s++)
                uf[dt][s] = *(const bf16x8*)swz32x64(UtBuf, 16 * dt + lm, s * 32 + kh);

        // m2: O = Qt*S0 + M*U  -> global (strided o_core)
        f32x4 oacc[2] = {};
#pragma unroll
        for (int dt = 0; dt < 2; dt++)
#pragma unroll
            for (int s = 0; s < 2; s++) {
                oacc[dt] = mfma16(qa[s], sf[dt][s], oacc[dt]);
                oacc[dt] = mfma16(ma[s], uf[dt][s], oacc[dt]);
            }
        {
            const int tok0 = b * Tc + c * CHUNK;
#pragma unroll
            for (int dt = 0; dt < 2; dt++)
#pragma unroll
                for (int rI = 0; rI < 4; rI++)
                    o[(size_t)(tok0 + 16 * wave + lq * 4 + rI) * ldo + colV + 16 * dt + lm] =
                        f2bf(oacc[dt][rI]);
        }
        // m3: S = gC*S + U^T * Kbar  (f32 accumulators, wave's dk-tile)
#pragma unroll
        for (int dt = 0; dt < 2; dt++) {
#pragma unroll
            for (int e = 0; e < 4; e++) Sacc[dt][e] *= gC;
#pragma unroll
            for (int s = 0; s < 2; s++)
                Sacc[dt] = mfma16(uf[dt][s], kb[s], Sacc[dt]);
        }
        __syncthreads();   // all Sb/Ut reads done before shadow overwrite
#pragma unroll
        for (int dt = 0; dt < 2; dt++)
#pragma unroll
            for (int rI = 0; rI < 4; rI++)
                *swz32x64(SbBuf, 16 * dt + lq * 4 + rI, 16 * wave + lm) = f2bf(Sacc[dt][rI]);
        __syncthreads();   // publish S shadow

        if (c + 1 < NCHK) {
#pragma unroll
            for (int s = 0; s < 2; s++) { wa[s] = wa2[s]; qa[s] = qa2[s]; ma[s] = ma2[s]; kb[s] = kb2[s]; }
#pragma unroll
            for (int dt = 0; dt < 2; dt++)
#pragma unroll
                for (int rI = 0; rI < 4; rI++) uvv[dt][rI] = uvv2[dt][rI];
        }
    }
}

// ---------------- host launch ----------------
extern "C" void kernel_launch(void* const* d_in, const int* in_sizes, int n_in,
                              void* d_out, int out_size, void* d_ws, size_t ws_size,
                              hipStream_t stream) {
    const float* x        = (const float*)d_in[0];
    const float* q_w      = (const float*)d_in[1];
    const float* k_w      = (const float*)d_in[2];
    const float* v_w      = (const float*)d_in[3];
    const float* q_scale  = (const float*)d_in[4];
    const float* k_scale  = (const float*)d_in[5];
    const float* v_scale  = (const float*)d_in[6];
    const float* q_conv_k = (const float*)d_in[7];
    const float* q_conv_b = (const float*)d_in[8];
    const float* k_conv_k = (const float*)d_in[9];
    const float* k_conv_b = (const float*)d_in[10];
    const float* v_conv_k = (const float*)d_in[11];
    const float* v_conv_b = (const float*)d_in[12];
    const float* alpha_w  = (const float*)d_in[13];
    const float* beta_w   = (const float*)d_in[14];
    const float* out_w    = (const float*)d_in[15];
    const float* gate_w   = (const float*)d_in[16];

    // ---- workspace (~208 MB) ----
    char* w = (char*)d_ws;
    bf16* xb  = (bf16*)w; w += (size_t)Mc * Dc * 2;          // 16 MB
    bf16* qwT = (bf16*)w; w += (size_t)QKDc * Dc * 2;        //  2 MB  -- qwT|kwT|vwT|gwT
    bf16* kwT = (bf16*)w; w += (size_t)QKDc * Dc * 2;        //  2 MB     contiguous =
    bf16* vwT = (bf16*)w; w += (size_t)VDc * Dc * 2;         //  4 MB     [5120][1024]
    bf16* gwT = (bf16*)w; w += (size_t)Dc * Dc * 2;          //  2 MB
    bf16* owT = (bf16*)w; w += (size_t)Dc * VDc * 2;         //  4 MB
    bf16* lin_all = (bf16*)w; w += (size_t)Mc * NPRJ * 2;    // 80 MB  [M][5120] q|k|v|g
    bf16* qf = (bf16*)w; w += (size_t)Mc * QKDc * 2;         // 16 MB  (conv q -> Qtilde)
    bf16* kf = (bf16*)w; w += (size_t)Mc * QKDc * 2;         // 16 MB  (conv k -> KbarT)
    bf16* vc = (bf16*)w; w += (size_t)Mc * VDc * 2;          // 32 MB  (conv v -> Uv)
    float* af = (float*)w; w += (size_t)Mc * Hc * 4;
    float* bfv = (float*)w; w += (size_t)Mc * Hc * 4;
    const int NCH_TOT = Bc * Hc * NCHK;                      // 2048 chunk-heads
    bf16* Wb = (bf16*)w; w += (size_t)NCH_TOT * 64 * 64 * 2; // 16 MB
    bf16* Mb = (bf16*)w; w += (size_t)NCH_TOT * 64 * 64 * 2; // 16 MB
    float* gamC = (float*)w; w += (size_t)NCH_TOT * 4;       //  8 KB
    // scan output goes into lin_all cols 0:2048 (q|k sections, dead after convs)
    bf16* o_core = lin_all;

    dim3 tb(32, 8);
    cast_f32_bf16<<<(Mc * Dc / 4 + 255) / 256, 256, 0, stream>>>(x, xb, Mc * Dc / 4);
    transpose_cast<<<dim3(QKDc / 32, Dc / 32), tb, 0, stream>>>(q_w, qwT, Dc, QKDc);
    transpose_cast<<<dim3(QKDc / 32, Dc / 32), tb, 0, stream>>>(k_w, kwT, Dc, QKDc);
    transpose_cast<<<dim3(VDc / 32, Dc / 32), tb, 0, stream>>>(v_w, vwT, Dc, VDc);
    transpose_cast<<<dim3(Dc / 32, Dc / 32), tb, 0, stream>>>(gate_w, gwT, Dc, Dc);
    transpose_cast<<<dim3(Dc / 32, VDc / 32), tb, 0, stream>>>(out_w, owT, VDc, Dc);

    // fused q|k|v|gate projection: pipelined 256x256 GEMM, single-barrier, depth-3
    gemm_pipe<<<GP_NT * GP_MT, 512, 0, stream>>>(xb, qwT, lin_all);

    // norms (strided rows inside lin_all), vectorized x8
    zc_rms_v<QKDc><<<Mc, QKDc / 8, 0, stream>>>(lin_all,        q_scale, NPRJ);
    zc_rms_v<QKDc><<<Mc, QKDc / 8, 0, stream>>>(lin_all + 1024, k_scale, NPRJ);
    zc_rms_v<VDc><<<Mc, VDc / 8, 0, stream>>>(lin_all + 2048,   v_scale, NPRJ);

    // convs: strided in, compact bf16 out, vectorized x8
    conv_silu_v<QKDc><<<Mc, QKDc / 8, 0, stream>>>(lin_all,        q_conv_k, q_conv_b, qf, NPRJ);
    conv_silu_v<QKDc><<<Mc, QKDc / 8, 0, stream>>>(lin_all + 1024, k_conv_k, k_conv_b, kf, NPRJ);
    conv_silu_v<VDc><<<Mc, VDc / 8, 0, stream>>>(lin_all + 2048,   v_conv_k, v_conv_b, vc, NPRJ);

    // alpha/beta via MFMA (hi/lo-split weights, f32-grade)
    alphabeta_mfma<<<Mc / 128, 256, 0, stream>>>(xb, alpha_w, beta_w, af, bfv);

    // chunked delta rule: parallel prep (per chunk-head), then 32-deep MFMA scan
    prep<<<dim3(NCHK, Bc * Hc), 256, 0, stream>>>(qf, kf, vc, af, bfv, Wb, Mb, gamC);
    chunkloop<<<dim3(4, Bc * Hc), 256, 0, stream>>>(qf, kf, vc, Wb, Mb, gamC, o_core, NPRJ);

    // out-projection: pipelined 128x256 GEMM (256 blocks, no tail) + fused gate
    gemm_pipe_out<<<256, 512, 0, stream>>>(o_core, owT, (float*)d_out, lin_all + 4096);
}

// Round 6
// 493.407 us; speedup vs baseline: 1.8693x; 1.0630x over previous
//
#include <hip/hip_runtime.h>

// ---------------- problem constants ----------------
#define Bc   4
#define Tc   2048
#define Dc   1024
#define Hc   16
#define DKc  64
#define DVc  128
#define QKDc 1024
#define VDc  2048
#define NPRJ 5120        // q|k|v|gate fused projection width
#define Mc   (Bc * Tc)   // 8192 tokens
#define CHUNK 64         // delta-rule chunk size
#define NCHK (Tc / CHUNK) // 32 chunks per (b,h)

typedef __bf16 bf16;
typedef __bf16 bf16x4 __attribute__((ext_vector_type(4)));
typedef __bf16 bf16x8 __attribute__((ext_vector_type(8)));
typedef float  f32x4  __attribute__((ext_vector_type(4)));

__device__ __forceinline__ float bf2f(bf16 v) { return (float)v; }
__device__ __forceinline__ bf16  f2bf(float v) { return (bf16)v; }
__device__ __forceinline__ float sigmoidf_(float x) { return 1.0f / (1.0f + __expf(-x)); }
__device__ __forceinline__ f32x4 mfma16(bf16x8 a, bf16x8 b, f32x4 c) {
    return __builtin_amdgcn_mfma_f32_16x16x32_bf16(a, b, c, 0, 0, 0);
}

// async global->LDS, 16B/lane; lds dest = wave-uniform base + lane*16
__device__ __forceinline__ void glds16(const bf16* g, void* l) {
    __builtin_amdgcn_global_load_lds((const __attribute__((address_space(1))) void*)g,
                                     (__attribute__((address_space(3))) void*)l, 16, 0, 0);
}

// XOR-swizzled addressing for [32][64] bf16 LDS tiles (bank-conflict-free b128
// column-slice reads; bijective within each row's 128B).
__device__ __forceinline__ bf16* swz32x64(bf16* base, int r, int k) {
    int byte = (((r << 6) + k) << 1) ^ ((r & 7) << 4);
    return (bf16*)((char*)base + byte);
}

// ---------------- cast fp32 -> bf16 ----------------
__global__ __launch_bounds__(256) void cast_f32_bf16(const float* __restrict__ src,
                                                     bf16* __restrict__ dst, int n4) {
    int i = blockIdx.x * 256 + threadIdx.x;
    if (i < n4) {
        float4 v = ((const float4*)src)[i];
        bf16x4 o = { f2bf(v.x), f2bf(v.y), f2bf(v.z), f2bf(v.w) };
        ((bf16x4*)dst)[i] = o;
    }
}

// ---------------- transpose + cast: fp32 [R][C] -> bf16 [C][R] ----------------
__global__ __launch_bounds__(256) void transpose_cast(const float* __restrict__ src,
                                                      bf16* __restrict__ dst,
                                                      int R, int C) {
    __shared__ float tile[32][33];
    int c0 = blockIdx.x * 32, r0 = blockIdx.y * 32;
    int tx = threadIdx.x, ty = threadIdx.y;
#pragma unroll
    for (int i = 0; i < 32; i += 8) {
        int r = r0 + ty + i, c = c0 + tx;
        tile[ty + i][tx] = (r < R && c < C) ? src[(size_t)r * C + c] : 0.0f;
    }
    __syncthreads();
#pragma unroll
    for (int i = 0; i < 32; i += 8) {
        int rr = c0 + ty + i, cc = r0 + tx;
        if (rr < C && cc < R) dst[(size_t)rr * R + cc] = f2bf(tile[tx][ty + i]);
    }
}

// ============ pipelined 256x256 GEMM: lin_all[M,5120] = xb[M,1024] @ W^T ============
// BK=32, ring of 4 K-tile LDS slots (A 16K + B 16K each = 128 KiB), 8 waves.
// Single barrier per K-tile (r3: extra barriers regress), counted vmcnt depth-3,
// compiler-issued counted lgkm waits. Round-5: 2-way read swizzle via (row>>1)
// XOR (was (row&3): rows {0,4,8,12} shared a slot -> 4-way conflict).
#define GP_NT 20          // N tiles (5120/256)
#define GP_MT 32          // M tiles (8192/256)
#define GP_NKT 32         // K tiles (1024/32)
__global__ __launch_bounds__(512, 2) void gemm_pipe(const bf16* __restrict__ A,
                                                    const bf16* __restrict__ Bt,
                                                    bf16* __restrict__ C) {
    __shared__ __align__(16) char lds[131072];
    const int tid = threadIdx.x;
    const int wid = tid >> 6, lane = tid & 63;
    const int lm = lane & 15, lq = lane >> 4;
    const int wm = wid >> 2, wn = wid & 3;

    // bijective XCD swizzle (640 blocks, 640/8 = 80)
    const int id = blockIdx.x;
    const int nid = (id & 7) * ((GP_NT * GP_MT) / 8) + (id >> 3);
    const int tn = nid % GP_NT, tm = nid / GP_NT;
    const int n0 = tn * 256, m0 = tm * 256;

    // staging source addresses: chunk r*512+tid -> row r*128+(tid>>2);
    // physical 16B slot tid&3 holds logical slot (tid&3)^((row>>1)&3)
    const int r0 = tid >> 2;
    const int lsx = ((tid & 3) ^ ((r0 >> 1) & 3)) << 3;
    const bf16* sA0 = A  + (size_t)(m0 + r0) * Dc + lsx;
    const bf16* sA1 = sA0 + (size_t)128 * Dc;
    const bf16* sB0 = Bt + (size_t)(n0 + r0) * Dc + lsx;
    const bf16* sB1 = sB0 + (size_t)128 * Dc;

    auto stageA = [&](int kt) {
        char* d = lds + ((kt & 3) << 15) + wid * 1024;
        glds16(sA0 + kt * 32, d);
        glds16(sA1 + kt * 32, d + 8192);
    };
    auto stageB = [&](int kt) {
        char* d = lds + ((kt & 3) << 15) + 16384 + wid * 1024;
        glds16(sB0 + kt * 32, d);
        glds16(sB1 + kt * 32, d + 8192);
    };

    f32x4 acc[8][4] = {};
    const int sx = (lq ^ ((lm >> 1) & 3)) << 3;   // swizzled K-slot for reads
    const int aoff = wm * 4096 + lm * 32 + sx;    // elem offset in A region
    const int boff = wn * 2048 + lm * 32 + sx;    // elem offset in B region

    stageA(0); stageB(0); stageA(1); stageB(1); stageA(2); stageB(2);
    asm volatile("s_waitcnt vmcnt(8)" ::: "memory");
    asm volatile("s_barrier" ::: "memory");

    for (int kt = 0; kt < GP_NKT; kt++) {
        const bf16* sA = (const bf16*)(lds + ((kt & 3) << 15));
        const bf16* sB = (const bf16*)(lds + ((kt & 3) << 15) + 16384);
        bf16x8 aF[4], bF[4], aG[4];
#pragma unroll
        for (int i = 0; i < 4; i++) aF[i] = *(const bf16x8*)&sA[aoff + i * 512];
#pragma unroll
        for (int j = 0; j < 4; j++) bF[j] = *(const bf16x8*)&sB[boff + j * 512];
#pragma unroll
        for (int i = 0; i < 4; i++) aG[i] = *(const bf16x8*)&sA[aoff + (i + 4) * 512];
        if (kt + 3 < GP_NKT) { stageA(kt + 3); stageB(kt + 3); }
        __builtin_amdgcn_s_setprio(1);
#pragma unroll
        for (int i = 0; i < 4; i++)
#pragma unroll
            for (int j = 0; j < 4; j++)
                acc[i][j] = mfma16(aF[i], bF[j], acc[i][j]);
#pragma unroll
        for (int i = 0; i < 4; i++)
#pragma unroll
            for (int j = 0; j < 4; j++)
                acc[i + 4][j] = mfma16(aG[i], bF[j], acc[i + 4][j]);
        __builtin_amdgcn_s_setprio(0);
        if (kt + 3 < GP_NKT)      asm volatile("s_waitcnt vmcnt(8)" ::: "memory");
        else if (kt + 2 < GP_NKT) asm volatile("s_waitcnt vmcnt(4)" ::: "memory");
        else                      asm volatile("s_waitcnt vmcnt(0)" ::: "memory");
        asm volatile("s_barrier" ::: "memory");
    }

    const int rbase = m0 + wm * 128 + lq * 4;
    const int cbase = n0 + wn * 64 + lm;
#pragma unroll
    for (int i = 0; i < 8; i++)
#pragma unroll
        for (int j = 0; j < 4; j++)
#pragma unroll
            for (int rI = 0; rI < 4; rI++)
                C[(size_t)(rbase + i * 16 + rI) * NPRJ + cbase + j * 16] =
                    f2bf(acc[i][j][rI]);
}

// ============ pipelined out-projection: d_out[M,1024] = o_core @ owT^T, gated ============
// 128(M)x256(N) tiles -> exactly 256 blocks (no tail). BK=32, ring-4 (24 KB/slot,
// 96 KiB), depth-3 prefetch (3 loads/K-tile -> vmcnt(6)/(3)/(0)). Gate fused.
#define GO_NKT 64         // K tiles (2048/32)
__global__ __launch_bounds__(512, 2) void gemm_pipe_out(const bf16* __restrict__ A,
                                                        const bf16* __restrict__ Bt,
                                                        float* __restrict__ C,
                                                        const bf16* __restrict__ gate) {
    __shared__ __align__(16) char lds[98304];
    const int tid = threadIdx.x;
    const int wid = tid >> 6, lane = tid & 63;
    const int lm = lane & 15, lq = lane >> 4;
    const int wm = wid >> 2, wn = wid & 3;     // 2M x 4N waves, per-wave 64x64

    const int id = blockIdx.x;                  // 256 blocks
    const int nid = (id & 7) * 32 + (id >> 3);  // bijective XCD swizzle
    const int tm = nid >> 2, tn = nid & 3;      // 64 M-tiles x 4 N-tiles
    const int m0 = tm * 128, n0 = tn * 256;

    const int r0 = tid >> 2;
    const int lsx = ((tid & 3) ^ ((r0 >> 1) & 3)) << 3;
    const bf16* sAp = A  + (size_t)(m0 + r0) * NPRJ + lsx;      // strided o_core
    const bf16* sB0 = Bt + (size_t)(n0 + r0) * VDc + lsx;
    const bf16* sB1 = sB0 + (size_t)128 * VDc;

    auto stageA = [&](int kt) {
        glds16(sAp + kt * 32, lds + (kt & 3) * 24576 + wid * 1024);
    };
    auto stageB = [&](int kt) {
        char* d = lds + (kt & 3) * 24576 + 8192 + wid * 1024;
        glds16(sB0 + kt * 32, d);
        glds16(sB1 + kt * 32, d + 8192);
    };

    f32x4 acc[4][4] = {};
    const int sx = (lq ^ ((lm >> 1) & 3)) << 3;
    const int aoff = wm * 2048 + lm * 32 + sx;    // A region: 128 rows
    const int boff = wn * 2048 + lm * 32 + sx;    // B region: 256 rows

    stageA(0); stageB(0); stageA(1); stageB(1); stageA(2); stageB(2);
    asm volatile("s_waitcnt vmcnt(6)" ::: "memory");
    asm volatile("s_barrier" ::: "memory");

    for (int kt = 0; kt < GO_NKT; kt++) {
        const bf16* sA = (const bf16*)(lds + (kt & 3) * 24576);
        const bf16* sB = sA + 4096;
        bf16x8 a[4], b[4];
#pragma unroll
        for (int i = 0; i < 4; i++) a[i] = *(const bf16x8*)&sA[aoff + i * 512];
#pragma unroll
        for (int j = 0; j < 4; j++) b[j] = *(const bf16x8*)&sB[boff + j * 512];
        if (kt + 3 < GO_NKT) { stageA(kt + 3); stageB(kt + 3); }
        __builtin_amdgcn_s_setprio(1);
#pragma unroll
        for (int i = 0; i < 4; i++)
#pragma unroll
            for (int j = 0; j < 4; j++)
                acc[i][j] = mfma16(a[i], b[j], acc[i][j]);
        __builtin_amdgcn_s_setprio(0);
        if (kt + 3 < GO_NKT)      asm volatile("s_waitcnt vmcnt(6)" ::: "memory");
        else if (kt + 2 < GO_NKT) asm volatile("s_waitcnt vmcnt(3)" ::: "memory");
        else                      asm volatile("s_waitcnt vmcnt(0)" ::: "memory");
        asm volatile("s_barrier" ::: "memory");
    }

    const int rbase = m0 + wm * 64 + lq * 4;
    const int cbase = n0 + wn * 64 + lm;
#pragma unroll
    for (int i = 0; i < 4; i++)
#pragma unroll
        for (int j = 0; j < 4; j++)
#pragma unroll
            for (int rI = 0; rI < 4; rI++) {
                int row = rbase + i * 16 + rI;
                int col = cbase + j * 16;
                float g = bf2f(gate[(size_t)row * NPRJ + col]);
                C[(size_t)row * Dc + col] = acc[i][j][rI] * sigmoidf_(g);
            }
}

// ---------------- fused zc-RMSNorm + causal conv(K=4) + SiLU ----------------
// Block per token; stats for the 4 tap rows recomputed in-register (each row's
// stats also computed by 3 neighbor blocks — pure recompute, L2-hot reads).
// Replaces separate rms (in-place write) + conv (re-read): saves 32MB/tensor
// of HBM round-trip + 3 launches. Normalized taps stay f32 (>= old accuracy).
template <int CCH>
__global__ __launch_bounds__(256) void normconv(const bf16* __restrict__ xn,
                                                const float* __restrict__ scale,
                                                const float* __restrict__ kern,
                                                const float* __restrict__ bias,
                                                bf16* __restrict__ out, int ldin) {
    constexpr int NW = CCH / 8 / 64;     // waves: 2 (CCH=1024) or 4 (CCH=2048)
    const int btok = blockIdx.x;
    const int tt = btok & (Tc - 1);
    const int t = threadIdx.x;
    const int c8 = t * 8;

    float xv[4][8];
    float s[4] = {}, s2[4] = {};
#pragma unroll
    for (int i = 0; i < 4; i++) {
        if (tt - 3 + i >= 0) {
            bf16x8 v = *(const bf16x8*)&xn[(size_t)(btok - 3 + i) * ldin + c8];
#pragma unroll
            for (int e = 0; e < 8; e++) {
                float x = bf2f(v[e]);
                xv[i][e] = x; s[i] += x; s2[i] += x * x;
            }
        }
    }
    __shared__ float red[NW][8];
#pragma unroll
    for (int o = 32; o > 0; o >>= 1)
#pragma unroll
        for (int i = 0; i < 4; i++) {
            s[i]  += __shfl_down(s[i],  o, 64);
            s2[i] += __shfl_down(s2[i], o, 64);
        }
    if ((t & 63) == 0)
#pragma unroll
        for (int i = 0; i < 4; i++) { red[t >> 6][i] = s[i]; red[t >> 6][4 + i] = s2[i]; }
    __syncthreads();
#pragma unroll
    for (int i = 0; i < 4; i++) {
        s[i] = 0.f; s2[i] = 0.f;
#pragma unroll
        for (int w = 0; w < NW; w++) { s[i] += red[w][i]; s2[i] += red[w][4 + i]; }
    }

    float4 sc0 = *(const float4*)&scale[c8], sc1 = *(const float4*)&scale[c8 + 4];
    float sc[8] = { sc0.x, sc0.y, sc0.z, sc0.w, sc1.x, sc1.y, sc1.z, sc1.w };
    float4 b0 = *(const float4*)&bias[c8], b1 = *(const float4*)&bias[c8 + 4];
    float acc[8] = { b0.x, b0.y, b0.z, b0.w, b1.x, b1.y, b1.z, b1.w };
#pragma unroll
    for (int i = 0; i < 4; i++) {
        if (tt - 3 + i >= 0) {
            float mean = s[i] / (float)CCH;
            float inv = rsqrtf(s2[i] / (float)CCH - mean * mean + 1e-5f);
            float4 k0 = *(const float4*)&kern[i * CCH + c8];
            float4 k1 = *(const float4*)&kern[i * CCH + c8 + 4];
            float kk[8] = { k0.x, k0.y, k0.z, k0.w, k1.x, k1.y, k1.z, k1.w };
#pragma unroll
            for (int e = 0; e < 8; e++)
                acc[e] += (xv[i][e] - mean) * inv * sc[e] * kk[e];
        }
    }
    bf16x8 o;
#pragma unroll
    for (int e = 0; e < 8; e++) {
        float y = acc[e] * sigmoidf_(acc[e]);
        o[e] = f2bf(y);
    }
    *(bf16x8*)&out[(size_t)btok * CCH + c8] = o;
}

// ---------------- alpha/beta via MFMA: sigmoid(x @ [aw|bw]), hi/lo-split weights ----------------
__global__ __launch_bounds__(256) void alphabeta_mfma(const bf16* __restrict__ x,
                                                      const float* __restrict__ aw,
                                                      const float* __restrict__ bw,
                                                      float* __restrict__ af,
                                                      float* __restrict__ bfv) {
    __shared__ bf16 whi[32][136];
    __shared__ bf16 wlo[32][136];
    const int tid = threadIdx.x, wave = tid >> 6, lane = tid & 63;
    const int lm = lane & 15, lq = lane >> 4;
    const int m0 = blockIdx.x * 128;
    f32x4 acc[2][2] = {};

    for (int k0 = 0; k0 < Dc; k0 += 128) {
        for (int idx = tid; idx < 4096; idx += 256) {
            int n = idx & 31, kk = idx >> 5;
            float v = (n < 16) ? aw[(size_t)(k0 + kk) * Hc + n]
                               : bw[(size_t)(k0 + kk) * Hc + (n - 16)];
            bf16 h = f2bf(v);
            whi[n][kk] = h;
            wlo[n][kk] = f2bf(v - bf2f(h));
        }
        __syncthreads();
#pragma unroll
        for (int ks = 0; ks < 4; ks++) {
            bf16x8 bh[2], bl[2];
#pragma unroll
            for (int j = 0; j < 2; j++) {
                bh[j] = *(const bf16x8*)&whi[j * 16 + lm][ks * 32 + lq * 8];
                bl[j] = *(const bf16x8*)&wlo[j * 16 + lm][ks * 32 + lq * 8];
            }
#pragma unroll
            for (int ii = 0; ii < 2; ii++) {
                int row = m0 + wave * 32 + ii * 16 + lm;
                bf16x8 a = *(const bf16x8*)&x[(size_t)row * Dc + k0 + ks * 32 + lq * 8];
#pragma unroll
                for (int j = 0; j < 2; j++) {
                    acc[ii][j] = mfma16(a, bh[j], acc[ii][j]);
                    acc[ii][j] = mfma16(a, bl[j], acc[ii][j]);
                }
            }
        }
        __syncthreads();
    }
#pragma unroll
    for (int ii = 0; ii < 2; ii++)
#pragma unroll
        for (int rI = 0; rI < 4; rI++) {
            int row = m0 + wave * 32 + ii * 16 + lq * 4 + rI;
            af[(size_t)row * Hc + lm]  = sigmoidf_(acc[ii][0][rI]);
            bfv[(size_t)row * Hc + lm] = sigmoidf_(acc[ii][1][rI]);
        }
}

// ================= chunked gated delta rule =================
// Chunk (C=64) closed form with gamma_i = prod_{s<=i} a_s:
//   A_ij = b_i (g_i/g_j) k_i.k_j (j<i);  (I+A) U = diag(b)V - diag(b g) K S0
//   U = Uv - W S0,  Uv = T diag(b)V,  W = T diag(b g)K,  T = (I+A)^-1
//   O  = diag(g) Q S0 + M U,  M_ij = (g_i/g_j) q_i.k_j (j<=i)
//   S' = g_C S0 + Kbar^T U,   Kbar_j = (g_C/g_j) k_j
// T via BLOCKED inversion: 4 diagonal 16x16 register inverses + MFMA
// off-diagonal combines with bf16 hi/lo split (~f32 accuracy).
__global__ __launch_bounds__(256) void prep(bf16* __restrict__ qf,
                                            bf16* __restrict__ kf,
                                            bf16* __restrict__ vc,
                                            const float* __restrict__ af,
                                            const float* __restrict__ bfv,
                                            bf16* __restrict__ Wb,
                                            bf16* __restrict__ Mb,
                                            float* __restrict__ gamC) {
    __shared__ __align__(16) char smem[53248];
    bf16*  Kc   = (bf16*)(smem);             // [64][72] bf16, live whole kernel
    bf16*  Qc   = (bf16*)(smem + 9216);      // [64][72] bf16 (phase B only)
    float* DT   = (float*)(smem + 9216);     // [4][16][17] f32: I_g^T (solve)
    float* Pn   = (float*)(smem + 13568);    // [2][16][17] f32: -P^T pair L/H
    float* TT   = (float*)(smem + 15744);    // [16][17] f32: T10^T
    float* Qn   = (float*)(smem + 9216);     // [32][33] f32 (overlays DT, s3+)
    bf16*  Tb   = (bf16*)(smem + 9216);      // [64][72] bf16 T (after s4)
    float* As   = (float*)(smem + 18432);    // [64][65] f32
    bf16*  Vtb  = (bf16*)(smem + 18432);     // [128][72] bf16 (after Tb copy)
    float* Ts   = (float*)(smem + 35072);    // [64][65] f32
    float* lg_s = (float*)(smem + 51712);    // 64 log2-cumsum
    float* bv_s = lg_s + 64;                 // b_i
    float* bg_s = lg_s + 128;                // b_i * g_i
    float* gm_s = lg_s + 192;                // g_i
    float* kr_s = lg_s + 256;                // g_C / g_i

    const int c    = blockIdx.x;
    const int bh   = blockIdx.y;
    const int b    = bh >> 4, h = bh & 15;
    const int ch   = bh * NCHK + c;
    const int tok0 = b * Tc + c * CHUNK;
    const int tid  = threadIdx.x;
    const int wave = tid >> 6, lane = tid & 63;
    const int lm = lane & 15, lq = lane >> 4, kh = lq * 8;

    // ---- phase A: stage K,Q; zero Ts (upper blocks are never written); ab prefix
#pragma unroll
    for (int r = 0; r < 2; r++) {
        int idx = tid + r * 256;
        int row = idx >> 3, c8 = (idx & 7) * 8;
        *(bf16x8*)&Kc[row * 72 + c8] =
            *(const bf16x8*)&kf[(size_t)(tok0 + row) * QKDc + h * DKc + c8];
        *(bf16x8*)&Qc[row * 72 + c8] =
            *(const bf16x8*)&qf[(size_t)(tok0 + row) * QKDc + h * DKc + c8];
    }
    for (int idx = tid; idx < 64 * 65; idx += 256) Ts[idx] = 0.f;
    if (tid < 64) {
        float a  = af[(size_t)(tok0 + tid) * Hc + h];
        float bb = bfv[(size_t)(tok0 + tid) * Hc + h];
        float la = __log2f(fmaxf(a, 1e-30f));
#pragma unroll
        for (int o = 1; o < 64; o <<= 1) {       // inclusive prefix sum
            float t = __shfl_up(la, o, 64);
            if (tid >= o) la += t;
        }
        float lgC = __shfl(la, 63, 64);
        lg_s[tid] = la;
        bv_s[tid] = bb;
        float g   = exp2f(la);
        gm_s[tid] = g;
        bg_s[tid] = bb * g;
        kr_s[tid] = exp2f(lgC - la);
        if (tid == 0) gamC[ch] = exp2f(lgC);
    }
    __syncthreads();

    // ---- phase B: KK^T -> A; QK^T -> M; Qtilde/KbarT global writes
    {
        bf16x8 ka[2], qa[2];
#pragma unroll
        for (int s = 0; s < 2; s++) {
            ka[s] = *(const bf16x8*)&Kc[(16 * wave + lm) * 72 + s * 32 + kh];
            qa[s] = *(const bf16x8*)&Qc[(16 * wave + lm) * 72 + s * 32 + kh];
        }
#pragma unroll
        for (int jt = 0; jt < 4; jt++) {
            f32x4 kkacc = {}, qkacc = {};
#pragma unroll
            for (int s = 0; s < 2; s++) {
                bf16x8 kbf = *(const bf16x8*)&Kc[(16 * jt + lm) * 72 + s * 32 + kh];
                kkacc = mfma16(ka[s], kbf, kkacc);
                qkacc = mfma16(qa[s], kbf, qkacc);
            }
#pragma unroll
            for (int rI = 0; rI < 4; rI++) {
                int i = 16 * wave + lq * 4 + rI;
                int j = 16 * jt + lm;
                float ratio = exp2f(lg_s[i] - lg_s[j]);
                As[i * 65 + j] = (j < i) ? bv_s[i] * ratio * kkacc[rI] : 0.f;
                Mb[((size_t)ch * 64 + i) * 64 + j] =
                    (j <= i) ? f2bf(ratio * qkacc[rI]) : f2bf(0.f);
            }
        }
    }
    {   // Qtilde -> qf (in place); KbarT -> kf (in place, transposed [d][j])
#pragma unroll
        for (int r = 0; r < 2; r++) {
            int idx = tid + r * 256;
            int row = idx >> 3, c8 = (idx & 7) * 8;
            bf16x8 v = *(const bf16x8*)&Qc[row * 72 + c8];
            float g = gm_s[row];
            bf16x8 oq;
#pragma unroll
            for (int e = 0; e < 8; e++) oq[e] = f2bf(bf2f(v[e]) * g);
            *(bf16x8*)&qf[(size_t)(tok0 + row) * QKDc + h * DKc + c8] = oq;
            bf16x8 ok;
#pragma unroll
            for (int e = 0; e < 8; e++)
                ok[e] = f2bf(kr_s[c8 + e] * bf2f(Kc[(c8 + e) * 72 + row]));
            *(bf16x8*)&kf[(size_t)(tok0 + row) * QKDc + h * DKc + c8] = ok;
        }
    }
    __syncthreads();   // As complete; Qc dead -> DT/Pn/TT scratch usable

    // ---- phase C: 4 diagonal 16x16 inverses in registers (wave 0) ----
    if (tid < 64) {
        const int g = lane >> 4, jj = lane & 15, base = lane & 48;
        float areg[16], tcol[16];
#pragma unroll
        for (int i = 0; i < 16; i++) areg[i] = As[(16 * g + i) * 65 + 16 * g + jj];
#pragma unroll
        for (int i = 0; i < 16; i++) tcol[i] = (i == jj) ? 1.f : 0.f;
#pragma unroll
        for (int i = 1; i < 16; i++) {
            float s = 0.f;
#pragma unroll
            for (int m = 0; m < i; m++)
                s = fmaf(__shfl(areg[i], base + m, 64), tcol[m], s);
            tcol[i] = (i == jj) ? 1.f : -s;
        }
#pragma unroll
        for (int i = 0; i < 16; i++) {
            Ts[(16 * g + i) * 65 + 16 * g + jj] = tcol[i];   // I_g row-major
            DT[g * 272 + jj * 17 + i] = tcol[i];             // I_g^T row-major
        }
    }
    __syncthreads();

    // ---- s1: Pn = -(I_{2w}^T * A_off^T), pairs L(w=0): A10, H(w=1): A32. K=16
    if (wave < 2) {
        const int w = wave;
        bf16x8 ah, al, bh, bl;
#pragma unroll
        for (int e = 0; e < 8; e++) {
            int k = kh + e;
            float xa = (k < 16) ? DT[2 * w * 272 + lm * 17 + k] : 0.f;
            bf16 ha = f2bf(xa); ah[e] = ha; al[e] = f2bf(xa - bf2f(ha));
            float xb = (k < 16) ? As[(16 + 32 * w + lm) * 65 + 32 * w + k] : 0.f;
            bf16 hb = f2bf(xb); bh[e] = hb; bl[e] = f2bf(xb - bf2f(hb));
        }
        f32x4 acc = {};
        acc = mfma16(ah, bh, acc); acc = mfma16(ah, bl, acc); acc = mfma16(al, bh, acc);
#pragma unroll
        for (int rI = 0; rI < 4; rI++)
            Pn[w * 272 + (lq * 4 + rI) * 17 + lm] = -acc[rI];
    }
    __syncthreads();

    // ---- s2: T10 -> Ts[16:32,0:16]; T10^T -> TT; T32 -> Ts[48:64,32:48]. K=16
    if (wave < 3) {
        bf16x8 ah, al, bh, bl;
#pragma unroll
        for (int e = 0; e < 8; e++) {
            int k = kh + e;
            float xa = 0.f, xb = 0.f;
            if (k < 16) {
                if (wave == 0)      { xa = Ts[(16 + lm) * 65 + 16 + k]; xb = Pn[lm * 17 + k]; }
                else if (wave == 1) { xa = Pn[lm * 17 + k];             xb = Ts[(16 + lm) * 65 + 16 + k]; }
                else                { xa = Ts[(48 + lm) * 65 + 48 + k]; xb = Pn[272 + lm * 17 + k]; }
            }
            bf16 ha = f2bf(xa); ah[e] = ha; al[e] = f2bf(xa - bf2f(ha));
            bf16 hb = f2bf(xb); bh[e] = hb; bl[e] = f2bf(xb - bf2f(hb));
        }
        f32x4 acc = {};
        acc = mfma16(ah, bh, acc); acc = mfma16(ah, bl, acc); acc = mfma16(al, bh, acc);
#pragma unroll
        for (int rI = 0; rI < 4; rI++) {
            int ro = lq * 4 + rI;
            if (wave == 0)      Ts[(16 + ro) * 65 + lm]      = acc[rI];
            else if (wave == 1) TT[ro * 17 + lm]             = acc[rI];
            else                Ts[(48 + ro) * 65 + 32 + lm] = acc[rI];
        }
    }
    __syncthreads();

    // ---- s3: Qn = -(iL1^T * A_BL^T), 32x32, K=32; tile (a,b) per wave.
    {
        const int a = wave >> 1, bq = wave & 1;
        bf16x8 ah, al, bh, bl;
#pragma unroll
        for (int e = 0; e < 8; e++) {
            int k = kh + e;  // 0..31
            float xa;
            if (a == 0) xa = (k < 16) ? DT[lm * 17 + k] : TT[lm * 17 + (k - 16)];
            else        xa = (k < 16) ? 0.f : DT[272 + lm * 17 + (k - 16)];
            bf16 ha = f2bf(xa); ah[e] = ha; al[e] = f2bf(xa - bf2f(ha));
            float xb = As[(32 + 16 * bq + lm) * 65 + k];
            bf16 hb = f2bf(xb); bh[e] = hb; bl[e] = f2bf(xb - bf2f(hb));
        }
        f32x4 acc = {};
        acc = mfma16(ah, bh, acc); acc = mfma16(ah, bl, acc); acc = mfma16(al, bh, acc);
        __syncthreads();   // all DT/TT reads done before Qn overlays DT
#pragma unroll
        for (int rI = 0; rI < 4; rI++)
            Qn[(16 * a + lq * 4 + rI) * 33 + 16 * bq + lm] = -acc[rI];
    }
    __syncthreads();

    // ---- s4: T_BL = mfma(R(iL2), R(Qn)) -> Ts[32:64, 0:32]. K=32
    {
        const int a = wave >> 1, bq = wave & 1;
        bf16x8 ah, al, bh, bl;
#pragma unroll
        for (int e = 0; e < 8; e++) {
            int k = kh + e;  // 0..31
            float xa = Ts[(32 + 16 * a + lm) * 65 + 32 + k];
            bf16 ha = f2bf(xa); ah[e] = ha; al[e] = f2bf(xa - bf2f(ha));
            float xb = Qn[(16 * bq + lm) * 33 + k];
            bf16 hb = f2bf(xb); bh[e] = hb; bl[e] = f2bf(xb - bf2f(hb));
        }
        f32x4 acc = {};
        acc = mfma16(ah, bh, acc); acc = mfma16(ah, bl, acc); acc = mfma16(al, bh, acc);
#pragma unroll
        for (int rI = 0; rI < 4; rI++)
            Ts[(32 + 16 * a + lq * 4 + rI) * 65 + 16 * bq + lm] = acc[rI];
    }
    __syncthreads();

    // ---- Tb = bf16(Ts) into Qc region (solve scratch dead) ----
    for (int idx = tid; idx < 4096; idx += 256) {
        int i = idx >> 6, j = idx & 63;
        Tb[i * 72 + j] = f2bf(Ts[i * 65 + j]);
    }
    __syncthreads();                      // Ts dead; Vtb may overlay As/Ts-head
    // Vtb = (diag(b) V)^T [128][72]. Round-5 mapping: threads iterate j minor
    // (16 lanes -> 16 j's of one d-row) => per-e write banks = 8*(l>>4) +
    // ((l&15)>>1) + 36e mod 32: 32 distinct -> conflict-free (was 16-way).
#pragma unroll
    for (int r = 0; r < 4; r++) {
        int j = r * 16 + (tid & 15);
        int dbase = (tid >> 4) * 8;
        bf16x8 v = *(const bf16x8*)&vc[(size_t)(tok0 + j) * VDc + h * DVc + dbase];
        float bb = bv_s[j];
#pragma unroll
        for (int e = 0; e < 8; e++)
            Vtb[(dbase + e) * 72 + j] = f2bf(bf2f(v[e]) * bb);
    }
    __syncthreads();
    {   // W = T diag(b g) K -> Wb;  Uv = T diag(b) V -> vc (in place)
        bf16x8 ta[2];
#pragma unroll
        for (int s = 0; s < 2; s++)
            ta[s] = *(const bf16x8*)&Tb[(16 * wave + lm) * 72 + s * 32 + kh];
#pragma unroll
        for (int dt = 0; dt < 4; dt++) {
            f32x4 wacc = {};
#pragma unroll
            for (int s = 0; s < 2; s++) {
                bf16x8 wbf;
                int d = 16 * dt + lm;
#pragma unroll
                for (int e = 0; e < 8; e++) {
                    int j = s * 32 + kh + e;
                    wbf[e] = f2bf(bg_s[j] * bf2f(Kc[j * 72 + d]));
                }
                wacc = mfma16(ta[s], wbf, wacc);
            }
#pragma unroll
            for (int rI = 0; rI < 4; rI++) {
                int i = 16 * wave + lq * 4 + rI;
                Wb[((size_t)ch * 64 + i) * 64 + 16 * dt + lm] = f2bf(wacc[rI]);
            }
        }
#pragma unroll
        for (int dt = 0; dt < 8; dt++) {
            f32x4 uacc = {};
#pragma unroll
            for (int s = 0; s < 2; s++) {
                bf16x8 vb = *(const bf16x8*)&Vtb[(16 * dt + lm) * 72 + s * 32 + kh];
                uacc = mfma16(ta[s], vb, uacc);
            }
#pragma unroll
            for (int rI = 0; rI < 4; rI++) {
                int i = 16 * wave + lq * 4 + rI;
                vc[(size_t)(tok0 + i) * VDc + h * DVc + 16 * dt + lm] = f2bf(uacc[rI]);
            }
        }
    }
}

// Sequential part: 32 chunk steps per (b,h), dv split 4 ways -> 256 blocks.
// Round-5: XCD-grouped mapping — the 4 vg blocks of one bh land on the SAME
// XCD (hw round-robin: XCD = blockIdx % 8), so W/M/q/k fetches (shared across
// vg) hit that XCD's L2 instead of 4 separate L2s re-fetching from L3/HBM.
__global__ __launch_bounds__(256) void chunkloop(const bf16* __restrict__ qf,
                                                 const bf16* __restrict__ kf,
                                                 const bf16* __restrict__ vc,
                                                 const bf16* __restrict__ Wb,
                                                 const bf16* __restrict__ Mb,
                                                 const float* __restrict__ gamC,
                                                 bf16* __restrict__ o, int ldo) {
    const int bi = blockIdx.x;           // 0..255
    const int xcd = bi & 7;
    const int r8 = bi >> 3;              // 0..31
    const int bh = xcd * 8 + (r8 & 7);   // 8 bh per XCD
    const int vg = r8 >> 3;              // 0..3, co-located with its bh peers
    const int b = bh >> 4, h = bh & 15;
    const int tid = threadIdx.x;
    const int wave = tid >> 6, lane = tid & 63;
    const int lm = lane & 15, lq = lane >> 4, kh = lq * 8;

    __shared__ __align__(16) bf16 SbBuf[32 * 64];   // S^T shadow [dv][dk]
    __shared__ __align__(16) bf16 UtBuf[32 * 64];   // U^T [dv][t]

    for (int idx = tid; idx < 32 * 64; idx += 256) SbBuf[idx] = f2bf(0.f);

    f32x4 Sacc[2] = {};                  // wave's dk-tile = wave; dv tiles 0,1

    const int colK = h * DKc;
    const int colV = h * DVc + vg * 32;

    bf16x8 wa[2], qa[2], ma[2], kb[2];
    bf16 uvv[2][4];

    auto loadFrags = [&](int c, bf16x8 (&wa_)[2], bf16x8 (&qa_)[2], bf16x8 (&ma_)[2],
                         bf16x8 (&kb_)[2], bf16 (&uvv_)[2][4]) {
        const int tok0 = b * Tc + c * CHUNK;
        const size_t chb = ((size_t)bh * NCHK + c) * 64;
#pragma unroll
        for (int s = 0; s < 2; s++) {
            wa_[s] = *(const bf16x8*)&Wb[(chb + 16 * wave + lm) * 64 + s * 32 + kh];
            ma_[s] = *(const bf16x8*)&Mb[(chb + 16 * wave + lm) * 64 + s * 32 + kh];
            qa_[s] = *(const bf16x8*)&qf[(size_t)(tok0 + 16 * wave + lm) * QKDc + colK + s * 32 + kh];
            kb_[s] = *(const bf16x8*)&kf[(size_t)(tok0 + 16 * wave + lm) * QKDc + colK + s * 32 + kh];
        }
#pragma unroll
        for (int dt = 0; dt < 2; dt++)
#pragma unroll
            for (int rI = 0; rI < 4; rI++)
                uvv_[dt][rI] =
                    vc[(size_t)(tok0 + 16 * wave + lq * 4 + rI) * VDc + colV + 16 * dt + lm];
    };

    loadFrags(0, wa, qa, ma, kb, uvv);
    __syncthreads();

    for (int c = 0; c < NCHK; c++) {
        const float gC = gamC[(size_t)bh * NCHK + c];
        bf16x8 sf[2][2];
#pragma unroll
        for (int dt = 0; dt < 2; dt++)
#pragma unroll
            for (int s = 0; s < 2; s++)
                sf[dt][s] = *(const bf16x8*)swz32x64(SbBuf, 16 * dt + lm, s * 32 + kh);
        // m1: P = W * S0
        f32x4 pacc[2] = {};
#pragma unroll
        for (int dt = 0; dt < 2; dt++)
#pragma unroll
            for (int s = 0; s < 2; s++)
                pacc[dt] = mfma16(wa[s], sf[dt][s], pacc[dt]);

        // prefetch next chunk's fragments (global only)
        bf16x8 wa2[2], qa2[2], ma2[2], kb2[2];
        bf16 uvv2[2][4];
        if (c + 1 < NCHK) loadFrags(c + 1, wa2, qa2, ma2, kb2, uvv2);

        // U = Uv - P  -> Ut (transposed, swizzled)
#pragma unroll
        for (int dt = 0; dt < 2; dt++)
#pragma unroll
            for (int rI = 0; rI < 4; rI++) {
                float u = bf2f(uvv[dt][rI]) - pacc[dt][rI];
                *swz32x64(UtBuf, 16 * dt + lm, 16 * wave + lq * 4 + rI) = f2bf(u);
            }
        __syncthreads();   // publish Ut

        bf16x8 uf[2][2];
#pragma unroll
        for (int dt = 0; dt < 2; dt++)
#pragma unroll
            for (int s = 0; s < 2; s++)
                uf[dt][s] = *(const bf16x8*)swz32x64(UtBuf, 16 * dt + lm, s * 32 + kh);

        // m2: O = Qt*S0 + M*U  -> global (strided o_core)
        f32x4 oacc[2] = {};
#pragma unroll
        for (int dt = 0; dt < 2; dt++)
#pragma unroll
            for (int s = 0; s < 2; s++) {
                oacc[dt] = mfma16(qa[s], sf[dt][s], oacc[dt]);
                oacc[dt] = mfma16(ma[s], uf[dt][s], oacc[dt]);
            }
        {
            const int tok0 = b * Tc + c * CHUNK;
#pragma unroll
            for (int dt = 0; dt < 2; dt++)
#pragma unroll
                for (int rI = 0; rI < 4; rI++)
                    o[(size_t)(tok0 + 16 * wave + lq * 4 + rI) * ldo + colV + 16 * dt + lm] =
                        f2bf(oacc[dt][rI]);
        }
        // m3: S = gC*S + U^T * Kbar  (f32 accumulators, wave's dk-tile)
#pragma unroll
        for (int dt = 0; dt < 2; dt++) {
#pragma unroll
            for (int e = 0; e < 4; e++) Sacc[dt][e] *= gC;
#pragma unroll
            for (int s = 0; s < 2; s++)
                Sacc[dt] = mfma16(uf[dt][s], kb[s], Sacc[dt]);
        }
        __syncthreads();   // all Sb/Ut reads done before shadow overwrite
#pragma unroll
        for (int dt = 0; dt < 2; dt++)
#pragma unroll
            for (int rI = 0; rI < 4; rI++)
                *swz32x64(SbBuf, 16 * dt + lq * 4 + rI, 16 * wave + lm) = f2bf(Sacc[dt][rI]);
        __syncthreads();   // publish S shadow

        if (c + 1 < NCHK) {
#pragma unroll
            for (int s = 0; s < 2; s++) { wa[s] = wa2[s]; qa[s] = qa2[s]; ma[s] = ma2[s]; kb[s] = kb2[s]; }
#pragma unroll
            for (int dt = 0; dt < 2; dt++)
#pragma unroll
                for (int rI = 0; rI < 4; rI++) uvv[dt][rI] = uvv2[dt][rI];
        }
    }
}

// ---------------- host launch ----------------
extern "C" void kernel_launch(void* const* d_in, const int* in_sizes, int n_in,
                              void* d_out, int out_size, void* d_ws, size_t ws_size,
                              hipStream_t stream) {
    const float* x        = (const float*)d_in[0];
    const float* q_w      = (const float*)d_in[1];
    const float* k_w      = (const float*)d_in[2];
    const float* v_w      = (const float*)d_in[3];
    const float* q_scale  = (const float*)d_in[4];
    const float* k_scale  = (const float*)d_in[5];
    const float* v_scale  = (const float*)d_in[6];
    const float* q_conv_k = (const float*)d_in[7];
    const float* q_conv_b = (const float*)d_in[8];
    const float* k_conv_k = (const float*)d_in[9];
    const float* k_conv_b = (const float*)d_in[10];
    const float* v_conv_k = (const float*)d_in[11];
    const float* v_conv_b = (const float*)d_in[12];
    const float* alpha_w  = (const float*)d_in[13];
    const float* beta_w   = (const float*)d_in[14];
    const float* out_w    = (const float*)d_in[15];
    const float* gate_w   = (const float*)d_in[16];

    // ---- workspace (~208 MB) ----
    char* w = (char*)d_ws;
    bf16* xb  = (bf16*)w; w += (size_t)Mc * Dc * 2;          // 16 MB
    bf16* qwT = (bf16*)w; w += (size_t)QKDc * Dc * 2;        //  2 MB  -- qwT|kwT|vwT|gwT
    bf16* kwT = (bf16*)w; w += (size_t)QKDc * Dc * 2;        //  2 MB     contiguous =
    bf16* vwT = (bf16*)w; w += (size_t)VDc * Dc * 2;         //  4 MB     [5120][1024]
    bf16* gwT = (bf16*)w; w += (size_t)Dc * Dc * 2;          //  2 MB
    bf16* owT = (bf16*)w; w += (size_t)Dc * VDc * 2;         //  4 MB
    bf16* lin_all = (bf16*)w; w += (size_t)Mc * NPRJ * 2;    // 80 MB  [M][5120] q|k|v|g
    bf16* qf = (bf16*)w; w += (size_t)Mc * QKDc * 2;         // 16 MB  (conv q -> Qtilde)
    bf16* kf = (bf16*)w; w += (size_t)Mc * QKDc * 2;         // 16 MB  (conv k -> KbarT)
    bf16* vc = (bf16*)w; w += (size_t)Mc * VDc * 2;          // 32 MB  (conv v -> Uv)
    float* af = (float*)w; w += (size_t)Mc * Hc * 4;
    float* bfv = (float*)w; w += (size_t)Mc * Hc * 4;
    const int NCH_TOT = Bc * Hc * NCHK;                      // 2048 chunk-heads
    bf16* Wb = (bf16*)w; w += (size_t)NCH_TOT * 64 * 64 * 2; // 16 MB
    bf16* Mb = (bf16*)w; w += (size_t)NCH_TOT * 64 * 64 * 2; // 16 MB
    float* gamC = (float*)w; w += (size_t)NCH_TOT * 4;       //  8 KB
    // scan output goes into lin_all cols 0:2048 (q|k sections, dead after convs)
    bf16* o_core = lin_all;

    dim3 tb(32, 8);
    cast_f32_bf16<<<(Mc * Dc / 4 + 255) / 256, 256, 0, stream>>>(x, xb, Mc * Dc / 4);
    transpose_cast<<<dim3(QKDc / 32, Dc / 32), tb, 0, stream>>>(q_w, qwT, Dc, QKDc);
    transpose_cast<<<dim3(QKDc / 32, Dc / 32), tb, 0, stream>>>(k_w, kwT, Dc, QKDc);
    transpose_cast<<<dim3(VDc / 32, Dc / 32), tb, 0, stream>>>(v_w, vwT, Dc, VDc);
    transpose_cast<<<dim3(Dc / 32, Dc / 32), tb, 0, stream>>>(gate_w, gwT, Dc, Dc);
    transpose_cast<<<dim3(Dc / 32, VDc / 32), tb, 0, stream>>>(out_w, owT, VDc, Dc);

    // fused q|k|v|gate projection: pipelined 256x256 GEMM, single-barrier, depth-3
    gemm_pipe<<<GP_NT * GP_MT, 512, 0, stream>>>(xb, qwT, lin_all);

    // fused zc-RMSNorm + causal conv + SiLU (raw lin_all in, compact out)
    normconv<QKDc><<<Mc, QKDc / 8, 0, stream>>>(lin_all,        q_scale, q_conv_k, q_conv_b, qf, NPRJ);
    normconv<QKDc><<<Mc, QKDc / 8, 0, stream>>>(lin_all + 1024, k_scale, k_conv_k, k_conv_b, kf, NPRJ);
    normconv<VDc><<<Mc, VDc / 8, 0, stream>>>(lin_all + 2048,   v_scale, v_conv_k, v_conv_b, vc, NPRJ);

    // alpha/beta via MFMA (hi/lo-split weights, f32-grade)
    alphabeta_mfma<<<Mc / 128, 256, 0, stream>>>(xb, alpha_w, beta_w, af, bfv);

    // chunked delta rule: parallel prep (per chunk-head), then 32-deep MFMA scan
    prep<<<dim3(NCHK, Bc * Hc), 256, 0, stream>>>(qf, kf, vc, af, bfv, Wb, Mb, gamC);
    chunkloop<<<256, 256, 0, stream>>>(qf, kf, vc, Wb, Mb, gamC, o_core, NPRJ);

    // out-projection: pipelined 128x256 GEMM (256 blocks, no tail) + fused gate
    gemm_pipe_out<<<256, 512, 0, stream>>>(o_core, owT, (float*)d_out, lin_all + 4096);
}